// Round 4
// baseline (1082.649 us; speedup 1.0000x reference)
//
#include <hip/hip_runtime.h>
#include <math.h>

#define N_NODES 50000
#define N_EDGES 600000
#define N_GRAPHS 512
#define HID 128
#define LAT 64
#define NL 4
#define N_TILES (N_NODES / 16)  // 3125 exact

typedef __attribute__((ext_vector_type(8))) __bf16 bf16x8;
typedef __attribute__((ext_vector_type(4))) float f32x4;

union Chunk {
    bf16x8 v;
    uint4 u4;
    ushort us[8];
};

__device__ __forceinline__ float gelu_exact(float x) {
    return 0.5f * x * (1.0f + erff(x * 0.70710678118654752f));
}
__device__ __forceinline__ float bf2f(ushort h) {
    return __uint_as_float(((unsigned int)h) << 16);
}
__device__ __forceinline__ ushort f2bf(float f) {  // RNE
    unsigned int u = __float_as_uint(f);
    unsigned int r = (u + 0x7FFFu + ((u >> 16) & 1u)) >> 16;
    return (ushort)r;
}

// ---------------------------------------------------------------------------
// Weight pre-transpose + bf16: Wt[g][n][k] = W_g[k][n], g=0..3 fc1, 4..7 fc2
// ---------------------------------------------------------------------------
__global__ __launch_bounds__(256) void wt_build(const float* __restrict__ fc1w,
                                                const float* __restrict__ fc2w,
                                                ushort* __restrict__ Wt) {
    int i = blockIdx.x * 256 + threadIdx.x;  // 131072
    if (i >= 8 * HID * HID) return;
    int g = i >> 14;
    int rem = i & 16383;
    int n = rem >> 7, k = rem & 127;
    const float* W = (g < 4) ? (fc1w + (long)g * HID * HID) : (fc2w + (long)(g - 4) * HID * HID);
    Wt[i] = f2bf(W[k * HID + n]);
}

// ---------------------------------------------------------------------------
// Column stats over fp32 X: branch-free clamped loads -> 8 loads in flight
// ---------------------------------------------------------------------------
__global__ __launch_bounds__(256) void col_stats(const float* __restrict__ X,
                                                 float* __restrict__ stats) {
    __shared__ float sh[2048];
    int t = threadIdx.x;
    int tx = t & 31, ty = t >> 5;
    int r0 = blockIdx.x * 64;
    float4 v[8];
    float wgt[8];
#pragma unroll
    for (int i = 0; i < 8; ++i) {
        int r = r0 + ty + 8 * i;
        int rc = min(r, N_NODES - 1);
        v[i] = *(const float4*)(X + (long)rc * HID + 4 * tx);
        wgt[i] = (r < N_NODES) ? 1.f : 0.f;
    }
    float s[4] = {0, 0, 0, 0}, q[4] = {0, 0, 0, 0};
#pragma unroll
    for (int i = 0; i < 8; ++i) {
        float w = wgt[i];
        float x0 = v[i].x * w, x1 = v[i].y * w, x2 = v[i].z * w, x3 = v[i].w * w;
        s[0] += x0; s[1] += x1; s[2] += x2; s[3] += x3;
        q[0] += x0 * v[i].x; q[1] += x1 * v[i].y; q[2] += x2 * v[i].z; q[3] += x3 * v[i].w;
    }
#pragma unroll
    for (int c = 0; c < 4; ++c) {
        sh[ty * HID + 4 * tx + c] = s[c];
        sh[1024 + ty * HID + 4 * tx + c] = q[c];
    }
    __syncthreads();
    if (ty == 0) {
#pragma unroll
        for (int c = 0; c < 4; ++c) {
            float a = 0, b = 0;
#pragma unroll
            for (int j = 0; j < 8; ++j) {
                a += sh[j * HID + 4 * tx + c];
                b += sh[1024 + j * HID + 4 * tx + c];
            }
            atomicAdd(stats + 4 * tx + c, a);
            atomicAdd(stats + HID + 4 * tx + c, b);
        }
    }
}

// ---------------------------------------------------------------------------
// BN apply, fp32 in -> bf16 out (input BN). Scale/shift computed inline.
// ---------------------------------------------------------------------------
__global__ __launch_bounds__(256) void bn_apply_f32(const float* __restrict__ X,
                                                    ushort* __restrict__ Y,
                                                    const float* __restrict__ stats,
                                                    const float* __restrict__ g,
                                                    const float* __restrict__ b) {
    int i = blockIdx.x * 256 + threadIdx.x;
    if (i >= N_NODES * (HID / 4)) return;
    int c4 = (i & 31) * 4;
    const float invN = 1.0f / (float)N_NODES;
    float sc[4], sf[4];
#pragma unroll
    for (int j = 0; j < 4; ++j) {
        int c = c4 + j;
        float mean = stats[c] * invN;
        float var = stats[HID + c] * invN - mean * mean;
        float s = g[c] * rsqrtf(var + 1e-5f);
        sc[j] = s;
        sf[j] = b[c] - mean * s;
    }
    float4 v = ((const float4*)X)[i];
    ushort4 w;
    w.x = f2bf(v.x * sc[0] + sf[0]);
    w.y = f2bf(v.y * sc[1] + sf[1]);
    w.z = f2bf(v.z * sc[2] + sf[2]);
    w.w = f2bf(v.w * sc[3] + sf[3]);
    ((ushort4*)Y)[i] = w;
}

// BN + gelu, bf16 in -> bf16 out (8 elems/thread). Scale/shift inline.
__global__ __launch_bounds__(256) void bn_apply_bf(const ushort* __restrict__ X,
                                                   ushort* __restrict__ Y,
                                                   const float* __restrict__ stats,
                                                   const float* __restrict__ g,
                                                   const float* __restrict__ b) {
    int i = blockIdx.x * 256 + threadIdx.x;
    if (i >= N_NODES * (HID / 8)) return;
    int c8 = (i & 15) * 8;
    const float invN = 1.0f / (float)N_NODES;
    Chunk ch;
    ch.u4 = ((const uint4*)X)[i];
#pragma unroll
    for (int j = 0; j < 8; ++j) {
        int c = c8 + j;
        float mean = stats[c] * invN;
        float var = stats[HID + c] * invN - mean * mean;
        float s = g[c] * rsqrtf(var + 1e-5f);
        float f = bf2f(ch.us[j]) * s + (b[c] - mean * s);
        ch.us[j] = f2bf(gelu_exact(f));
    }
    ((uint4*)Y)[i] = ch.u4;
}

// ---------------------------------------------------------------------------
// CSR build: counting sort of edges by dst
// ---------------------------------------------------------------------------
__global__ __launch_bounds__(256) void csr_count(const int* __restrict__ dst,
                                                 int* __restrict__ counts) {
    int e = blockIdx.x * blockDim.x + threadIdx.x;
    if (e >= N_EDGES) return;
    atomicAdd(counts + dst[e], 1);
}

__global__ __launch_bounds__(256) void scan_pass1(const int* __restrict__ counts,
                                                  int* __restrict__ offs,
                                                  int* __restrict__ bsum) {
    __shared__ int sh[256];
    int t = threadIdx.x;
    int i = blockIdx.x * 256 + t;
    int v = (i < N_NODES) ? counts[i] : 0;
    sh[t] = v;
    __syncthreads();
    for (int off = 1; off < 256; off <<= 1) {
        int a = (t >= off) ? sh[t - off] : 0;
        __syncthreads();
        sh[t] += a;
        __syncthreads();
    }
    if (i < N_NODES) offs[i] = sh[t] - v;
    if (t == 255) bsum[blockIdx.x] = sh[255];
}

__global__ __launch_bounds__(256) void scan_pass2(int* __restrict__ bsum, int nblk) {
    __shared__ int sh[256];
    int t = threadIdx.x;
    int v = (t < nblk) ? bsum[t] : 0;
    sh[t] = v;
    __syncthreads();
    for (int off = 1; off < 256; off <<= 1) {
        int a = (t >= off) ? sh[t - off] : 0;
        __syncthreads();
        sh[t] += a;
        __syncthreads();
    }
    if (t < nblk) bsum[t] = sh[t] - v;
}

__global__ __launch_bounds__(256) void scan_pass3(int* __restrict__ offs,
                                                  const int* __restrict__ bsum,
                                                  int* __restrict__ cursor) {
    int i = blockIdx.x * 256 + threadIdx.x;
    if (i >= N_NODES) return;
    int o = offs[i] + bsum[blockIdx.x];
    offs[i] = o;
    cursor[i] = o;
}

__global__ __launch_bounds__(256) void csr_fill(const int* __restrict__ src,
                                                const int* __restrict__ dst,
                                                int* __restrict__ cursor,
                                                int* __restrict__ csr) {
    int e = blockIdx.x * blockDim.x + threadIdx.x;
    if (e >= N_EDGES) return;
    int pos = atomicAdd(cursor + dst[e], 1);
    csr[pos] = src[e];
}

// ---------------------------------------------------------------------------
// GIN aggregation (bf16): Hp[n] = (1+eps)*X[n] + sum X[nbr]; 4-deep pipelined
// 32 lanes per node (4 cols each), 8 nodes per 256-block
// ---------------------------------------------------------------------------
__global__ __launch_bounds__(256) void gin_gather_bf(const ushort* __restrict__ Xbf,
                                                     ushort* __restrict__ Hp,
                                                     const int* __restrict__ offs,
                                                     const int* __restrict__ counts,
                                                     const int* __restrict__ csr,
                                                     const float* __restrict__ eps, int l) {
    int t = threadIdx.x;
    int tx = t & 31;
    int node = blockIdx.x * 8 + (t >> 5);
    if (node >= N_NODES) return;
    float ev = 1.0f + eps[l];
    ushort4 sv = *(const ushort4*)(Xbf + (long)node * HID + 4 * tx);
    float a0 = bf2f(sv.x) * ev, a1 = bf2f(sv.y) * ev, a2 = bf2f(sv.z) * ev, a3 = bf2f(sv.w) * ev;
    int o = offs[node];
    int d = counts[node];
    int k = 0;
    for (; k + 4 <= d; k += 4) {
        int s0 = csr[o + k], s1 = csr[o + k + 1], s2 = csr[o + k + 2], s3 = csr[o + k + 3];
        ushort4 v0 = *(const ushort4*)(Xbf + (long)s0 * HID + 4 * tx);
        ushort4 v1 = *(const ushort4*)(Xbf + (long)s1 * HID + 4 * tx);
        ushort4 v2 = *(const ushort4*)(Xbf + (long)s2 * HID + 4 * tx);
        ushort4 v3 = *(const ushort4*)(Xbf + (long)s3 * HID + 4 * tx);
        a0 += bf2f(v0.x) + bf2f(v1.x) + bf2f(v2.x) + bf2f(v3.x);
        a1 += bf2f(v0.y) + bf2f(v1.y) + bf2f(v2.y) + bf2f(v3.y);
        a2 += bf2f(v0.z) + bf2f(v1.z) + bf2f(v2.z) + bf2f(v3.z);
        a3 += bf2f(v0.w) + bf2f(v1.w) + bf2f(v2.w) + bf2f(v3.w);
    }
    for (; k < d; ++k) {
        int s = csr[o + k];
        ushort4 v = *(const ushort4*)(Xbf + (long)s * HID + 4 * tx);
        a0 += bf2f(v.x); a1 += bf2f(v.y); a2 += bf2f(v.z); a3 += bf2f(v.w);
    }
    ushort4 w;
    w.x = f2bf(a0); w.y = f2bf(a1); w.z = f2bf(a2); w.w = f2bf(a3);
    *(ushort4*)(Hp + (long)node * HID + 4 * tx) = w;
}

// ---------------------------------------------------------------------------
// Streaming MFMA GEMM, B in registers, zero LDS staging, no barriers in loop.
// C[M,128] = A[M,128] @ W + bias (all bf16, fp32 accum). Wt[n][k] pretransposed.
// Wave handles 16-row tiles (grid-stride). 50000 = 3125*16 exactly -> no guards.
// Per-column sum/sumsq accumulated in registers, combined per block at end.
// ---------------------------------------------------------------------------
__global__ __launch_bounds__(256) void gemm_stream(const ushort* __restrict__ Abf,
                                                   const ushort* __restrict__ Wt,
                                                   const float* __restrict__ bias,
                                                   ushort* __restrict__ Cbf,
                                                   float* __restrict__ stats) {
    __shared__ float shs[1024];
    int t = threadIdx.x;
    int w = t >> 6, lane = t & 63;
    int m = lane & 15, q = lane >> 4;

    // B fragments: Bfrag[nt][kc] = Wt[nt*16+m][kc*32+q*8 .. +8)
    bf16x8 Bfrag[8][4];
#pragma unroll
    for (int nt = 0; nt < 8; ++nt)
#pragma unroll
        for (int kc = 0; kc < 4; ++kc)
            Bfrag[nt][kc] = *(const bf16x8*)(Wt + (nt * 16 + m) * HID + kc * 32 + q * 8);

    float bias8[8];
#pragma unroll
    for (int nt = 0; nt < 8; ++nt) bias8[nt] = bias[nt * 16 + m];

    float s_col[8], q_col[8];
#pragma unroll
    for (int nt = 0; nt < 8; ++nt) { s_col[nt] = 0.f; q_col[nt] = 0.f; }

    int waveId = blockIdx.x * 4 + w;
    int nWaves = gridDim.x * 4;

    for (int tile = waveId; tile < N_TILES; tile += nWaves) {
        const ushort* arow = Abf + (long)(tile * 16 + m) * HID + q * 8;
        bf16x8 A4[4];
        A4[0] = *(const bf16x8*)(arow);
        A4[1] = *(const bf16x8*)(arow + 32);
        A4[2] = *(const bf16x8*)(arow + 64);
        A4[3] = *(const bf16x8*)(arow + 96);

        f32x4 acc[8];
#pragma unroll
        for (int nt = 0; nt < 8; ++nt) acc[nt] = (f32x4){0.f, 0.f, 0.f, 0.f};
#pragma unroll
        for (int kc = 0; kc < 4; ++kc)
#pragma unroll
            for (int nt = 0; nt < 8; ++nt)
                acc[nt] = __builtin_amdgcn_mfma_f32_16x16x32_bf16(A4[kc], Bfrag[nt][kc],
                                                                  acc[nt], 0, 0, 0);

        int rbase = tile * 16 + q * 4;
#pragma unroll
        for (int nt = 0; nt < 8; ++nt) {
            int col = nt * 16 + m;
#pragma unroll
            for (int r = 0; r < 4; ++r) {
                float z = acc[nt][r] + bias8[nt];
                Cbf[(long)(rbase + r) * HID + col] = f2bf(z);
                s_col[nt] += z;
                q_col[nt] += z * z;
            }
        }
    }

    // combine stats: reduce over q (shfl), then over 4 waves via LDS
#pragma unroll
    for (int nt = 0; nt < 8; ++nt) {
        s_col[nt] += __shfl_xor(s_col[nt], 16);
        s_col[nt] += __shfl_xor(s_col[nt], 32);
        q_col[nt] += __shfl_xor(q_col[nt], 16);
        q_col[nt] += __shfl_xor(q_col[nt], 32);
    }
    if (q == 0) {
#pragma unroll
        for (int nt = 0; nt < 8; ++nt) {
            shs[w * HID + nt * 16 + m] = s_col[nt];
            shs[512 + w * HID + nt * 16 + m] = q_col[nt];
        }
    }
    __syncthreads();
    if (t < HID) {
        float a = 0, b = 0;
#pragma unroll
        for (int j = 0; j < 4; ++j) {
            a += shs[j * HID + t];
            b += shs[512 + j * HID + t];
        }
        atomicAdd(stats + t, a);
        atomicAdd(stats + HID + t, b);
    }
}

// JK attention over 4 layers (bf16 in, fp32 out): one wave per node
__global__ __launch_bounds__(256) void jk_attn_bf(const ushort* __restrict__ H0,
                                                  const ushort* __restrict__ H1,
                                                  const ushort* __restrict__ H2,
                                                  const ushort* __restrict__ H3,
                                                  const float* __restrict__ att,
                                                  float* __restrict__ Y) {
    long gid = (long)blockIdx.x * blockDim.x + threadIdx.x;
    int lane = (int)(gid & 63);
    int node = (int)(gid >> 6);
    if (node >= N_NODES) return;
    const ushort* Hs[4] = {H0, H1, H2, H3};
    float hx[4], hy[4], sc[4];
#pragma unroll
    for (int l = 0; l < 4; ++l) {
        unsigned int u = *(const unsigned int*)(Hs[l] + (long)node * HID + 2 * lane);
        float vx = bf2f((ushort)(u & 0xFFFF));
        float vy = bf2f((ushort)(u >> 16));
        float2 a = *(const float2*)(att + l * HID + 2 * lane);
        hx[l] = vx; hy[l] = vy;
        float p = vx * a.x + vy * a.y;
#pragma unroll
        for (int off = 32; off > 0; off >>= 1) p += __shfl_xor(p, off);
        sc[l] = p * (1.0f / HID);
    }
    float mm = fmaxf(fmaxf(sc[0], sc[1]), fmaxf(sc[2], sc[3]));
    float e[4], se = 0.f;
#pragma unroll
    for (int l = 0; l < 4; ++l) { e[l] = expf(sc[l] - mm); se += e[l]; }
    float inv = 1.0f / se;
    float ox = 0.f, oy = 0.f;
#pragma unroll
    for (int l = 0; l < 4; ++l) {
        float a = e[l] * inv;
        ox += a * hx[l];
        oy += a * hy[l];
    }
    *(float2*)(Y + (long)node * HID + 2 * lane) = make_float2(ox, oy);
}

__global__ void graph_ranges(const int* __restrict__ batch, int* __restrict__ gstart,
                             int* __restrict__ gend) {
    int n = blockIdx.x * blockDim.x + threadIdx.x;
    if (n >= N_NODES) return;
    int b = batch[n];
    if (n == 0 || batch[n - 1] != b) gstart[b] = n;
    if (n == N_NODES - 1 || batch[n + 1] != b) gend[b] = n + 1;
}

__global__ __launch_bounds__(128) void pool_kernel(const float* __restrict__ X,
                                                   const int* __restrict__ gstart,
                                                   const int* __restrict__ gend,
                                                   const float* __restrict__ pw,
                                                   float* __restrict__ pooled) {
    int g = blockIdx.x;
    int f = threadIdx.x;
    float w0 = pw[0], w1 = pw[1], w2 = pw[2];
    float m = fmaxf(w0, fmaxf(w1, w2));
    float e0 = expf(w0 - m), e1 = expf(w1 - m), e2 = expf(w2 - m);
    float inv = 1.0f / (e0 + e1 + e2);
    e0 *= inv; e1 *= inv; e2 *= inv;
    int s = gstart[g], e = gend[g];
    float sum = 0.f, mx = -INFINITY;
    for (int n = s; n < e; ++n) {
        float v = X[(long)n * HID + f];
        sum += v;
        mx = fmaxf(mx, v);
    }
    int cnt = e - s;
    float mean = cnt > 0 ? sum / (float)cnt : 0.f;
    float mxv = cnt > 0 ? mx : 0.f;
    pooled[g * HID + f] = sum * e0 + mean * e1 + mxv * e2;
}

__global__ __launch_bounds__(128) void head_kernel(const float* __restrict__ pooled,
                                                   const float* __restrict__ fcAw,
                                                   const float* __restrict__ fcAb,
                                                   const float* __restrict__ lng,
                                                   const float* __restrict__ lnb,
                                                   const float* __restrict__ fcBw,
                                                   const float* __restrict__ fcBb,
                                                   float* __restrict__ out) {
    __shared__ float p[HID], q[HID], red[HID];
    int g = blockIdx.x, j = threadIdx.x;
    p[j] = pooled[g * HID + j];
    __syncthreads();
    float acc = fcAb[j];
    for (int k = 0; k < HID; ++k) acc += p[k] * fcAw[k * HID + j];
    red[j] = acc;
    __syncthreads();
    for (int off = 64; off > 0; off >>= 1) {
        if (j < off) red[j] += red[j + off];
        __syncthreads();
    }
    float mean = red[0] * (1.0f / HID);
    __syncthreads();
    float d = acc - mean;
    red[j] = d * d;
    __syncthreads();
    for (int off = 64; off > 0; off >>= 1) {
        if (j < off) red[j] += red[j + off];
        __syncthreads();
    }
    float var = red[0] * (1.0f / HID);
    float y = d * rsqrtf(var + 1e-5f) * lng[j] + lnb[j];
    q[j] = gelu_exact(y) + p[j];
    __syncthreads();
    if (j < LAT) {
        float o = fcBb[j];
        for (int k = 0; k < HID; ++k) o += q[k] * fcBw[k * LAT + j];
        out[g * LAT + j] = o;
    }
}

extern "C" void kernel_launch(void* const* d_in, const int* in_sizes, int n_in,
                              void* d_out, int out_size, void* d_ws, size_t ws_size,
                              hipStream_t stream) {
    const float* x = (const float*)d_in[0];
    const int* ei = (const int*)d_in[1];
    const int* src = ei;
    const int* dst = ei + N_EDGES;
    const int* batch = (const int*)d_in[2];
    const float* ibn_g = (const float*)d_in[3];
    const float* ibn_b = (const float*)d_in[4];
    const float* eps = (const float*)d_in[5];
    const float* fc1w = (const float*)d_in[6];
    const float* fc1b = (const float*)d_in[7];
    const float* bn1g = (const float*)d_in[8];
    const float* bn1b = (const float*)d_in[9];
    const float* fc2w = (const float*)d_in[10];
    const float* fc2b = (const float*)d_in[11];
    const float* bng = (const float*)d_in[12];
    const float* bnb = (const float*)d_in[13];
    const float* att = (const float*)d_in[14];
    const float* pw = (const float*)d_in[15];
    const float* fcAw = (const float*)d_in[16];
    const float* fcAb = (const float*)d_in[17];
    const float* lng = (const float*)d_in[18];
    const float* lnb = (const float*)d_in[19];
    const float* fcBw = (const float*)d_in[20];
    const float* fcBb = (const float*)d_in[21];
    float* out = (float*)d_out;

    const size_t NH = (size_t)N_NODES * HID;
    char* w8 = (char*)d_ws;
    ushort* x0bf = (ushort*)w8;     w8 += NH * 2;
    ushort* hprebf = (ushort*)w8;   w8 += NH * 2;  // also reused as act1
    ushort* g1bf = (ushort*)w8;     w8 += NH * 2;  // also reused as g2
    ushort* Hlbf[NL];
    for (int l = 0; l < NL; ++l) { Hlbf[l] = (ushort*)w8; w8 += NH * 2; }
    float* ztmp = (float*)w8;       w8 += NH * 4;
    float* statsAll = (float*)w8;   w8 += 9 * 256 * 4;  // 9 independent stat sets
    float* pooled = (float*)w8;     w8 += (size_t)N_GRAPHS * HID * 4;
    int* gstart = (int*)w8;         w8 += N_GRAPHS * 4;
    int* gend = (int*)w8;           w8 += N_GRAPHS * 4;
    int* counts = (int*)w8;         w8 += N_NODES * 4;
    int* offs = (int*)w8;           w8 += N_NODES * 4;
    int* cursor = (int*)w8;         w8 += N_NODES * 4;
    int* bsum = (int*)w8;           w8 += 256 * 4;
    int* csr = (int*)w8;            w8 += (size_t)N_EDGES * 4;
    ushort* WtBf = (ushort*)w8;     w8 += (size_t)8 * HID * HID * 2;

    const int rowBlocks = (N_NODES + 63) / 64;   // 782
    const int nodeBlocks = (N_NODES + 255) / 256;
    const int edgeBlocks = (N_EDGES + 255) / 256;
    const int elem4Blocks = (N_NODES * (HID / 4) + 255) / 256;  // 6250
    const int elem8Blocks = (N_NODES * (HID / 8) + 255) / 256;  // 3125

    // weights once
    wt_build<<<512, 256, 0, stream>>>(fc1w, fc2w, WtBf);

    // CSR build
    hipMemsetAsync(counts, 0, N_NODES * sizeof(int), stream);
    csr_count<<<edgeBlocks, 256, 0, stream>>>(dst, counts);
    scan_pass1<<<nodeBlocks, 256, 0, stream>>>(counts, offs, bsum);
    scan_pass2<<<1, 256, 0, stream>>>(bsum, nodeBlocks);
    scan_pass3<<<nodeBlocks, 256, 0, stream>>>(offs, bsum, cursor);
    csr_fill<<<edgeBlocks, 256, 0, stream>>>(src, dst, cursor, csr);

    // all stat sets zeroed once (each is written by exactly one producer)
    hipMemsetAsync(statsAll, 0, 9 * 256 * sizeof(float), stream);

    // input BN -> bf16 x0
    col_stats<<<rowBlocks, 256, 0, stream>>>(x, statsAll);
    bn_apply_f32<<<elem4Blocks, 256, 0, stream>>>(x, x0bf, statsAll, ibn_g, ibn_b);

    const ushort* xin = x0bf;
    for (int l = 0; l < NL; ++l) {
        float* st1 = statsAll + (1 + 2 * l) * 256;
        float* st2 = statsAll + (2 + 2 * l) * 256;
        gin_gather_bf<<<(N_NODES + 7) / 8, 256, 0, stream>>>(xin, hprebf, offs, counts,
                                                             csr, eps, l);
        gemm_stream<<<rowBlocks, 256, 0, stream>>>(hprebf, WtBf + (size_t)l * HID * HID,
                                                   fc1b + l * HID, g1bf, st1);
        bn_apply_bf<<<elem8Blocks, 256, 0, stream>>>(g1bf, hprebf, st1, bn1g + l * HID,
                                                     bn1b + l * HID);
        gemm_stream<<<rowBlocks, 256, 0, stream>>>(hprebf,
                                                   WtBf + (size_t)(4 + l) * HID * HID,
                                                   fc2b + l * HID, g1bf, st2);
        bn_apply_bf<<<elem8Blocks, 256, 0, stream>>>(g1bf, Hlbf[l], st2, bng + l * HID,
                                                     bnb + l * HID);
        xin = Hlbf[l];
    }

    // JK attention -> ztmp (fp32)
    jk_attn_bf<<<(int)(((long)N_NODES * 64 + 255) / 256), 256, 0, stream>>>(
        Hlbf[0], Hlbf[1], Hlbf[2], Hlbf[3], att, ztmp);

    // pooling
    hipMemsetAsync(gstart, 0, 2 * N_GRAPHS * sizeof(int), stream);
    graph_ranges<<<nodeBlocks, 256, 0, stream>>>(batch, gstart, gend);
    pool_kernel<<<N_GRAPHS, 128, 0, stream>>>(ztmp, gstart, gend, pw, pooled);

    // head
    head_kernel<<<N_GRAPHS, 128, 0, stream>>>(pooled, fcAw, fcAb, lng, lnb, fcBw, fcBb, out);
}

// Round 5
// 884.083 us; speedup vs baseline: 1.2246x; 1.2246x over previous
//
#include <hip/hip_runtime.h>
#include <math.h>

#define N_NODES 50000
#define N_EDGES 600000
#define N_GRAPHS 512
#define HID 128
#define LAT 64
#define NL 4
#define LDA 136        // padded LDS row stride (bf16 elems)
#define SSTR 16        // stats padding: 1 float per 64B cache line
#define SSET 4096      // floats per stat set: 256 entries * 16

typedef __attribute__((ext_vector_type(8))) __bf16 bf16x8;
typedef __attribute__((ext_vector_type(4))) float f32x4;

union Chunk {
    bf16x8 v;
    uint4 u4;
    ushort us[8];
};

__device__ __forceinline__ float gelu_exact(float x) {
    return 0.5f * x * (1.0f + erff(x * 0.70710678118654752f));
}
__device__ __forceinline__ float bf2f(ushort h) {
    return __uint_as_float(((unsigned int)h) << 16);
}
__device__ __forceinline__ ushort f2bf(float f) {  // RNE
    unsigned int u = __float_as_uint(f);
    unsigned int r = (u + 0x7FFFu + ((u >> 16) & 1u)) >> 16;
    return (ushort)r;
}

// ---------------------------------------------------------------------------
// Weight pre-transpose + bf16: Wt[g][n][k] = W_g[k][n], g=0..3 fc1, 4..7 fc2
// ---------------------------------------------------------------------------
__global__ __launch_bounds__(256) void wt_build(const float* __restrict__ fc1w,
                                                const float* __restrict__ fc2w,
                                                ushort* __restrict__ Wt) {
    int i = blockIdx.x * 256 + threadIdx.x;  // 131072
    if (i >= 8 * HID * HID) return;
    int g = i >> 14;
    int rem = i & 16383;
    int n = rem >> 7, k = rem & 127;
    const float* W = (g < 4) ? (fc1w + (long)g * HID * HID) : (fc2w + (long)(g - 4) * HID * HID);
    Wt[i] = f2bf(W[k * HID + n]);
}

// ---------------------------------------------------------------------------
// Column stats over fp32 X -> padded stats (sum at [c*16], sumsq at [(128+c)*16])
// Grid-stride over 64-row tiles; one padded-atomic set per block at the end.
// ---------------------------------------------------------------------------
__global__ __launch_bounds__(256) void col_stats(const float* __restrict__ X,
                                                 float* __restrict__ stats) {
    __shared__ float sh[2048];
    int t = threadIdx.x;
    int tx = t & 31, ty = t >> 5;
    float s[4] = {0, 0, 0, 0}, q[4] = {0, 0, 0, 0};
    const int nTiles = (N_NODES + 63) / 64;  // 782
    for (int tile = blockIdx.x; tile < nTiles; tile += gridDim.x) {
        int r0 = tile * 64;
#pragma unroll
        for (int i = 0; i < 8; ++i) {
            int r = r0 + ty + 8 * i;
            int rc = min(r, N_NODES - 1);
            float4 v = *(const float4*)(X + (long)rc * HID + 4 * tx);
            float w = (r < N_NODES) ? 1.f : 0.f;
            float x0 = v.x * w, x1 = v.y * w, x2 = v.z * w, x3 = v.w * w;
            s[0] += x0; s[1] += x1; s[2] += x2; s[3] += x3;
            q[0] += x0 * v.x; q[1] += x1 * v.y; q[2] += x2 * v.z; q[3] += x3 * v.w;
        }
    }
#pragma unroll
    for (int c = 0; c < 4; ++c) {
        sh[ty * HID + 4 * tx + c] = s[c];
        sh[1024 + ty * HID + 4 * tx + c] = q[c];
    }
    __syncthreads();
    if (ty == 0) {
#pragma unroll
        for (int c = 0; c < 4; ++c) {
            float a = 0, b = 0;
#pragma unroll
            for (int j = 0; j < 8; ++j) {
                a += sh[j * HID + 4 * tx + c];
                b += sh[1024 + j * HID + 4 * tx + c];
            }
            atomicAdd(stats + (4 * tx + c) * SSTR, a);
            atomicAdd(stats + (HID + 4 * tx + c) * SSTR, b);
        }
    }
}

// ---------------------------------------------------------------------------
// BN apply, fp32 in -> bf16 out; scale/shift computed inline from padded stats
// ---------------------------------------------------------------------------
__global__ __launch_bounds__(256) void bn_apply_f32(const float* __restrict__ X,
                                                    ushort* __restrict__ Y,
                                                    const float* __restrict__ stats,
                                                    const float* __restrict__ g,
                                                    const float* __restrict__ b,
                                                    int doGelu) {
    int i = blockIdx.x * 256 + threadIdx.x;
    if (i >= N_NODES * (HID / 4)) return;
    int c4 = (i & 31) * 4;
    const float invN = 1.0f / (float)N_NODES;
    float4 v = ((const float4*)X)[i];
    float o[4] = {v.x, v.y, v.z, v.w};
#pragma unroll
    for (int j = 0; j < 4; ++j) {
        int c = c4 + j;
        float mean = stats[c * SSTR] * invN;
        float var = stats[(HID + c) * SSTR] * invN - mean * mean;
        float s = g[c] * rsqrtf(var + 1e-5f);
        float f = o[j] * s + (b[c] - mean * s);
        o[j] = doGelu ? gelu_exact(f) : f;
    }
    ushort4 w;
    w.x = f2bf(o[0]); w.y = f2bf(o[1]); w.z = f2bf(o[2]); w.w = f2bf(o[3]);
    ((ushort4*)Y)[i] = w;
}

// ---------------------------------------------------------------------------
// CSR build: counting sort of edges by dst
// ---------------------------------------------------------------------------
__global__ __launch_bounds__(256) void csr_count(const int* __restrict__ dst,
                                                 int* __restrict__ counts) {
    int e = blockIdx.x * blockDim.x + threadIdx.x;
    if (e >= N_EDGES) return;
    atomicAdd(counts + dst[e], 1);
}

__global__ __launch_bounds__(256) void scan_pass1(const int* __restrict__ counts,
                                                  int* __restrict__ offs,
                                                  int* __restrict__ bsum) {
    __shared__ int sh[256];
    int t = threadIdx.x;
    int i = blockIdx.x * 256 + t;
    int v = (i < N_NODES) ? counts[i] : 0;
    sh[t] = v;
    __syncthreads();
    for (int off = 1; off < 256; off <<= 1) {
        int a = (t >= off) ? sh[t - off] : 0;
        __syncthreads();
        sh[t] += a;
        __syncthreads();
    }
    if (i < N_NODES) offs[i] = sh[t] - v;
    if (t == 255) bsum[blockIdx.x] = sh[255];
}

__global__ __launch_bounds__(256) void scan_pass2(int* __restrict__ bsum, int nblk) {
    __shared__ int sh[256];
    int t = threadIdx.x;
    int v = (t < nblk) ? bsum[t] : 0;
    sh[t] = v;
    __syncthreads();
    for (int off = 1; off < 256; off <<= 1) {
        int a = (t >= off) ? sh[t - off] : 0;
        __syncthreads();
        sh[t] += a;
        __syncthreads();
    }
    if (t < nblk) bsum[t] = sh[t] - v;
}

__global__ __launch_bounds__(256) void scan_pass3(int* __restrict__ offs,
                                                  const int* __restrict__ bsum,
                                                  int* __restrict__ cursor) {
    int i = blockIdx.x * 256 + threadIdx.x;
    if (i >= N_NODES) return;
    int o = offs[i] + bsum[blockIdx.x];
    offs[i] = o;
    cursor[i] = o;
}

__global__ __launch_bounds__(256) void csr_fill(const int* __restrict__ src,
                                                const int* __restrict__ dst,
                                                int* __restrict__ cursor,
                                                int* __restrict__ csr) {
    int e = blockIdx.x * blockDim.x + threadIdx.x;
    if (e >= N_EDGES) return;
    int pos = atomicAdd(cursor + dst[e], 1);
    csr[pos] = src[e];
}

// ---------------------------------------------------------------------------
// GIN aggregation (bf16): Hp[n] = (1+eps)*X[n] + sum X[nbr]; 4-deep pipelined
// ---------------------------------------------------------------------------
__global__ __launch_bounds__(256) void gin_gather_bf(const ushort* __restrict__ Xbf,
                                                     ushort* __restrict__ Hp,
                                                     const int* __restrict__ offs,
                                                     const int* __restrict__ counts,
                                                     const int* __restrict__ csr,
                                                     const float* __restrict__ eps, int l) {
    int t = threadIdx.x;
    int tx = t & 31;
    int node = blockIdx.x * 8 + (t >> 5);
    if (node >= N_NODES) return;
    float ev = 1.0f + eps[l];
    ushort4 sv = *(const ushort4*)(Xbf + (long)node * HID + 4 * tx);
    float a0 = bf2f(sv.x) * ev, a1 = bf2f(sv.y) * ev, a2 = bf2f(sv.z) * ev, a3 = bf2f(sv.w) * ev;
    int o = offs[node];
    int d = counts[node];
    int k = 0;
    for (; k + 4 <= d; k += 4) {
        int s0 = csr[o + k], s1 = csr[o + k + 1], s2 = csr[o + k + 2], s3 = csr[o + k + 3];
        ushort4 v0 = *(const ushort4*)(Xbf + (long)s0 * HID + 4 * tx);
        ushort4 v1 = *(const ushort4*)(Xbf + (long)s1 * HID + 4 * tx);
        ushort4 v2 = *(const ushort4*)(Xbf + (long)s2 * HID + 4 * tx);
        ushort4 v3 = *(const ushort4*)(Xbf + (long)s3 * HID + 4 * tx);
        a0 += bf2f(v0.x) + bf2f(v1.x) + bf2f(v2.x) + bf2f(v3.x);
        a1 += bf2f(v0.y) + bf2f(v1.y) + bf2f(v2.y) + bf2f(v3.y);
        a2 += bf2f(v0.z) + bf2f(v1.z) + bf2f(v2.z) + bf2f(v3.z);
        a3 += bf2f(v0.w) + bf2f(v1.w) + bf2f(v2.w) + bf2f(v3.w);
    }
    for (; k < d; ++k) {
        int s = csr[o + k];
        ushort4 v = *(const ushort4*)(Xbf + (long)s * HID + 4 * tx);
        a0 += bf2f(v.x); a1 += bf2f(v.y); a2 += bf2f(v.z); a3 += bf2f(v.w);
    }
    ushort4 w;
    w.x = f2bf(a0); w.y = f2bf(a1); w.z = f2bf(a2); w.w = f2bf(a3);
    *(ushort4*)(Hp + (long)node * HID + 4 * tx) = w;
}

// ---------------------------------------------------------------------------
// MFMA GEMM (LDS-staged, R3 structure): C = A' @ W + bias.
// A' = A, or gelu(A*scale+shift) with scale/shift computed per-block from
// padded statsIn + gIn/bIn. Output fp32 (Cf) or bf16 (Cbf). Column sum/sumsq
// accumulated to padded statsOut (one 64B line per value -> no line contention).
// ---------------------------------------------------------------------------
__global__ __launch_bounds__(256) void gemm_mfma(const ushort* __restrict__ Abf,
                                                 const ushort* __restrict__ Wt,
                                                 const float* __restrict__ bias,
                                                 float* __restrict__ Cf,
                                                 ushort* __restrict__ Cbf,
                                                 const float* __restrict__ statsIn,
                                                 const float* __restrict__ gIn,
                                                 const float* __restrict__ bIn,
                                                 int applyIn,
                                                 float* __restrict__ statsOut, int M) {
    __shared__ __align__(16) ushort As[64 * LDA];   // 17408 B
    __shared__ __align__(16) ushort Bs[128 * LDA];  // 34816 B
    __shared__ float scL[HID], sfL[HID];
    int t = threadIdx.x;
    int r0 = blockIdx.x * 64;

    if (applyIn && t < HID) {
        const float invN = 1.0f / (float)N_NODES;
        float mean = statsIn[t * SSTR] * invN;
        float var = statsIn[(HID + t) * SSTR] * invN - mean * mean;
        float s = gIn[t] * rsqrtf(var + 1e-5f);
        scL[t] = s;
        sfL[t] = bIn[t] - mean * s;
    }
    // stage Wt -> Bs (2048 16B chunks)
#pragma unroll
    for (int it = 0; it < 8; ++it) {
        int c = it * 256 + t;
        int n = c >> 4, ko = (c & 15) * 8;
        *(uint4*)(Bs + n * LDA + ko) = *(const uint4*)(Wt + n * HID + ko);
    }
    __syncthreads();  // scL/sfL visible + Bs independent of As staging below
    // stage A -> As (1024 16B chunks), optional BN+gelu on load
#pragma unroll
    for (int it = 0; it < 4; ++it) {
        int c = it * 256 + t;
        int row = c >> 4, ko = (c & 15) * 8;
        int r = r0 + row;
        Chunk ch;
        ch.u4 = make_uint4(0, 0, 0, 0);
        if (r < M) ch.u4 = *(const uint4*)(Abf + (long)r * HID + ko);
        if (applyIn) {
#pragma unroll
            for (int j = 0; j < 8; ++j) {
                float f = bf2f(ch.us[j]) * scL[ko + j] + sfL[ko + j];
                ch.us[j] = f2bf(gelu_exact(f));
            }
        }
        *(uint4*)(As + row * LDA + ko) = ch.u4;
    }
    __syncthreads();

    int lane = t & 63, w = t >> 6;
    int m = lane & 15, q = lane >> 4;
    const ushort* a_base = As + (w * 16 + m) * LDA + q * 8;
    const ushort* b_base = Bs + m * LDA + q * 8;

    f32x4 acc[8];
#pragma unroll
    for (int nt = 0; nt < 8; ++nt) acc[nt] = (f32x4){0.f, 0.f, 0.f, 0.f};

#pragma unroll
    for (int kc = 0; kc < 4; ++kc) {
        bf16x8 a = *(const bf16x8*)(a_base + kc * 32);
#pragma unroll
        for (int nt = 0; nt < 8; ++nt) {
            bf16x8 b = *(const bf16x8*)(b_base + nt * 16 * LDA + kc * 32);
            acc[nt] = __builtin_amdgcn_mfma_f32_16x16x32_bf16(a, b, acc[nt], 0, 0, 0);
        }
    }

    // epilogue: bias, store, per-column sum/sumsq
    float s_arr[8], q_arr[8];
    int rbase = r0 + w * 16 + q * 4;
#pragma unroll
    for (int nt = 0; nt < 8; ++nt) {
        int col = nt * 16 + m;
        float bb = bias[col];
        float s = 0.f, ss = 0.f;
#pragma unroll
        for (int r = 0; r < 4; ++r) {
            int row = rbase + r;
            if (row < M) {
                float z = acc[nt][r] + bb;
                long idx = (long)row * HID + col;
                if (Cf) Cf[idx] = z;
                else Cbf[idx] = f2bf(z);
                s += z;
                ss += z * z;
            }
        }
        s += __shfl_xor(s, 16); s += __shfl_xor(s, 32);
        ss += __shfl_xor(ss, 16); ss += __shfl_xor(ss, 32);
        s_arr[nt] = s;
        q_arr[nt] = ss;
    }
    __syncthreads();  // done with As; reuse as fp32 scratch
    float* shs = (float*)As;
    if (q == 0) {
#pragma unroll
        for (int nt = 0; nt < 8; ++nt) {
            shs[w * HID + nt * 16 + m] = s_arr[nt];
            shs[512 + w * HID + nt * 16 + m] = q_arr[nt];
        }
    }
    __syncthreads();
    if (t < HID) {
        float a = 0, b = 0;
#pragma unroll
        for (int j = 0; j < 4; ++j) {
            a += shs[j * HID + t];
            b += shs[512 + j * HID + t];
        }
        atomicAdd(statsOut + t * SSTR, a);
        atomicAdd(statsOut + (HID + t) * SSTR, b);
    }
}

// JK attention over 4 layers (bf16 in, fp32 out): one wave per node
__global__ __launch_bounds__(256) void jk_attn_bf(const ushort* __restrict__ H0,
                                                  const ushort* __restrict__ H1,
                                                  const ushort* __restrict__ H2,
                                                  const ushort* __restrict__ H3,
                                                  const float* __restrict__ att,
                                                  float* __restrict__ Y) {
    long gid = (long)blockIdx.x * blockDim.x + threadIdx.x;
    int lane = (int)(gid & 63);
    int node = (int)(gid >> 6);
    if (node >= N_NODES) return;
    const ushort* Hs[4] = {H0, H1, H2, H3};
    float hx[4], hy[4], sc[4];
#pragma unroll
    for (int l = 0; l < 4; ++l) {
        unsigned int u = *(const unsigned int*)(Hs[l] + (long)node * HID + 2 * lane);
        float vx = bf2f((ushort)(u & 0xFFFF));
        float vy = bf2f((ushort)(u >> 16));
        float2 a = *(const float2*)(att + l * HID + 2 * lane);
        hx[l] = vx; hy[l] = vy;
        float p = vx * a.x + vy * a.y;
#pragma unroll
        for (int off = 32; off > 0; off >>= 1) p += __shfl_xor(p, off);
        sc[l] = p * (1.0f / HID);
    }
    float mm = fmaxf(fmaxf(sc[0], sc[1]), fmaxf(sc[2], sc[3]));
    float e[4], se = 0.f;
#pragma unroll
    for (int l = 0; l < 4; ++l) { e[l] = expf(sc[l] - mm); se += e[l]; }
    float inv = 1.0f / se;
    float ox = 0.f, oy = 0.f;
#pragma unroll
    for (int l = 0; l < 4; ++l) {
        float a = e[l] * inv;
        ox += a * hx[l];
        oy += a * hy[l];
    }
    *(float2*)(Y + (long)node * HID + 2 * lane) = make_float2(ox, oy);
}

__global__ void graph_ranges(const int* __restrict__ batch, int* __restrict__ gstart,
                             int* __restrict__ gend) {
    int n = blockIdx.x * blockDim.x + threadIdx.x;
    if (n >= N_NODES) return;
    int b = batch[n];
    if (n == 0 || batch[n - 1] != b) gstart[b] = n;
    if (n == N_NODES - 1 || batch[n + 1] != b) gend[b] = n + 1;
}

__global__ __launch_bounds__(128) void pool_kernel(const float* __restrict__ X,
                                                   const int* __restrict__ gstart,
                                                   const int* __restrict__ gend,
                                                   const float* __restrict__ pw,
                                                   float* __restrict__ pooled) {
    int g = blockIdx.x;
    int f = threadIdx.x;
    float w0 = pw[0], w1 = pw[1], w2 = pw[2];
    float m = fmaxf(w0, fmaxf(w1, w2));
    float e0 = expf(w0 - m), e1 = expf(w1 - m), e2 = expf(w2 - m);
    float inv = 1.0f / (e0 + e1 + e2);
    e0 *= inv; e1 *= inv; e2 *= inv;
    int s = gstart[g], e = gend[g];
    float sum = 0.f, mx = -INFINITY;
    for (int n = s; n < e; ++n) {
        float v = X[(long)n * HID + f];
        sum += v;
        mx = fmaxf(mx, v);
    }
    int cnt = e - s;
    float mean = cnt > 0 ? sum / (float)cnt : 0.f;
    float mxv = cnt > 0 ? mx : 0.f;
    pooled[g * HID + f] = sum * e0 + mean * e1 + mxv * e2;
}

__global__ __launch_bounds__(128) void head_kernel(const float* __restrict__ pooled,
                                                   const float* __restrict__ fcAw,
                                                   const float* __restrict__ fcAb,
                                                   const float* __restrict__ lng,
                                                   const float* __restrict__ lnb,
                                                   const float* __restrict__ fcBw,
                                                   const float* __restrict__ fcBb,
                                                   float* __restrict__ out) {
    __shared__ float p[HID], q[HID], red[HID];
    int g = blockIdx.x, j = threadIdx.x;
    p[j] = pooled[g * HID + j];
    __syncthreads();
    float acc = fcAb[j];
    for (int k = 0; k < HID; ++k) acc += p[k] * fcAw[k * HID + j];
    red[j] = acc;
    __syncthreads();
    for (int off = 64; off > 0; off >>= 1) {
        if (j < off) red[j] += red[j + off];
        __syncthreads();
    }
    float mean = red[0] * (1.0f / HID);
    __syncthreads();
    float d = acc - mean;
    red[j] = d * d;
    __syncthreads();
    for (int off = 64; off > 0; off >>= 1) {
        if (j < off) red[j] += red[j + off];
        __syncthreads();
    }
    float var = red[0] * (1.0f / HID);
    float y = d * rsqrtf(var + 1e-5f) * lng[j] + lnb[j];
    q[j] = gelu_exact(y) + p[j];
    __syncthreads();
    if (j < LAT) {
        float o = fcBb[j];
        for (int k = 0; k < HID; ++k) o += q[k] * fcBw[k * LAT + j];
        out[g * LAT + j] = o;
    }
}

extern "C" void kernel_launch(void* const* d_in, const int* in_sizes, int n_in,
                              void* d_out, int out_size, void* d_ws, size_t ws_size,
                              hipStream_t stream) {
    const float* x = (const float*)d_in[0];
    const int* ei = (const int*)d_in[1];
    const int* src = ei;
    const int* dst = ei + N_EDGES;
    const int* batch = (const int*)d_in[2];
    const float* ibn_g = (const float*)d_in[3];
    const float* ibn_b = (const float*)d_in[4];
    const float* eps = (const float*)d_in[5];
    const float* fc1w = (const float*)d_in[6];
    const float* fc1b = (const float*)d_in[7];
    const float* bn1g = (const float*)d_in[8];
    const float* bn1b = (const float*)d_in[9];
    const float* fc2w = (const float*)d_in[10];
    const float* fc2b = (const float*)d_in[11];
    const float* bng = (const float*)d_in[12];
    const float* bnb = (const float*)d_in[13];
    const float* att = (const float*)d_in[14];
    const float* pw = (const float*)d_in[15];
    const float* fcAw = (const float*)d_in[16];
    const float* fcAb = (const float*)d_in[17];
    const float* lng = (const float*)d_in[18];
    const float* lnb = (const float*)d_in[19];
    const float* fcBw = (const float*)d_in[20];
    const float* fcBb = (const float*)d_in[21];
    float* out = (float*)d_out;

    const size_t NH = (size_t)N_NODES * HID;
    char* w8 = (char*)d_ws;
    ushort* x0bf = (ushort*)w8;     w8 += NH * 2;
    ushort* hprebf = (ushort*)w8;   w8 += NH * 2;
    ushort* z1bf = (ushort*)w8;     w8 += NH * 2;
    ushort* Hlbf[NL];
    for (int l = 0; l < NL; ++l) { Hlbf[l] = (ushort*)w8; w8 += NH * 2; }
    float* ztmp = (float*)w8;       w8 += NH * 4;
    float* statsAll = (float*)w8;   w8 += (size_t)9 * SSET * 4;  // 9 padded stat sets
    float* pooled = (float*)w8;     w8 += (size_t)N_GRAPHS * HID * 4;
    int* gstart = (int*)w8;         w8 += N_GRAPHS * 4;
    int* gend = (int*)w8;           w8 += N_GRAPHS * 4;
    int* counts = (int*)w8;         w8 += N_NODES * 4;
    int* offs = (int*)w8;           w8 += N_NODES * 4;
    int* cursor = (int*)w8;         w8 += N_NODES * 4;
    int* bsum = (int*)w8;           w8 += 256 * 4;
    int* csr = (int*)w8;            w8 += (size_t)N_EDGES * 4;
    ushort* WtBf = (ushort*)w8;     w8 += (size_t)8 * HID * HID * 2;

    const int rowBlocks = (N_NODES + 63) / 64;   // 782
    const int nodeBlocks = (N_NODES + 255) / 256;
    const int edgeBlocks = (N_EDGES + 255) / 256;
    const int elem4Blocks = (N_NODES * (HID / 4) + 255) / 256;  // 6250

    // weights once
    wt_build<<<512, 256, 0, stream>>>(fc1w, fc2w, WtBf);

    // CSR build
    hipMemsetAsync(counts, 0, N_NODES * sizeof(int), stream);
    csr_count<<<edgeBlocks, 256, 0, stream>>>(dst, counts);
    scan_pass1<<<nodeBlocks, 256, 0, stream>>>(counts, offs, bsum);
    scan_pass2<<<1, 256, 0, stream>>>(bsum, nodeBlocks);
    scan_pass3<<<nodeBlocks, 256, 0, stream>>>(offs, bsum, cursor);
    csr_fill<<<edgeBlocks, 256, 0, stream>>>(src, dst, cursor, csr);

    // zero all padded stat sets once
    hipMemsetAsync(statsAll, 0, (size_t)9 * SSET * sizeof(float), stream);

    // input BN -> bf16 x0
    col_stats<<<256, 256, 0, stream>>>(x, statsAll);
    bn_apply_f32<<<elem4Blocks, 256, 0, stream>>>(x, x0bf, statsAll, ibn_g, ibn_b, 0);

    const ushort* xin = x0bf;
    for (int l = 0; l < NL; ++l) {
        float* st1 = statsAll + (size_t)(1 + 2 * l) * SSET;
        float* st2 = statsAll + (size_t)(2 + 2 * l) * SSET;
        gin_gather_bf<<<(N_NODES + 7) / 8, 256, 0, stream>>>(xin, hprebf, offs, counts,
                                                             csr, eps, l);
        // z1 = hpre @ fc1 + b1 (bf16 out), stats -> st1
        gemm_mfma<<<rowBlocks, 256, 0, stream>>>(hprebf, WtBf + (size_t)l * HID * HID,
                                                 fc1b + l * HID, nullptr, z1bf,
                                                 nullptr, nullptr, nullptr, 0, st1,
                                                 N_NODES);
        // ztmp = gelu(bn1(z1)) @ fc2 + b2 (fp32 out), stats -> st2
        gemm_mfma<<<rowBlocks, 256, 0, stream>>>(z1bf, WtBf + (size_t)(4 + l) * HID * HID,
                                                 fc2b + l * HID, ztmp, nullptr,
                                                 st1, bn1g + l * HID, bn1b + l * HID, 1,
                                                 st2, N_NODES);
        // Hl = bf16(gelu(bn(ztmp)))
        bn_apply_f32<<<elem4Blocks, 256, 0, stream>>>(ztmp, Hlbf[l], st2, bng + l * HID,
                                                      bnb + l * HID, 1);
        xin = Hlbf[l];
    }

    // JK attention -> ztmp (fp32)
    jk_attn_bf<<<(int)(((long)N_NODES * 64 + 255) / 256), 256, 0, stream>>>(
        Hlbf[0], Hlbf[1], Hlbf[2], Hlbf[3], att, ztmp);

    // pooling
    hipMemsetAsync(gstart, 0, 2 * N_GRAPHS * sizeof(int), stream);
    graph_ranges<<<nodeBlocks, 256, 0, stream>>>(batch, gstart, gend);
    pool_kernel<<<N_GRAPHS, 128, 0, stream>>>(ztmp, gstart, gend, pw, pooled);

    // head
    head_kernel<<<N_GRAPHS, 128, 0, stream>>>(pooled, fcAw, fcAb, lng, lnb, fcBw, fcBb, out);
}

// Round 6
// 831.673 us; speedup vs baseline: 1.3018x; 1.0630x over previous
//
#include <hip/hip_runtime.h>
#include <math.h>

#define N_NODES 50000
#define N_EDGES 600000
#define N_GRAPHS 512
#define HID 128
#define LAT 64
#define NL 4
#define SSTR 16        // stats padding: 1 float per 64B cache line
#define SSET 4096      // floats per stat set: 256 entries * 16
#define N_TILES (N_NODES / 16)  // 3125 exact
#define TLD 136        // per-wave LDS C-tile row stride (ushort)

typedef __attribute__((ext_vector_type(8))) __bf16 bf16x8;
typedef __attribute__((ext_vector_type(4))) float f32x4;

union Chunk {
    bf16x8 v;
    uint4 u4;
    ushort us[8];
};

__device__ __forceinline__ float gelu_exact(float x) {
    return 0.5f * x * (1.0f + erff(x * 0.70710678118654752f));
}
__device__ __forceinline__ float bf2f(ushort h) {
    return __uint_as_float(((unsigned int)h) << 16);
}
__device__ __forceinline__ ushort f2bf(float f) {  // RNE
    unsigned int u = __float_as_uint(f);
    unsigned int r = (u + 0x7FFFu + ((u >> 16) & 1u)) >> 16;
    return (ushort)r;
}

// ---------------------------------------------------------------------------
// Weight pre-transpose + bf16: Wt[g][n][k] = W_g[k][n], g=0..3 fc1, 4..7 fc2
// ---------------------------------------------------------------------------
__global__ __launch_bounds__(256) void wt_build(const float* __restrict__ fc1w,
                                                const float* __restrict__ fc2w,
                                                ushort* __restrict__ Wt) {
    int i = blockIdx.x * 256 + threadIdx.x;  // 131072
    if (i >= 8 * HID * HID) return;
    int g = i >> 14;
    int rem = i & 16383;
    int n = rem >> 7, k = rem & 127;
    const float* W = (g < 4) ? (fc1w + (long)g * HID * HID) : (fc2w + (long)(g - 4) * HID * HID);
    Wt[i] = f2bf(W[k * HID + n]);
}

// ---------------------------------------------------------------------------
// Column stats over fp32 X -> padded stats
// ---------------------------------------------------------------------------
__global__ __launch_bounds__(256) void col_stats(const float* __restrict__ X,
                                                 float* __restrict__ stats) {
    __shared__ float sh[2048];
    int t = threadIdx.x;
    int tx = t & 31, ty = t >> 5;
    float s[4] = {0, 0, 0, 0}, q[4] = {0, 0, 0, 0};
    const int nTiles = (N_NODES + 63) / 64;  // 782
    for (int tile = blockIdx.x; tile < nTiles; tile += gridDim.x) {
        int r0 = tile * 64;
#pragma unroll
        for (int i = 0; i < 8; ++i) {
            int r = r0 + ty + 8 * i;
            int rc = min(r, N_NODES - 1);
            float4 v = *(const float4*)(X + (long)rc * HID + 4 * tx);
            float w = (r < N_NODES) ? 1.f : 0.f;
            float x0 = v.x * w, x1 = v.y * w, x2 = v.z * w, x3 = v.w * w;
            s[0] += x0; s[1] += x1; s[2] += x2; s[3] += x3;
            q[0] += x0 * v.x; q[1] += x1 * v.y; q[2] += x2 * v.z; q[3] += x3 * v.w;
        }
    }
#pragma unroll
    for (int c = 0; c < 4; ++c) {
        sh[ty * HID + 4 * tx + c] = s[c];
        sh[1024 + ty * HID + 4 * tx + c] = q[c];
    }
    __syncthreads();
    if (ty == 0) {
#pragma unroll
        for (int c = 0; c < 4; ++c) {
            float a = 0, b = 0;
#pragma unroll
            for (int j = 0; j < 8; ++j) {
                a += sh[j * HID + 4 * tx + c];
                b += sh[1024 + j * HID + 4 * tx + c];
            }
            atomicAdd(stats + (4 * tx + c) * SSTR, a);
            atomicAdd(stats + (HID + 4 * tx + c) * SSTR, b);
        }
    }
}

// ---------------------------------------------------------------------------
// BN apply, fp32 in -> bf16 out (input BN)
// ---------------------------------------------------------------------------
__global__ __launch_bounds__(256) void bn_apply_f32(const float* __restrict__ X,
                                                    ushort* __restrict__ Y,
                                                    const float* __restrict__ stats,
                                                    const float* __restrict__ g,
                                                    const float* __restrict__ b) {
    int i = blockIdx.x * 256 + threadIdx.x;
    if (i >= N_NODES * (HID / 4)) return;
    int c4 = (i & 31) * 4;
    const float invN = 1.0f / (float)N_NODES;
    float4 v = ((const float4*)X)[i];
    float o[4] = {v.x, v.y, v.z, v.w};
#pragma unroll
    for (int j = 0; j < 4; ++j) {
        int c = c4 + j;
        float mean = stats[c * SSTR] * invN;
        float var = stats[(HID + c) * SSTR] * invN - mean * mean;
        float s = g[c] * rsqrtf(var + 1e-5f);
        o[j] = o[j] * s + (b[c] - mean * s);
    }
    ushort4 w;
    w.x = f2bf(o[0]); w.y = f2bf(o[1]); w.z = f2bf(o[2]); w.w = f2bf(o[3]);
    ((ushort4*)Y)[i] = w;
}

// BN + gelu, bf16 in -> bf16 out (8 elems/thread), padded stats
__global__ __launch_bounds__(256) void bn_apply_bf(const ushort* __restrict__ X,
                                                   ushort* __restrict__ Y,
                                                   const float* __restrict__ stats,
                                                   const float* __restrict__ g,
                                                   const float* __restrict__ b) {
    int i = blockIdx.x * 256 + threadIdx.x;
    if (i >= N_NODES * (HID / 8)) return;
    int c8 = (i & 15) * 8;
    const float invN = 1.0f / (float)N_NODES;
    Chunk ch;
    ch.u4 = ((const uint4*)X)[i];
#pragma unroll
    for (int j = 0; j < 8; ++j) {
        int c = c8 + j;
        float mean = stats[c * SSTR] * invN;
        float var = stats[(HID + c) * SSTR] * invN - mean * mean;
        float s = g[c] * rsqrtf(var + 1e-5f);
        float f = bf2f(ch.us[j]) * s + (b[c] - mean * s);
        ch.us[j] = f2bf(gelu_exact(f));
    }
    ((uint4*)Y)[i] = ch.u4;
}

// ---------------------------------------------------------------------------
// CSR build: counting sort of edges by dst
// ---------------------------------------------------------------------------
__global__ __launch_bounds__(256) void csr_count(const int* __restrict__ dst,
                                                 int* __restrict__ counts) {
    int e = blockIdx.x * blockDim.x + threadIdx.x;
    if (e >= N_EDGES) return;
    atomicAdd(counts + dst[e], 1);
}

__global__ __launch_bounds__(256) void scan_pass1(const int* __restrict__ counts,
                                                  int* __restrict__ offs,
                                                  int* __restrict__ bsum) {
    __shared__ int sh[256];
    int t = threadIdx.x;
    int i = blockIdx.x * 256 + t;
    int v = (i < N_NODES) ? counts[i] : 0;
    sh[t] = v;
    __syncthreads();
    for (int off = 1; off < 256; off <<= 1) {
        int a = (t >= off) ? sh[t - off] : 0;
        __syncthreads();
        sh[t] += a;
        __syncthreads();
    }
    if (i < N_NODES) offs[i] = sh[t] - v;
    if (t == 255) bsum[blockIdx.x] = sh[255];
}

__global__ __launch_bounds__(256) void scan_pass2(int* __restrict__ bsum, int nblk) {
    __shared__ int sh[256];
    int t = threadIdx.x;
    int v = (t < nblk) ? bsum[t] : 0;
    sh[t] = v;
    __syncthreads();
    for (int off = 1; off < 256; off <<= 1) {
        int a = (t >= off) ? sh[t - off] : 0;
        __syncthreads();
        sh[t] += a;
        __syncthreads();
    }
    if (t < nblk) bsum[t] = sh[t] - v;
}

__global__ __launch_bounds__(256) void scan_pass3(int* __restrict__ offs,
                                                  const int* __restrict__ bsum,
                                                  int* __restrict__ cursor) {
    int i = blockIdx.x * 256 + threadIdx.x;
    if (i >= N_NODES) return;
    int o = offs[i] + bsum[blockIdx.x];
    offs[i] = o;
    cursor[i] = o;
}

__global__ __launch_bounds__(256) void csr_fill(const int* __restrict__ src,
                                                const int* __restrict__ dst,
                                                int* __restrict__ cursor,
                                                int* __restrict__ csr) {
    int e = blockIdx.x * blockDim.x + threadIdx.x;
    if (e >= N_EDGES) return;
    int pos = atomicAdd(cursor + dst[e], 1);
    csr[pos] = src[e];
}

// ---------------------------------------------------------------------------
// GIN aggregation (bf16): Hp[n] = (1+eps)*X[n] + sum X[nbr]; 4-deep pipelined
// ---------------------------------------------------------------------------
__global__ __launch_bounds__(256) void gin_gather_bf(const ushort* __restrict__ Xbf,
                                                     ushort* __restrict__ Hp,
                                                     const int* __restrict__ offs,
                                                     const int* __restrict__ counts,
                                                     const int* __restrict__ csr,
                                                     const float* __restrict__ eps, int l) {
    int t = threadIdx.x;
    int tx = t & 31;
    int node = blockIdx.x * 8 + (t >> 5);
    if (node >= N_NODES) return;
    float ev = 1.0f + eps[l];
    ushort4 sv = *(const ushort4*)(Xbf + (long)node * HID + 4 * tx);
    float a0 = bf2f(sv.x) * ev, a1 = bf2f(sv.y) * ev, a2 = bf2f(sv.z) * ev, a3 = bf2f(sv.w) * ev;
    int o = offs[node];
    int d = counts[node];
    int k = 0;
    for (; k + 4 <= d; k += 4) {
        int s0 = csr[o + k], s1 = csr[o + k + 1], s2 = csr[o + k + 2], s3 = csr[o + k + 3];
        ushort4 v0 = *(const ushort4*)(Xbf + (long)s0 * HID + 4 * tx);
        ushort4 v1 = *(const ushort4*)(Xbf + (long)s1 * HID + 4 * tx);
        ushort4 v2 = *(const ushort4*)(Xbf + (long)s2 * HID + 4 * tx);
        ushort4 v3 = *(const ushort4*)(Xbf + (long)s3 * HID + 4 * tx);
        a0 += bf2f(v0.x) + bf2f(v1.x) + bf2f(v2.x) + bf2f(v3.x);
        a1 += bf2f(v0.y) + bf2f(v1.y) + bf2f(v2.y) + bf2f(v3.y);
        a2 += bf2f(v0.z) + bf2f(v1.z) + bf2f(v2.z) + bf2f(v3.z);
        a3 += bf2f(v0.w) + bf2f(v1.w) + bf2f(v2.w) + bf2f(v3.w);
    }
    for (; k < d; ++k) {
        int s = csr[o + k];
        ushort4 v = *(const ushort4*)(Xbf + (long)s * HID + 4 * tx);
        a0 += bf2f(v.x); a1 += bf2f(v.y); a2 += bf2f(v.z); a3 += bf2f(v.w);
    }
    ushort4 w;
    w.x = f2bf(a0); w.y = f2bf(a1); w.z = f2bf(a2); w.w = f2bf(a3);
    *(ushort4*)(Hp + (long)node * HID + 4 * tx) = w;
}

// ---------------------------------------------------------------------------
// Persistent MFMA GEMM, B entirely in registers, no barriers in the tile loop.
// C[M,128] = A'[M,128] @ W + bias (bf16 in/out, fp32 accum).
// A' = A, or gelu(A*scale+shift) fused from LDS-cached BN coefficients.
// C stored via per-wave LDS tile -> 4 coalesced dwordx4 wave-stores (1KB each).
// Column sum/sumsq accumulated in registers, one padded-atomic set per block.
// Grid: 512 blocks x 4 waves grid-striding over 3125 16-row tiles.
// ---------------------------------------------------------------------------
__global__ __launch_bounds__(256, 2) void gemm_persist(
    const ushort* __restrict__ Abf, const ushort* __restrict__ Wt,
    const float* __restrict__ bias, ushort* __restrict__ Cbf,
    const float* __restrict__ statsIn, const float* __restrict__ gIn,
    const float* __restrict__ bIn, int applyIn, float* __restrict__ statsOut) {
    __shared__ float scL[HID], sfL[HID];
    __shared__ __align__(16) ushort T[4][16 * TLD];  // per-wave C tile
    __shared__ float shs[1024];
    int t = threadIdx.x;
    if (applyIn && t < HID) {
        const float invN = 1.0f / (float)N_NODES;
        float mean = statsIn[t * SSTR] * invN;
        float var = statsIn[(HID + t) * SSTR] * invN - mean * mean;
        float s = gIn[t] * rsqrtf(var + 1e-5f);
        scL[t] = s;
        sfL[t] = bIn[t] - mean * s;
    }
    __syncthreads();

    int w = t >> 6, lane = t & 63;
    int m = lane & 15, q = lane >> 4;
    ushort* Tw = T[w];

    // B resident in registers: Bfrag[nt][kc] = Wt[nt*16+m][kc*32+q*8 .. +8)
    bf16x8 Bfrag[8][4];
#pragma unroll
    for (int nt = 0; nt < 8; ++nt)
#pragma unroll
        for (int kc = 0; kc < 4; ++kc)
            Bfrag[nt][kc] = *(const bf16x8*)(Wt + (nt * 16 + m) * HID + kc * 32 + q * 8);

    float bias8[8];
#pragma unroll
    for (int nt = 0; nt < 8; ++nt) bias8[nt] = bias[nt * 16 + m];

    float s_col[8], q_col[8];
#pragma unroll
    for (int nt = 0; nt < 8; ++nt) { s_col[nt] = 0.f; q_col[nt] = 0.f; }

    int wid = blockIdx.x * 4 + w;
    int nw = gridDim.x * 4;

    for (int tile = wid; tile < N_TILES; tile += nw) {
        const ushort* arow = Abf + (long)(tile * 16 + m) * HID + q * 8;
        Chunk A4[4];
#pragma unroll
        for (int kc = 0; kc < 4; ++kc) A4[kc].u4 = *(const uint4*)(arow + kc * 32);
        if (applyIn) {
#pragma unroll
            for (int kc = 0; kc < 4; ++kc)
#pragma unroll
                for (int j = 0; j < 8; ++j) {
                    int k = kc * 32 + q * 8 + j;
                    float f = bf2f(A4[kc].us[j]) * scL[k] + sfL[k];
                    A4[kc].us[j] = f2bf(gelu_exact(f));
                }
        }
        f32x4 acc[8];
#pragma unroll
        for (int nt = 0; nt < 8; ++nt) acc[nt] = (f32x4){0.f, 0.f, 0.f, 0.f};
#pragma unroll
        for (int kc = 0; kc < 4; ++kc)
#pragma unroll
            for (int nt = 0; nt < 8; ++nt)
                acc[nt] = __builtin_amdgcn_mfma_f32_16x16x32_bf16(A4[kc].v, Bfrag[nt][kc],
                                                                  acc[nt], 0, 0, 0);
        // write C tile (MFMA layout) into per-wave LDS; stats in registers
#pragma unroll
        for (int nt = 0; nt < 8; ++nt) {
            int col = nt * 16 + m;
#pragma unroll
            for (int r = 0; r < 4; ++r) {
                float z = acc[nt][r] + bias8[nt];
                Tw[(q * 4 + r) * TLD + col] = f2bf(z);
                s_col[nt] += z;
                q_col[nt] += z * z;
            }
        }
        __asm__ volatile("s_waitcnt lgkmcnt(0)" ::: "memory");  // wave-local LDS fence
        // coalesced store: slot i*64+lane covers 1KB contiguous per inst
        long cbase = (long)tile * 16 * HID;
#pragma unroll
        for (int i = 0; i < 4; ++i) {
            int slot = i * 64 + lane;
            int row = slot >> 4, off = slot & 15;
            uint4 vv = *(const uint4*)(Tw + row * TLD + off * 8);
            *(uint4*)(Cbf + cbase + (long)slot * 8) = vv;
        }
    }

    // stats combine: shfl over q, LDS over waves, padded atomics
#pragma unroll
    for (int nt = 0; nt < 8; ++nt) {
        s_col[nt] += __shfl_xor(s_col[nt], 16);
        s_col[nt] += __shfl_xor(s_col[nt], 32);
        q_col[nt] += __shfl_xor(q_col[nt], 16);
        q_col[nt] += __shfl_xor(q_col[nt], 32);
    }
    if (q == 0) {
#pragma unroll
        for (int nt = 0; nt < 8; ++nt) {
            shs[w * HID + nt * 16 + m] = s_col[nt];
            shs[512 + w * HID + nt * 16 + m] = q_col[nt];
        }
    }
    __syncthreads();
    if (t < HID) {
        float a = 0, b = 0;
#pragma unroll
        for (int j = 0; j < 4; ++j) {
            a += shs[j * HID + t];
            b += shs[512 + j * HID + t];
        }
        atomicAdd(statsOut + t * SSTR, a);
        atomicAdd(statsOut + (HID + t) * SSTR, b);
    }
}

// JK attention over 4 layers (bf16 in, fp32 out): one wave per node
__global__ __launch_bounds__(256) void jk_attn_bf(const ushort* __restrict__ H0,
                                                  const ushort* __restrict__ H1,
                                                  const ushort* __restrict__ H2,
                                                  const ushort* __restrict__ H3,
                                                  const float* __restrict__ att,
                                                  float* __restrict__ Y) {
    long gid = (long)blockIdx.x * blockDim.x + threadIdx.x;
    int lane = (int)(gid & 63);
    int node = (int)(gid >> 6);
    if (node >= N_NODES) return;
    const ushort* Hs[4] = {H0, H1, H2, H3};
    float hx[4], hy[4], sc[4];
#pragma unroll
    for (int l = 0; l < 4; ++l) {
        unsigned int u = *(const unsigned int*)(Hs[l] + (long)node * HID + 2 * lane);
        float vx = bf2f((ushort)(u & 0xFFFF));
        float vy = bf2f((ushort)(u >> 16));
        float2 a = *(const float2*)(att + l * HID + 2 * lane);
        hx[l] = vx; hy[l] = vy;
        float p = vx * a.x + vy * a.y;
#pragma unroll
        for (int off = 32; off > 0; off >>= 1) p += __shfl_xor(p, off);
        sc[l] = p * (1.0f / HID);
    }
    float mm = fmaxf(fmaxf(sc[0], sc[1]), fmaxf(sc[2], sc[3]));
    float e[4], se = 0.f;
#pragma unroll
    for (int l = 0; l < 4; ++l) { e[l] = expf(sc[l] - mm); se += e[l]; }
    float inv = 1.0f / se;
    float ox = 0.f, oy = 0.f;
#pragma unroll
    for (int l = 0; l < 4; ++l) {
        float a = e[l] * inv;
        ox += a * hx[l];
        oy += a * hy[l];
    }
    *(float2*)(Y + (long)node * HID + 2 * lane) = make_float2(ox, oy);
}

__global__ void graph_ranges(const int* __restrict__ batch, int* __restrict__ gstart,
                             int* __restrict__ gend) {
    int n = blockIdx.x * blockDim.x + threadIdx.x;
    if (n >= N_NODES) return;
    int b = batch[n];
    if (n == 0 || batch[n - 1] != b) gstart[b] = n;
    if (n == N_NODES - 1 || batch[n + 1] != b) gend[b] = n + 1;
}

__global__ __launch_bounds__(128) void pool_kernel(const float* __restrict__ X,
                                                   const int* __restrict__ gstart,
                                                   const int* __restrict__ gend,
                                                   const float* __restrict__ pw,
                                                   float* __restrict__ pooled) {
    int g = blockIdx.x;
    int f = threadIdx.x;
    float w0 = pw[0], w1 = pw[1], w2 = pw[2];
    float m = fmaxf(w0, fmaxf(w1, w2));
    float e0 = expf(w0 - m), e1 = expf(w1 - m), e2 = expf(w2 - m);
    float inv = 1.0f / (e0 + e1 + e2);
    e0 *= inv; e1 *= inv; e2 *= inv;
    int s = gstart[g], e = gend[g];
    float sum = 0.f, mx = -INFINITY;
    for (int n = s; n < e; ++n) {
        float v = X[(long)n * HID + f];
        sum += v;
        mx = fmaxf(mx, v);
    }
    int cnt = e - s;
    float mean = cnt > 0 ? sum / (float)cnt : 0.f;
    float mxv = cnt > 0 ? mx : 0.f;
    pooled[g * HID + f] = sum * e0 + mean * e1 + mxv * e2;
}

__global__ __launch_bounds__(128) void head_kernel(const float* __restrict__ pooled,
                                                   const float* __restrict__ fcAw,
                                                   const float* __restrict__ fcAb,
                                                   const float* __restrict__ lng,
                                                   const float* __restrict__ lnb,
                                                   const float* __restrict__ fcBw,
                                                   const float* __restrict__ fcBb,
                                                   float* __restrict__ out) {
    __shared__ float p[HID], q[HID], red[HID];
    int g = blockIdx.x, j = threadIdx.x;
    p[j] = pooled[g * HID + j];
    __syncthreads();
    float acc = fcAb[j];
    for (int k = 0; k < HID; ++k) acc += p[k] * fcAw[k * HID + j];
    red[j] = acc;
    __syncthreads();
    for (int off = 64; off > 0; off >>= 1) {
        if (j < off) red[j] += red[j + off];
        __syncthreads();
    }
    float mean = red[0] * (1.0f / HID);
    __syncthreads();
    float d = acc - mean;
    red[j] = d * d;
    __syncthreads();
    for (int off = 64; off > 0; off >>= 1) {
        if (j < off) red[j] += red[j + off];
        __syncthreads();
    }
    float var = red[0] * (1.0f / HID);
    float y = d * rsqrtf(var + 1e-5f) * lng[j] + lnb[j];
    q[j] = gelu_exact(y) + p[j];
    __syncthreads();
    if (j < LAT) {
        float o = fcBb[j];
        for (int k = 0; k < HID; ++k) o += q[k] * fcBw[k * LAT + j];
        out[g * LAT + j] = o;
    }
}

extern "C" void kernel_launch(void* const* d_in, const int* in_sizes, int n_in,
                              void* d_out, int out_size, void* d_ws, size_t ws_size,
                              hipStream_t stream) {
    const float* x = (const float*)d_in[0];
    const int* ei = (const int*)d_in[1];
    const int* src = ei;
    const int* dst = ei + N_EDGES;
    const int* batch = (const int*)d_in[2];
    const float* ibn_g = (const float*)d_in[3];
    const float* ibn_b = (const float*)d_in[4];
    const float* eps = (const float*)d_in[5];
    const float* fc1w = (const float*)d_in[6];
    const float* fc1b = (const float*)d_in[7];
    const float* bn1g = (const float*)d_in[8];
    const float* bn1b = (const float*)d_in[9];
    const float* fc2w = (const float*)d_in[10];
    const float* fc2b = (const float*)d_in[11];
    const float* bng = (const float*)d_in[12];
    const float* bnb = (const float*)d_in[13];
    const float* att = (const float*)d_in[14];
    const float* pw = (const float*)d_in[15];
    const float* fcAw = (const float*)d_in[16];
    const float* fcAb = (const float*)d_in[17];
    const float* lng = (const float*)d_in[18];
    const float* lnb = (const float*)d_in[19];
    const float* fcBw = (const float*)d_in[20];
    const float* fcBb = (const float*)d_in[21];
    float* out = (float*)d_out;

    const size_t NH = (size_t)N_NODES * HID;
    char* w8 = (char*)d_ws;
    ushort* x0bf = (ushort*)w8;     w8 += NH * 2;
    ushort* hprebf = (ushort*)w8;   w8 += NH * 2;  // GEMM1 in; GEMM2 out
    ushort* z1bf = (ushort*)w8;     w8 += NH * 2;  // GEMM1 out / GEMM2 in
    ushort* Hlbf[NL];
    for (int l = 0; l < NL; ++l) { Hlbf[l] = (ushort*)w8; w8 += NH * 2; }
    float* ztmp = (float*)w8;       w8 += NH * 4;
    float* statsAll = (float*)w8;   w8 += (size_t)9 * SSET * 4;
    float* pooled = (float*)w8;     w8 += (size_t)N_GRAPHS * HID * 4;
    int* gstart = (int*)w8;         w8 += N_GRAPHS * 4;
    int* gend = (int*)w8;           w8 += N_GRAPHS * 4;
    int* counts = (int*)w8;         w8 += N_NODES * 4;
    int* offs = (int*)w8;           w8 += N_NODES * 4;
    int* cursor = (int*)w8;         w8 += N_NODES * 4;
    int* bsum = (int*)w8;           w8 += 256 * 4;
    int* csr = (int*)w8;            w8 += (size_t)N_EDGES * 4;
    ushort* WtBf = (ushort*)w8;     w8 += (size_t)8 * HID * HID * 2;

    const int nodeBlocks = (N_NODES + 255) / 256;
    const int edgeBlocks = (N_EDGES + 255) / 256;
    const int elem4Blocks = (N_NODES * (HID / 4) + 255) / 256;  // 6250
    const int elem8Blocks = (N_NODES * (HID / 8) + 255) / 256;  // 3125

    // weights once
    wt_build<<<512, 256, 0, stream>>>(fc1w, fc2w, WtBf);

    // CSR build
    hipMemsetAsync(counts, 0, N_NODES * sizeof(int), stream);
    csr_count<<<edgeBlocks, 256, 0, stream>>>(dst, counts);
    scan_pass1<<<nodeBlocks, 256, 0, stream>>>(counts, offs, bsum);
    scan_pass2<<<1, 256, 0, stream>>>(bsum, nodeBlocks);
    scan_pass3<<<nodeBlocks, 256, 0, stream>>>(offs, bsum, cursor);
    csr_fill<<<edgeBlocks, 256, 0, stream>>>(src, dst, cursor, csr);

    // zero all padded stat sets once
    hipMemsetAsync(statsAll, 0, (size_t)9 * SSET * sizeof(float), stream);

    // input BN -> bf16 x0
    col_stats<<<256, 256, 0, stream>>>(x, statsAll);
    bn_apply_f32<<<elem4Blocks, 256, 0, stream>>>(x, x0bf, statsAll, ibn_g, ibn_b);

    const ushort* xin = x0bf;
    for (int l = 0; l < NL; ++l) {
        float* st1 = statsAll + (size_t)(1 + 2 * l) * SSET;
        float* st2 = statsAll + (size_t)(2 + 2 * l) * SSET;
        gin_gather_bf<<<(N_NODES + 7) / 8, 256, 0, stream>>>(xin, hprebf, offs, counts,
                                                             csr, eps, l);
        // z1 = hpre @ fc1 + b1, stats -> st1
        gemm_persist<<<512, 256, 0, stream>>>(hprebf, WtBf + (size_t)l * HID * HID,
                                              fc1b + l * HID, z1bf,
                                              nullptr, nullptr, nullptr, 0, st1);
        // z2 = gelu(bn1(z1)) @ fc2 + b2 -> hprebf (reuse), stats -> st2
        gemm_persist<<<512, 256, 0, stream>>>(z1bf, WtBf + (size_t)(4 + l) * HID * HID,
                                              fc2b + l * HID, hprebf,
                                              st1, bn1g + l * HID, bn1b + l * HID, 1, st2);
        // Hl = bf16(gelu(bn(z2)))
        bn_apply_bf<<<elem8Blocks, 256, 0, stream>>>(hprebf, Hlbf[l], st2, bng + l * HID,
                                                     bnb + l * HID);
        xin = Hlbf[l];
    }

    // JK attention -> ztmp (fp32)
    jk_attn_bf<<<(int)(((long)N_NODES * 64 + 255) / 256), 256, 0, stream>>>(
        Hlbf[0], Hlbf[1], Hlbf[2], Hlbf[3], att, ztmp);

    // pooling
    hipMemsetAsync(gstart, 0, 2 * N_GRAPHS * sizeof(int), stream);
    graph_ranges<<<nodeBlocks, 256, 0, stream>>>(batch, gstart, gend);
    pool_kernel<<<N_GRAPHS, 128, 0, stream>>>(ztmp, gstart, gend, pw, pooled);

    // head
    head_kernel<<<N_GRAPHS, 128, 0, stream>>>(pooled, fcAw, fcAb, lng, lnb, fcBw, fcBb, out);
}

// Round 7
// 617.720 us; speedup vs baseline: 1.7527x; 1.3464x over previous
//
#include <hip/hip_runtime.h>
#include <math.h>

#define N_NODES 50000
#define N_EDGES 600000
#define N_GRAPHS 512
#define HID 128
#define LAT 64
#define NL 4
#define SSTR 16        // stats padding: 1 float per 64B cache line
#define SSET 4096      // floats per stat set: 256 entries * 16
#define N_TILES (N_NODES / 16)  // 3125 exact
#define TLD 136        // per-wave LDS C-tile row stride (ushort)

typedef __attribute__((ext_vector_type(8))) __bf16 bf16x8;
typedef __attribute__((ext_vector_type(4))) float f32x4;

union Chunk {
    bf16x8 v;
    uint4 u4;
    ushort us[8];
};

__device__ __forceinline__ float gelu_exact(float x) {
    return 0.5f * x * (1.0f + erff(x * 0.70710678118654752f));
}
// Branchless gelu via A&S 7.1.26 erf poly (|err| <= 1.5e-7) + fast exp/rcp.
__device__ __forceinline__ float gelu_fast(float x) {
    float ax = fabsf(x) * 0.70710678118654752f;
    float t = __builtin_amdgcn_rcpf(fmaf(0.3275911f, ax, 1.0f));
    float p = t * (0.254829592f +
              t * (-0.284496736f +
              t * (1.421413741f +
              t * (-1.453152027f + t * 1.061405429f))));
    float e = __expf(-ax * ax);
    float erfv = 1.0f - p * e;           // erf(|x|/sqrt2) >= 0
    float erfs = copysignf(erfv, x);
    return 0.5f * x * (1.0f + erfs);
}
__device__ __forceinline__ float bf2f(ushort h) {
    return __uint_as_float(((unsigned int)h) << 16);
}
__device__ __forceinline__ ushort f2bf(float f) {  // RNE
    unsigned int u = __float_as_uint(f);
    unsigned int r = (u + 0x7FFFu + ((u >> 16) & 1u)) >> 16;
    return (ushort)r;
}

// ---------------------------------------------------------------------------
// Weight pre-transpose + bf16: Wt[g][n][k] = W_g[k][n], g=0..3 fc1, 4..7 fc2
// ---------------------------------------------------------------------------
__global__ __launch_bounds__(256) void wt_build(const float* __restrict__ fc1w,
                                                const float* __restrict__ fc2w,
                                                ushort* __restrict__ Wt) {
    int i = blockIdx.x * 256 + threadIdx.x;  // 131072
    if (i >= 8 * HID * HID) return;
    int g = i >> 14;
    int rem = i & 16383;
    int n = rem >> 7, k = rem & 127;
    const float* W = (g < 4) ? (fc1w + (long)g * HID * HID) : (fc2w + (long)(g - 4) * HID * HID);
    Wt[i] = f2bf(W[k * HID + n]);
}

// ---------------------------------------------------------------------------
// Column stats over fp32 X -> padded stats
// ---------------------------------------------------------------------------
__global__ __launch_bounds__(256) void col_stats(const float* __restrict__ X,
                                                 float* __restrict__ stats) {
    __shared__ float sh[2048];
    int t = threadIdx.x;
    int tx = t & 31, ty = t >> 5;
    float s[4] = {0, 0, 0, 0}, q[4] = {0, 0, 0, 0};
    const int nTiles = (N_NODES + 63) / 64;  // 782
    for (int tile = blockIdx.x; tile < nTiles; tile += gridDim.x) {
        int r0 = tile * 64;
#pragma unroll
        for (int i = 0; i < 8; ++i) {
            int r = r0 + ty + 8 * i;
            int rc = min(r, N_NODES - 1);
            float4 v = *(const float4*)(X + (long)rc * HID + 4 * tx);
            float w = (r < N_NODES) ? 1.f : 0.f;
            float x0 = v.x * w, x1 = v.y * w, x2 = v.z * w, x3 = v.w * w;
            s[0] += x0; s[1] += x1; s[2] += x2; s[3] += x3;
            q[0] += x0 * v.x; q[1] += x1 * v.y; q[2] += x2 * v.z; q[3] += x3 * v.w;
        }
    }
#pragma unroll
    for (int c = 0; c < 4; ++c) {
        sh[ty * HID + 4 * tx + c] = s[c];
        sh[1024 + ty * HID + 4 * tx + c] = q[c];
    }
    __syncthreads();
    if (ty == 0) {
#pragma unroll
        for (int c = 0; c < 4; ++c) {
            float a = 0, b = 0;
#pragma unroll
            for (int j = 0; j < 8; ++j) {
                a += sh[j * HID + 4 * tx + c];
                b += sh[1024 + j * HID + 4 * tx + c];
            }
            atomicAdd(stats + (4 * tx + c) * SSTR, a);
            atomicAdd(stats + (HID + 4 * tx + c) * SSTR, b);
        }
    }
}

// ---------------------------------------------------------------------------
// BN apply, fp32 in -> bf16 out (input BN, no gelu). Scale/shift from LDS.
// Block handles 1024 consecutive float4 chunks (thread t does k*256+t, k<4)
// => channel quad (t&31)*4 is constant per thread.
// ---------------------------------------------------------------------------
__global__ __launch_bounds__(256) void bn_apply_f32(const float* __restrict__ X,
                                                    ushort* __restrict__ Y,
                                                    const float* __restrict__ stats,
                                                    const float* __restrict__ g,
                                                    const float* __restrict__ b) {
    __shared__ float scL[HID], sfL[HID];
    int t = threadIdx.x;
    if (t < HID) {
        const float invN = 1.0f / (float)N_NODES;
        float mean = stats[t * SSTR] * invN;
        float var = stats[(HID + t) * SSTR] * invN - mean * mean;
        float s = g[t] * rsqrtf(var + 1e-5f);
        scL[t] = s;
        sfL[t] = b[t] - mean * s;
    }
    __syncthreads();
    int c4 = (t & 31) * 4;
    float sc[4], sf[4];
#pragma unroll
    for (int j = 0; j < 4; ++j) { sc[j] = scL[c4 + j]; sf[j] = sfL[c4 + j]; }
    const int NC = N_NODES * (HID / 4);  // 1.6M float4
    int base = blockIdx.x * 1024 + t;
#pragma unroll
    for (int k = 0; k < 4; ++k) {
        int i = base + k * 256;
        if (i < NC) {
            float4 v = ((const float4*)X)[i];
            ushort4 w;
            w.x = f2bf(v.x * sc[0] + sf[0]);
            w.y = f2bf(v.y * sc[1] + sf[1]);
            w.z = f2bf(v.z * sc[2] + sf[2]);
            w.w = f2bf(v.w * sc[3] + sf[3]);
            ((ushort4*)Y)[i] = w;
        }
    }
}

// BN + gelu, bf16 in -> bf16 out. Scale/shift from LDS; fast gelu; 4 uint4/thread.
__global__ __launch_bounds__(256) void bn_apply_bf(const ushort* __restrict__ X,
                                                   ushort* __restrict__ Y,
                                                   const float* __restrict__ stats,
                                                   const float* __restrict__ g,
                                                   const float* __restrict__ b) {
    __shared__ float scL[HID], sfL[HID];
    int t = threadIdx.x;
    if (t < HID) {
        const float invN = 1.0f / (float)N_NODES;
        float mean = stats[t * SSTR] * invN;
        float var = stats[(HID + t) * SSTR] * invN - mean * mean;
        float s = g[t] * rsqrtf(var + 1e-5f);
        scL[t] = s;
        sfL[t] = b[t] - mean * s;
    }
    __syncthreads();
    int c8 = (t & 15) * 8;
    float sc[8], sf[8];
#pragma unroll
    for (int j = 0; j < 8; ++j) { sc[j] = scL[c8 + j]; sf[j] = sfL[c8 + j]; }
    const int NC = N_NODES * (HID / 8);  // 800000 uint4
    int base = blockIdx.x * 1024 + t;
#pragma unroll
    for (int k = 0; k < 4; ++k) {
        int i = base + k * 256;
        if (i < NC) {
            Chunk ch;
            ch.u4 = ((const uint4*)X)[i];
#pragma unroll
            for (int j = 0; j < 8; ++j) {
                float f = bf2f(ch.us[j]) * sc[j] + sf[j];
                ch.us[j] = f2bf(gelu_fast(f));
            }
            ((uint4*)Y)[i] = ch.u4;
        }
    }
}

// ---------------------------------------------------------------------------
// CSR build: counting sort of edges by dst
// ---------------------------------------------------------------------------
__global__ __launch_bounds__(256) void csr_count(const int* __restrict__ dst,
                                                 int* __restrict__ counts) {
    int e = blockIdx.x * blockDim.x + threadIdx.x;
    if (e >= N_EDGES) return;
    atomicAdd(counts + dst[e], 1);
}

__global__ __launch_bounds__(256) void scan_pass1(const int* __restrict__ counts,
                                                  int* __restrict__ offs,
                                                  int* __restrict__ bsum) {
    __shared__ int sh[256];
    int t = threadIdx.x;
    int i = blockIdx.x * 256 + t;
    int v = (i < N_NODES) ? counts[i] : 0;
    sh[t] = v;
    __syncthreads();
    for (int off = 1; off < 256; off <<= 1) {
        int a = (t >= off) ? sh[t - off] : 0;
        __syncthreads();
        sh[t] += a;
        __syncthreads();
    }
    if (i < N_NODES) offs[i] = sh[t] - v;
    if (t == 255) bsum[blockIdx.x] = sh[255];
}

__global__ __launch_bounds__(256) void scan_pass2(int* __restrict__ bsum, int nblk) {
    __shared__ int sh[256];
    int t = threadIdx.x;
    int v = (t < nblk) ? bsum[t] : 0;
    sh[t] = v;
    __syncthreads();
    for (int off = 1; off < 256; off <<= 1) {
        int a = (t >= off) ? sh[t - off] : 0;
        __syncthreads();
        sh[t] += a;
        __syncthreads();
    }
    if (t < nblk) bsum[t] = sh[t] - v;
}

__global__ __launch_bounds__(256) void scan_pass3(int* __restrict__ offs,
                                                  const int* __restrict__ bsum,
                                                  int* __restrict__ cursor) {
    int i = blockIdx.x * 256 + threadIdx.x;
    if (i >= N_NODES) return;
    int o = offs[i] + bsum[blockIdx.x];
    offs[i] = o;
    cursor[i] = o;
}

__global__ __launch_bounds__(256) void csr_fill(const int* __restrict__ src,
                                                const int* __restrict__ dst,
                                                int* __restrict__ cursor,
                                                int* __restrict__ csr) {
    int e = blockIdx.x * blockDim.x + threadIdx.x;
    if (e >= N_EDGES) return;
    int pos = atomicAdd(cursor + dst[e], 1);
    csr[pos] = src[e];
}

// ---------------------------------------------------------------------------
// GIN aggregation (bf16): Hp[n] = (1+eps)*X[n] + sum X[nbr]; 8-deep pipelined
// ---------------------------------------------------------------------------
__global__ __launch_bounds__(256) void gin_gather_bf(const ushort* __restrict__ Xbf,
                                                     ushort* __restrict__ Hp,
                                                     const int* __restrict__ offs,
                                                     const int* __restrict__ counts,
                                                     const int* __restrict__ csr,
                                                     const float* __restrict__ eps, int l) {
    int t = threadIdx.x;
    int tx = t & 31;
    int node = blockIdx.x * 8 + (t >> 5);
    if (node >= N_NODES) return;
    float ev = 1.0f + eps[l];
    ushort4 sv = *(const ushort4*)(Xbf + (long)node * HID + 4 * tx);
    float a0 = bf2f(sv.x) * ev, a1 = bf2f(sv.y) * ev, a2 = bf2f(sv.z) * ev, a3 = bf2f(sv.w) * ev;
    int o = offs[node];
    int d = counts[node];
    int k = 0;
    for (; k + 8 <= d; k += 8) {
        int si[8];
#pragma unroll
        for (int j = 0; j < 8; ++j) si[j] = csr[o + k + j];
        ushort4 v[8];
#pragma unroll
        for (int j = 0; j < 8; ++j)
            v[j] = *(const ushort4*)(Xbf + (long)si[j] * HID + 4 * tx);
#pragma unroll
        for (int j = 0; j < 8; ++j) {
            a0 += bf2f(v[j].x); a1 += bf2f(v[j].y);
            a2 += bf2f(v[j].z); a3 += bf2f(v[j].w);
        }
    }
    for (; k + 4 <= d; k += 4) {
        int si[4];
#pragma unroll
        for (int j = 0; j < 4; ++j) si[j] = csr[o + k + j];
#pragma unroll
        for (int j = 0; j < 4; ++j) {
            ushort4 v = *(const ushort4*)(Xbf + (long)si[j] * HID + 4 * tx);
            a0 += bf2f(v.x); a1 += bf2f(v.y); a2 += bf2f(v.z); a3 += bf2f(v.w);
        }
    }
    for (; k < d; ++k) {
        int s = csr[o + k];
        ushort4 v = *(const ushort4*)(Xbf + (long)s * HID + 4 * tx);
        a0 += bf2f(v.x); a1 += bf2f(v.y); a2 += bf2f(v.z); a3 += bf2f(v.w);
    }
    ushort4 w;
    w.x = f2bf(a0); w.y = f2bf(a1); w.z = f2bf(a2); w.w = f2bf(a3);
    *(ushort4*)(Hp + (long)node * HID + 4 * tx) = w;
}

// ---------------------------------------------------------------------------
// Persistent MFMA GEMM, B in registers, next-tile A prefetch, no barriers in
// the tile loop. C stored via per-wave LDS tile -> coalesced dwordx4 stores.
// ---------------------------------------------------------------------------
__global__ __launch_bounds__(256, 2) void gemm_persist(
    const ushort* __restrict__ Abf, const ushort* __restrict__ Wt,
    const float* __restrict__ bias, ushort* __restrict__ Cbf,
    const float* __restrict__ statsIn, const float* __restrict__ gIn,
    const float* __restrict__ bIn, int applyIn, float* __restrict__ statsOut) {
    __shared__ float scL[HID], sfL[HID];
    __shared__ __align__(16) ushort T[4][16 * TLD];
    __shared__ float shs[1024];
    int t = threadIdx.x;
    if (applyIn && t < HID) {
        const float invN = 1.0f / (float)N_NODES;
        float mean = statsIn[t * SSTR] * invN;
        float var = statsIn[(HID + t) * SSTR] * invN - mean * mean;
        float s = gIn[t] * rsqrtf(var + 1e-5f);
        scL[t] = s;
        sfL[t] = bIn[t] - mean * s;
    }
    __syncthreads();

    int w = t >> 6, lane = t & 63;
    int m = lane & 15, q = lane >> 4;
    ushort* Tw = T[w];

    bf16x8 Bfrag[8][4];
#pragma unroll
    for (int nt = 0; nt < 8; ++nt)
#pragma unroll
        for (int kc = 0; kc < 4; ++kc)
            Bfrag[nt][kc] = *(const bf16x8*)(Wt + (nt * 16 + m) * HID + kc * 32 + q * 8);

    float bias8[8];
#pragma unroll
    for (int nt = 0; nt < 8; ++nt) bias8[nt] = bias[nt * 16 + m];

    float s_col[8], q_col[8];
#pragma unroll
    for (int nt = 0; nt < 8; ++nt) { s_col[nt] = 0.f; q_col[nt] = 0.f; }

    int wid = blockIdx.x * 4 + w;
    int nw = gridDim.x * 4;

    int tile = wid;
    Chunk Acur[4];
    if (tile < N_TILES) {
        const ushort* arow = Abf + (long)(tile * 16 + m) * HID + q * 8;
#pragma unroll
        for (int kc = 0; kc < 4; ++kc) Acur[kc].u4 = *(const uint4*)(arow + kc * 32);
    }
    while (tile < N_TILES) {
        int nxt = tile + nw;
        Chunk Anxt[4];
        if (nxt < N_TILES) {  // prefetch next tile's A before computing
            const ushort* arow = Abf + (long)(nxt * 16 + m) * HID + q * 8;
#pragma unroll
            for (int kc = 0; kc < 4; ++kc) Anxt[kc].u4 = *(const uint4*)(arow + kc * 32);
        }
        if (applyIn) {
#pragma unroll
            for (int kc = 0; kc < 4; ++kc)
#pragma unroll
                for (int j = 0; j < 8; ++j) {
                    int k = kc * 32 + q * 8 + j;
                    float f = bf2f(Acur[kc].us[j]) * scL[k] + sfL[k];
                    Acur[kc].us[j] = f2bf(gelu_fast(f));
                }
        }
        f32x4 acc[8];
#pragma unroll
        for (int nt = 0; nt < 8; ++nt) acc[nt] = (f32x4){0.f, 0.f, 0.f, 0.f};
#pragma unroll
        for (int kc = 0; kc < 4; ++kc)
#pragma unroll
            for (int nt = 0; nt < 8; ++nt)
                acc[nt] = __builtin_amdgcn_mfma_f32_16x16x32_bf16(Acur[kc].v, Bfrag[nt][kc],
                                                                  acc[nt], 0, 0, 0);
#pragma unroll
        for (int nt = 0; nt < 8; ++nt) {
            int col = nt * 16 + m;
#pragma unroll
            for (int r = 0; r < 4; ++r) {
                float z = acc[nt][r] + bias8[nt];
                Tw[(q * 4 + r) * TLD + col] = f2bf(z);
                s_col[nt] += z;
                q_col[nt] += z * z;
            }
        }
        __asm__ volatile("s_waitcnt lgkmcnt(0)" ::: "memory");
        long cbase = (long)tile * 16 * HID;
#pragma unroll
        for (int i = 0; i < 4; ++i) {
            int slot = i * 64 + lane;
            int row = slot >> 4, off = slot & 15;
            uint4 vv = *(const uint4*)(Tw + row * TLD + off * 8);
            *(uint4*)(Cbf + cbase + (long)slot * 8) = vv;
        }
        tile = nxt;
#pragma unroll
        for (int kc = 0; kc < 4; ++kc) Acur[kc] = Anxt[kc];
    }

#pragma unroll
    for (int nt = 0; nt < 8; ++nt) {
        s_col[nt] += __shfl_xor(s_col[nt], 16);
        s_col[nt] += __shfl_xor(s_col[nt], 32);
        q_col[nt] += __shfl_xor(q_col[nt], 16);
        q_col[nt] += __shfl_xor(q_col[nt], 32);
    }
    if (q == 0) {
#pragma unroll
        for (int nt = 0; nt < 8; ++nt) {
            shs[w * HID + nt * 16 + m] = s_col[nt];
            shs[512 + w * HID + nt * 16 + m] = q_col[nt];
        }
    }
    __syncthreads();
    if (t < HID) {
        float a = 0, b = 0;
#pragma unroll
        for (int j = 0; j < 4; ++j) {
            a += shs[j * HID + t];
            b += shs[512 + j * HID + t];
        }
        atomicAdd(statsOut + t * SSTR, a);
        atomicAdd(statsOut + (HID + t) * SSTR, b);
    }
}

// JK attention over 4 layers (bf16 in, fp32 out): one wave per node
__global__ __launch_bounds__(256) void jk_attn_bf(const ushort* __restrict__ H0,
                                                  const ushort* __restrict__ H1,
                                                  const ushort* __restrict__ H2,
                                                  const ushort* __restrict__ H3,
                                                  const float* __restrict__ att,
                                                  float* __restrict__ Y) {
    long gid = (long)blockIdx.x * blockDim.x + threadIdx.x;
    int lane = (int)(gid & 63);
    int node = (int)(gid >> 6);
    if (node >= N_NODES) return;
    const ushort* Hs[4] = {H0, H1, H2, H3};
    float hx[4], hy[4], sc[4];
#pragma unroll
    for (int l = 0; l < 4; ++l) {
        unsigned int u = *(const unsigned int*)(Hs[l] + (long)node * HID + 2 * lane);
        float vx = bf2f((ushort)(u & 0xFFFF));
        float vy = bf2f((ushort)(u >> 16));
        float2 a = *(const float2*)(att + l * HID + 2 * lane);
        hx[l] = vx; hy[l] = vy;
        float p = vx * a.x + vy * a.y;
#pragma unroll
        for (int off = 32; off > 0; off >>= 1) p += __shfl_xor(p, off);
        sc[l] = p * (1.0f / HID);
    }
    float mm = fmaxf(fmaxf(sc[0], sc[1]), fmaxf(sc[2], sc[3]));
    float e[4], se = 0.f;
#pragma unroll
    for (int l = 0; l < 4; ++l) { e[l] = expf(sc[l] - mm); se += e[l]; }
    float inv = 1.0f / se;
    float ox = 0.f, oy = 0.f;
#pragma unroll
    for (int l = 0; l < 4; ++l) {
        float a = e[l] * inv;
        ox += a * hx[l];
        oy += a * hy[l];
    }
    *(float2*)(Y + (long)node * HID + 2 * lane) = make_float2(ox, oy);
}

__global__ void graph_ranges(const int* __restrict__ batch, int* __restrict__ gstart,
                             int* __restrict__ gend) {
    int n = blockIdx.x * blockDim.x + threadIdx.x;
    if (n >= N_NODES) return;
    int b = batch[n];
    if (n == 0 || batch[n - 1] != b) gstart[b] = n;
    if (n == N_NODES - 1 || batch[n + 1] != b) gend[b] = n + 1;
}

__global__ __launch_bounds__(128) void pool_kernel(const float* __restrict__ X,
                                                   const int* __restrict__ gstart,
                                                   const int* __restrict__ gend,
                                                   const float* __restrict__ pw,
                                                   float* __restrict__ pooled) {
    int g = blockIdx.x;
    int f = threadIdx.x;
    float w0 = pw[0], w1 = pw[1], w2 = pw[2];
    float m = fmaxf(w0, fmaxf(w1, w2));
    float e0 = expf(w0 - m), e1 = expf(w1 - m), e2 = expf(w2 - m);
    float inv = 1.0f / (e0 + e1 + e2);
    e0 *= inv; e1 *= inv; e2 *= inv;
    int s = gstart[g], e = gend[g];
    float sum = 0.f, mx = -INFINITY;
    for (int n = s; n < e; ++n) {
        float v = X[(long)n * HID + f];
        sum += v;
        mx = fmaxf(mx, v);
    }
    int cnt = e - s;
    float mean = cnt > 0 ? sum / (float)cnt : 0.f;
    float mxv = cnt > 0 ? mx : 0.f;
    pooled[g * HID + f] = sum * e0 + mean * e1 + mxv * e2;
}

__global__ __launch_bounds__(128) void head_kernel(const float* __restrict__ pooled,
                                                   const float* __restrict__ fcAw,
                                                   const float* __restrict__ fcAb,
                                                   const float* __restrict__ lng,
                                                   const float* __restrict__ lnb,
                                                   const float* __restrict__ fcBw,
                                                   const float* __restrict__ fcBb,
                                                   float* __restrict__ out) {
    __shared__ float p[HID], q[HID], red[HID];
    int g = blockIdx.x, j = threadIdx.x;
    p[j] = pooled[g * HID + j];
    __syncthreads();
    float acc = fcAb[j];
    for (int k = 0; k < HID; ++k) acc += p[k] * fcAw[k * HID + j];
    red[j] = acc;
    __syncthreads();
    for (int off = 64; off > 0; off >>= 1) {
        if (j < off) red[j] += red[j + off];
        __syncthreads();
    }
    float mean = red[0] * (1.0f / HID);
    __syncthreads();
    float d = acc - mean;
    red[j] = d * d;
    __syncthreads();
    for (int off = 64; off > 0; off >>= 1) {
        if (j < off) red[j] += red[j + off];
        __syncthreads();
    }
    float var = red[0] * (1.0f / HID);
    float y = d * rsqrtf(var + 1e-5f) * lng[j] + lnb[j];
    q[j] = gelu_exact(y) + p[j];
    __syncthreads();
    if (j < LAT) {
        float o = fcBb[j];
        for (int k = 0; k < HID; ++k) o += q[k] * fcBw[k * LAT + j];
        out[g * LAT + j] = o;
    }
}

extern "C" void kernel_launch(void* const* d_in, const int* in_sizes, int n_in,
                              void* d_out, int out_size, void* d_ws, size_t ws_size,
                              hipStream_t stream) {
    const float* x = (const float*)d_in[0];
    const int* ei = (const int*)d_in[1];
    const int* src = ei;
    const int* dst = ei + N_EDGES;
    const int* batch = (const int*)d_in[2];
    const float* ibn_g = (const float*)d_in[3];
    const float* ibn_b = (const float*)d_in[4];
    const float* eps = (const float*)d_in[5];
    const float* fc1w = (const float*)d_in[6];
    const float* fc1b = (const float*)d_in[7];
    const float* bn1g = (const float*)d_in[8];
    const float* bn1b = (const float*)d_in[9];
    const float* fc2w = (const float*)d_in[10];
    const float* fc2b = (const float*)d_in[11];
    const float* bng = (const float*)d_in[12];
    const float* bnb = (const float*)d_in[13];
    const float* att = (const float*)d_in[14];
    const float* pw = (const float*)d_in[15];
    const float* fcAw = (const float*)d_in[16];
    const float* fcAb = (const float*)d_in[17];
    const float* lng = (const float*)d_in[18];
    const float* lnb = (const float*)d_in[19];
    const float* fcBw = (const float*)d_in[20];
    const float* fcBb = (const float*)d_in[21];
    float* out = (float*)d_out;

    const size_t NH = (size_t)N_NODES * HID;
    char* w8 = (char*)d_ws;
    ushort* x0bf = (ushort*)w8;     w8 += NH * 2;
    ushort* hprebf = (ushort*)w8;   w8 += NH * 2;  // GEMM1 in; GEMM2 out
    ushort* z1bf = (ushort*)w8;     w8 += NH * 2;  // GEMM1 out / GEMM2 in
    ushort* Hlbf[NL];
    for (int l = 0; l < NL; ++l) { Hlbf[l] = (ushort*)w8; w8 += NH * 2; }
    float* ztmp = (float*)w8;       w8 += NH * 4;
    float* statsAll = (float*)w8;   w8 += (size_t)9 * SSET * 4;
    float* pooled = (float*)w8;     w8 += (size_t)N_GRAPHS * HID * 4;
    int* gstart = (int*)w8;         w8 += N_GRAPHS * 4;
    int* gend = (int*)w8;           w8 += N_GRAPHS * 4;
    int* counts = (int*)w8;         w8 += N_NODES * 4;
    int* offs = (int*)w8;           w8 += N_NODES * 4;
    int* cursor = (int*)w8;         w8 += N_NODES * 4;
    int* bsum = (int*)w8;           w8 += 256 * 4;
    int* csr = (int*)w8;            w8 += (size_t)N_EDGES * 4;
    ushort* WtBf = (ushort*)w8;     w8 += (size_t)8 * HID * HID * 2;

    const int nodeBlocks = (N_NODES + 255) / 256;
    const int edgeBlocks = (N_EDGES + 255) / 256;
    const int bnBfBlocks = (N_NODES * (HID / 8) + 1023) / 1024;   // 782
    const int bnF32Blocks = (N_NODES * (HID / 4) + 1023) / 1024;  // 1563

    // weights once
    wt_build<<<512, 256, 0, stream>>>(fc1w, fc2w, WtBf);

    // CSR build
    hipMemsetAsync(counts, 0, N_NODES * sizeof(int), stream);
    csr_count<<<edgeBlocks, 256, 0, stream>>>(dst, counts);
    scan_pass1<<<nodeBlocks, 256, 0, stream>>>(counts, offs, bsum);
    scan_pass2<<<1, 256, 0, stream>>>(bsum, nodeBlocks);
    scan_pass3<<<nodeBlocks, 256, 0, stream>>>(offs, bsum, cursor);
    csr_fill<<<edgeBlocks, 256, 0, stream>>>(src, dst, cursor, csr);

    // zero all padded stat sets once
    hipMemsetAsync(statsAll, 0, (size_t)9 * SSET * sizeof(float), stream);

    // input BN -> bf16 x0
    col_stats<<<256, 256, 0, stream>>>(x, statsAll);
    bn_apply_f32<<<bnF32Blocks, 256, 0, stream>>>(x, x0bf, statsAll, ibn_g, ibn_b);

    const ushort* xin = x0bf;
    for (int l = 0; l < NL; ++l) {
        float* st1 = statsAll + (size_t)(1 + 2 * l) * SSET;
        float* st2 = statsAll + (size_t)(2 + 2 * l) * SSET;
        gin_gather_bf<<<(N_NODES + 7) / 8, 256, 0, stream>>>(xin, hprebf, offs, counts,
                                                             csr, eps, l);
        gemm_persist<<<512, 256, 0, stream>>>(hprebf, WtBf + (size_t)l * HID * HID,
                                              fc1b + l * HID, z1bf,
                                              nullptr, nullptr, nullptr, 0, st1);
        gemm_persist<<<512, 256, 0, stream>>>(z1bf, WtBf + (size_t)(4 + l) * HID * HID,
                                              fc2b + l * HID, hprebf,
                                              st1, bn1g + l * HID, bn1b + l * HID, 1, st2);
        bn_apply_bf<<<bnBfBlocks, 256, 0, stream>>>(hprebf, Hlbf[l], st2, bng + l * HID,
                                                    bnb + l * HID);
        xin = Hlbf[l];
    }

    // JK attention -> ztmp (fp32)
    jk_attn_bf<<<(int)(((long)N_NODES * 64 + 255) / 256), 256, 0, stream>>>(
        Hlbf[0], Hlbf[1], Hlbf[2], Hlbf[3], att, ztmp);

    // pooling
    hipMemsetAsync(gstart, 0, 2 * N_GRAPHS * sizeof(int), stream);
    graph_ranges<<<nodeBlocks, 256, 0, stream>>>(batch, gstart, gend);
    pool_kernel<<<N_GRAPHS, 128, 0, stream>>>(ztmp, gstart, gend, pw, pooled);

    // head
    head_kernel<<<N_GRAPHS, 128, 0, stream>>>(pooled, fcAw, fcAb, lng, lnb, fcBw, fcBb, out);
}

// Round 8
// 602.182 us; speedup vs baseline: 1.7979x; 1.0258x over previous
//
#include <hip/hip_runtime.h>
#include <math.h>

#define N_NODES 50000
#define N_EDGES 600000
#define N_GRAPHS 512
#define HID 128
#define LAT 64
#define NL 4
#define SSTR 16        // stats padding: 1 float per 64B cache line
#define SSET 4096      // floats per stat set: 256 entries * 16
#define N_TILES (N_NODES / 16)  // 3125 exact
#define TLD 72         // per-wave LDS C half-tile row stride (ushort), 64+8 pad

typedef __attribute__((ext_vector_type(8))) __bf16 bf16x8;
typedef __attribute__((ext_vector_type(4))) float f32x4;

union Chunk {
    bf16x8 v;
    uint4 u4;
    ushort us[8];
};

__device__ __forceinline__ float gelu_exact(float x) {
    return 0.5f * x * (1.0f + erff(x * 0.70710678118654752f));
}
// Branchless gelu via A&S 7.1.26 erf poly (|err| <= 1.5e-7) + fast exp/rcp.
__device__ __forceinline__ float gelu_fast(float x) {
    float ax = fabsf(x) * 0.70710678118654752f;
    float t = __builtin_amdgcn_rcpf(fmaf(0.3275911f, ax, 1.0f));
    float p = t * (0.254829592f +
              t * (-0.284496736f +
              t * (1.421413741f +
              t * (-1.453152027f + t * 1.061405429f))));
    float e = __expf(-ax * ax);
    float erfv = 1.0f - p * e;
    float erfs = copysignf(erfv, x);
    return 0.5f * x * (1.0f + erfs);
}
__device__ __forceinline__ float bf2f(ushort h) {
    return __uint_as_float(((unsigned int)h) << 16);
}
__device__ __forceinline__ ushort f2bf(float f) {  // RNE
    unsigned int u = __float_as_uint(f);
    unsigned int r = (u + 0x7FFFu + ((u >> 16) & 1u)) >> 16;
    return (ushort)r;
}

// ---------------------------------------------------------------------------
// Weight pre-transpose + bf16: Wt[g][n][k] = W_g[k][n], g=0..3 fc1, 4..7 fc2
// ---------------------------------------------------------------------------
__global__ __launch_bounds__(256) void wt_build(const float* __restrict__ fc1w,
                                                const float* __restrict__ fc2w,
                                                ushort* __restrict__ Wt) {
    int i = blockIdx.x * 256 + threadIdx.x;  // 131072
    if (i >= 8 * HID * HID) return;
    int g = i >> 14;
    int rem = i & 16383;
    int n = rem >> 7, k = rem & 127;
    const float* W = (g < 4) ? (fc1w + (long)g * HID * HID) : (fc2w + (long)(g - 4) * HID * HID);
    Wt[i] = f2bf(W[k * HID + n]);
}

// ---------------------------------------------------------------------------
// Column stats over fp32 X -> padded stats
// ---------------------------------------------------------------------------
__global__ __launch_bounds__(256) void col_stats(const float* __restrict__ X,
                                                 float* __restrict__ stats) {
    __shared__ float sh[2048];
    int t = threadIdx.x;
    int tx = t & 31, ty = t >> 5;
    float s[4] = {0, 0, 0, 0}, q[4] = {0, 0, 0, 0};
    const int nTiles = (N_NODES + 63) / 64;  // 782
    for (int tile = blockIdx.x; tile < nTiles; tile += gridDim.x) {
        int r0 = tile * 64;
#pragma unroll
        for (int i = 0; i < 8; ++i) {
            int r = r0 + ty + 8 * i;
            int rc = min(r, N_NODES - 1);
            float4 v = *(const float4*)(X + (long)rc * HID + 4 * tx);
            float w = (r < N_NODES) ? 1.f : 0.f;
            float x0 = v.x * w, x1 = v.y * w, x2 = v.z * w, x3 = v.w * w;
            s[0] += x0; s[1] += x1; s[2] += x2; s[3] += x3;
            q[0] += x0 * v.x; q[1] += x1 * v.y; q[2] += x2 * v.z; q[3] += x3 * v.w;
        }
    }
#pragma unroll
    for (int c = 0; c < 4; ++c) {
        sh[ty * HID + 4 * tx + c] = s[c];
        sh[1024 + ty * HID + 4 * tx + c] = q[c];
    }
    __syncthreads();
    if (ty == 0) {
#pragma unroll
        for (int c = 0; c < 4; ++c) {
            float a = 0, b = 0;
#pragma unroll
            for (int j = 0; j < 8; ++j) {
                a += sh[j * HID + 4 * tx + c];
                b += sh[1024 + j * HID + 4 * tx + c];
            }
            atomicAdd(stats + (4 * tx + c) * SSTR, a);
            atomicAdd(stats + (HID + 4 * tx + c) * SSTR, b);
        }
    }
}

// ---------------------------------------------------------------------------
// BN apply, fp32 in -> bf16 out (input BN). Scale/shift from LDS; channel
// index constant per thread.
// ---------------------------------------------------------------------------
__global__ __launch_bounds__(256) void bn_apply_f32(const float* __restrict__ X,
                                                    ushort* __restrict__ Y,
                                                    const float* __restrict__ stats,
                                                    const float* __restrict__ g,
                                                    const float* __restrict__ b) {
    __shared__ float scL[HID], sfL[HID];
    int t = threadIdx.x;
    if (t < HID) {
        const float invN = 1.0f / (float)N_NODES;
        float mean = stats[t * SSTR] * invN;
        float var = stats[(HID + t) * SSTR] * invN - mean * mean;
        float s = g[t] * rsqrtf(var + 1e-5f);
        scL[t] = s;
        sfL[t] = b[t] - mean * s;
    }
    __syncthreads();
    int c4 = (t & 31) * 4;
    float sc[4], sf[4];
#pragma unroll
    for (int j = 0; j < 4; ++j) { sc[j] = scL[c4 + j]; sf[j] = sfL[c4 + j]; }
    const int NC = N_NODES * (HID / 4);
    int base = blockIdx.x * 1024 + t;
#pragma unroll
    for (int k = 0; k < 4; ++k) {
        int i = base + k * 256;
        if (i < NC) {
            float4 v = ((const float4*)X)[i];
            ushort4 w;
            w.x = f2bf(v.x * sc[0] + sf[0]);
            w.y = f2bf(v.y * sc[1] + sf[1]);
            w.z = f2bf(v.z * sc[2] + sf[2]);
            w.w = f2bf(v.w * sc[3] + sf[3]);
            ((ushort4*)Y)[i] = w;
        }
    }
}

// BN + gelu, bf16 in -> bf16 out. Scale/shift from LDS; fast gelu.
__global__ __launch_bounds__(256) void bn_apply_bf(const ushort* __restrict__ X,
                                                   ushort* __restrict__ Y,
                                                   const float* __restrict__ stats,
                                                   const float* __restrict__ g,
                                                   const float* __restrict__ b) {
    __shared__ float scL[HID], sfL[HID];
    int t = threadIdx.x;
    if (t < HID) {
        const float invN = 1.0f / (float)N_NODES;
        float mean = stats[t * SSTR] * invN;
        float var = stats[(HID + t) * SSTR] * invN - mean * mean;
        float s = g[t] * rsqrtf(var + 1e-5f);
        scL[t] = s;
        sfL[t] = b[t] - mean * s;
    }
    __syncthreads();
    int c8 = (t & 15) * 8;
    float sc[8], sf[8];
#pragma unroll
    for (int j = 0; j < 8; ++j) { sc[j] = scL[c8 + j]; sf[j] = sfL[c8 + j]; }
    const int NC = N_NODES * (HID / 8);
    int base = blockIdx.x * 1024 + t;
#pragma unroll
    for (int k = 0; k < 4; ++k) {
        int i = base + k * 256;
        if (i < NC) {
            Chunk ch;
            ch.u4 = ((const uint4*)X)[i];
#pragma unroll
            for (int j = 0; j < 8; ++j) {
                float f = bf2f(ch.us[j]) * sc[j] + sf[j];
                ch.us[j] = f2bf(gelu_fast(f));
            }
            ((uint4*)Y)[i] = ch.u4;
        }
    }
}

// ---------------------------------------------------------------------------
// CSR build: counting sort of edges by dst
// ---------------------------------------------------------------------------
__global__ __launch_bounds__(256) void csr_count(const int* __restrict__ dst,
                                                 int* __restrict__ counts) {
    int e = blockIdx.x * blockDim.x + threadIdx.x;
    if (e >= N_EDGES) return;
    atomicAdd(counts + dst[e], 1);
}

__global__ __launch_bounds__(256) void scan_pass1(const int* __restrict__ counts,
                                                  int* __restrict__ offs,
                                                  int* __restrict__ bsum) {
    __shared__ int sh[256];
    int t = threadIdx.x;
    int i = blockIdx.x * 256 + t;
    int v = (i < N_NODES) ? counts[i] : 0;
    sh[t] = v;
    __syncthreads();
    for (int off = 1; off < 256; off <<= 1) {
        int a = (t >= off) ? sh[t - off] : 0;
        __syncthreads();
        sh[t] += a;
        __syncthreads();
    }
    if (i < N_NODES) offs[i] = sh[t] - v;
    if (t == 255) bsum[blockIdx.x] = sh[255];
}

__global__ __launch_bounds__(256) void scan_pass2(int* __restrict__ bsum, int nblk) {
    __shared__ int sh[256];
    int t = threadIdx.x;
    int v = (t < nblk) ? bsum[t] : 0;
    sh[t] = v;
    __syncthreads();
    for (int off = 1; off < 256; off <<= 1) {
        int a = (t >= off) ? sh[t - off] : 0;
        __syncthreads();
        sh[t] += a;
        __syncthreads();
    }
    if (t < nblk) bsum[t] = sh[t] - v;
}

__global__ __launch_bounds__(256) void scan_pass3(int* __restrict__ offs,
                                                  const int* __restrict__ bsum,
                                                  int* __restrict__ cursor) {
    int i = blockIdx.x * 256 + threadIdx.x;
    if (i >= N_NODES) return;
    int o = offs[i] + bsum[blockIdx.x];
    offs[i] = o;
    cursor[i] = o;
}

__global__ __launch_bounds__(256) void csr_fill(const int* __restrict__ src,
                                                const int* __restrict__ dst,
                                                int* __restrict__ cursor,
                                                int* __restrict__ csr) {
    int e = blockIdx.x * blockDim.x + threadIdx.x;
    if (e >= N_EDGES) return;
    int pos = atomicAdd(cursor + dst[e], 1);
    csr[pos] = src[e];
}

// ---------------------------------------------------------------------------
// GIN aggregation (bf16): Hp[n] = (1+eps)*X[n] + sum X[nbr]; 8-deep pipelined
// ---------------------------------------------------------------------------
__global__ __launch_bounds__(256) void gin_gather_bf(const ushort* __restrict__ Xbf,
                                                     ushort* __restrict__ Hp,
                                                     const int* __restrict__ offs,
                                                     const int* __restrict__ counts,
                                                     const int* __restrict__ csr,
                                                     const float* __restrict__ eps, int l) {
    int t = threadIdx.x;
    int tx = t & 31;
    int node = blockIdx.x * 8 + (t >> 5);
    if (node >= N_NODES) return;
    float ev = 1.0f + eps[l];
    ushort4 sv = *(const ushort4*)(Xbf + (long)node * HID + 4 * tx);
    float a0 = bf2f(sv.x) * ev, a1 = bf2f(sv.y) * ev, a2 = bf2f(sv.z) * ev, a3 = bf2f(sv.w) * ev;
    int o = offs[node];
    int d = counts[node];
    int k = 0;
    for (; k + 8 <= d; k += 8) {
        int si[8];
#pragma unroll
        for (int j = 0; j < 8; ++j) si[j] = csr[o + k + j];
        ushort4 v[8];
#pragma unroll
        for (int j = 0; j < 8; ++j)
            v[j] = *(const ushort4*)(Xbf + (long)si[j] * HID + 4 * tx);
#pragma unroll
        for (int j = 0; j < 8; ++j) {
            a0 += bf2f(v[j].x); a1 += bf2f(v[j].y);
            a2 += bf2f(v[j].z); a3 += bf2f(v[j].w);
        }
    }
    for (; k + 4 <= d; k += 4) {
        int si[4];
#pragma unroll
        for (int j = 0; j < 4; ++j) si[j] = csr[o + k + j];
#pragma unroll
        for (int j = 0; j < 4; ++j) {
            ushort4 v = *(const ushort4*)(Xbf + (long)si[j] * HID + 4 * tx);
            a0 += bf2f(v.x); a1 += bf2f(v.y); a2 += bf2f(v.z); a3 += bf2f(v.w);
        }
    }
    for (; k < d; ++k) {
        int s = csr[o + k];
        ushort4 v = *(const ushort4*)(Xbf + (long)s * HID + 4 * tx);
        a0 += bf2f(v.x); a1 += bf2f(v.y); a2 += bf2f(v.z); a3 += bf2f(v.w);
    }
    ushort4 w;
    w.x = f2bf(a0); w.y = f2bf(a1); w.z = f2bf(a2); w.w = f2bf(a3);
    *(ushort4*)(Hp + (long)node * HID + 4 * tx) = w;
}

// ---------------------------------------------------------------------------
// Persistent MFMA GEMM, wave-pair column split so B truly fits in registers:
// wave w = (r2, c2): r2=w>>1 grid-strides over 16-row tiles (pairId =
// blockIdx*2+r2, stride gridDim*2), c2=w&1 owns cols c2*64..+64.
// Bfrag = 4 nt x 4 kc x 4 VGPR = 64 VGPRs -> total ~130, stays resident.
// C stored via per-wave LDS half-tile -> 2 coalesced 16B stores/lane.
// ---------------------------------------------------------------------------
__global__ __launch_bounds__(256, 2) void gemm_persist(
    const ushort* __restrict__ Abf, const ushort* __restrict__ Wt,
    const float* __restrict__ bias, ushort* __restrict__ Cbf,
    const float* __restrict__ statsIn, const float* __restrict__ gIn,
    const float* __restrict__ bIn, int applyIn, float* __restrict__ statsOut) {
    __shared__ float scL[HID], sfL[HID];
    __shared__ __align__(16) ushort T[4][16 * TLD];  // 4 x 2304 B
    __shared__ float shs[8 * 64];                    // [w][64] sums + [4+w][64] sumsq
    int t = threadIdx.x;
    if (applyIn && t < HID) {
        const float invN = 1.0f / (float)N_NODES;
        float mean = statsIn[t * SSTR] * invN;
        float var = statsIn[(HID + t) * SSTR] * invN - mean * mean;
        float s = gIn[t] * rsqrtf(var + 1e-5f);
        scL[t] = s;
        sfL[t] = bIn[t] - mean * s;
    }
    __syncthreads();

    int w = t >> 6, lane = t & 63;
    int m = lane & 15, q = lane >> 4;
    int c2 = w & 1, r2 = w >> 1;
    ushort* Tw = T[w];

    // B fragments for this wave's 64 columns only: 64 VGPRs
    const ushort* Wh = Wt + (long)(c2 * 64) * HID;
    bf16x8 Bfrag[4][4];
#pragma unroll
    for (int nt = 0; nt < 4; ++nt)
#pragma unroll
        for (int kc = 0; kc < 4; ++kc)
            Bfrag[nt][kc] = *(const bf16x8*)(Wh + (nt * 16 + m) * HID + kc * 32 + q * 8);

    float bias4[4];
#pragma unroll
    for (int nt = 0; nt < 4; ++nt) bias4[nt] = bias[c2 * 64 + nt * 16 + m];

    float s_col[4], q_col[4];
#pragma unroll
    for (int nt = 0; nt < 4; ++nt) { s_col[nt] = 0.f; q_col[nt] = 0.f; }

    int pairId = blockIdx.x * 2 + r2;
    int stride = gridDim.x * 2;

    int tile = pairId;
    Chunk Acur[4];
    if (tile < N_TILES) {
        const ushort* arow = Abf + (long)(tile * 16 + m) * HID + q * 8;
#pragma unroll
        for (int kc = 0; kc < 4; ++kc) Acur[kc].u4 = *(const uint4*)(arow + kc * 32);
    }
    while (tile < N_TILES) {
        int nxt = tile + stride;
        Chunk Anxt[4];
        if (nxt < N_TILES) {
            const ushort* arow = Abf + (long)(nxt * 16 + m) * HID + q * 8;
#pragma unroll
            for (int kc = 0; kc < 4; ++kc) Anxt[kc].u4 = *(const uint4*)(arow + kc * 32);
        }
        if (applyIn) {
#pragma unroll
            for (int kc = 0; kc < 4; ++kc)
#pragma unroll
                for (int j = 0; j < 8; ++j) {
                    int k = kc * 32 + q * 8 + j;
                    float f = bf2f(Acur[kc].us[j]) * scL[k] + sfL[k];
                    Acur[kc].us[j] = f2bf(gelu_fast(f));
                }
        }
        f32x4 acc[4];
#pragma unroll
        for (int nt = 0; nt < 4; ++nt) acc[nt] = (f32x4){0.f, 0.f, 0.f, 0.f};
#pragma unroll
        for (int kc = 0; kc < 4; ++kc)
#pragma unroll
            for (int nt = 0; nt < 4; ++nt)
                acc[nt] = __builtin_amdgcn_mfma_f32_16x16x32_bf16(Acur[kc].v, Bfrag[nt][kc],
                                                                  acc[nt], 0, 0, 0);
        // epilogue: bias, stats, LDS half-tile, coalesced store
#pragma unroll
        for (int nt = 0; nt < 4; ++nt) {
            int col = nt * 16 + m;  // within the 64-col half
#pragma unroll
            for (int r = 0; r < 4; ++r) {
                float z = acc[nt][r] + bias4[nt];
                Tw[(q * 4 + r) * TLD + col] = f2bf(z);
                s_col[nt] += z;
                q_col[nt] += z * z;
            }
        }
        __asm__ volatile("s_waitcnt lgkmcnt(0)" ::: "memory");
        long cbase = (long)tile * 16 * HID + c2 * 64;
#pragma unroll
        for (int i = 0; i < 2; ++i) {
            int slot = i * 64 + lane;            // 0..127
            int row = slot >> 3, off = slot & 7; // 8 x 16B chunks per 64-col half-row
            uint4 vv = *(const uint4*)(Tw + row * TLD + off * 8);
            *(uint4*)(Cbf + cbase + (long)row * HID + off * 8) = vv;
        }
        tile = nxt;
#pragma unroll
        for (int kc = 0; kc < 4; ++kc) Acur[kc] = Anxt[kc];
    }

    // stats combine: shfl over q, then across waves via LDS
#pragma unroll
    for (int nt = 0; nt < 4; ++nt) {
        s_col[nt] += __shfl_xor(s_col[nt], 16);
        s_col[nt] += __shfl_xor(s_col[nt], 32);
        q_col[nt] += __shfl_xor(q_col[nt], 16);
        q_col[nt] += __shfl_xor(q_col[nt], 32);
    }
    if (q == 0) {
#pragma unroll
        for (int nt = 0; nt < 4; ++nt) {
            shs[w * 64 + nt * 16 + m] = s_col[nt];
            shs[256 + w * 64 + nt * 16 + m] = q_col[nt];
        }
    }
    __syncthreads();
    if (t < HID) {
        int half = t >> 6, lc = t & 63;
        // col t gets contributions from waves {half, 2+half}
        float a = shs[half * 64 + lc] + shs[(2 + half) * 64 + lc];
        float b = shs[256 + half * 64 + lc] + shs[256 + (2 + half) * 64 + lc];
        atomicAdd(statsOut + t * SSTR, a);
        atomicAdd(statsOut + (HID + t) * SSTR, b);
    }
}

// JK attention over 4 layers (bf16 in, fp32 out): one wave per node
__global__ __launch_bounds__(256) void jk_attn_bf(const ushort* __restrict__ H0,
                                                  const ushort* __restrict__ H1,
                                                  const ushort* __restrict__ H2,
                                                  const ushort* __restrict__ H3,
                                                  const float* __restrict__ att,
                                                  float* __restrict__ Y) {
    long gid = (long)blockIdx.x * blockDim.x + threadIdx.x;
    int lane = (int)(gid & 63);
    int node = (int)(gid >> 6);
    if (node >= N_NODES) return;
    const ushort* Hs[4] = {H0, H1, H2, H3};
    float hx[4], hy[4], sc[4];
#pragma unroll
    for (int l = 0; l < 4; ++l) {
        unsigned int u = *(const unsigned int*)(Hs[l] + (long)node * HID + 2 * lane);
        float vx = bf2f((ushort)(u & 0xFFFF));
        float vy = bf2f((ushort)(u >> 16));
        float2 a = *(const float2*)(att + l * HID + 2 * lane);
        hx[l] = vx; hy[l] = vy;
        float p = vx * a.x + vy * a.y;
#pragma unroll
        for (int off = 32; off > 0; off >>= 1) p += __shfl_xor(p, off);
        sc[l] = p * (1.0f / HID);
    }
    float mm = fmaxf(fmaxf(sc[0], sc[1]), fmaxf(sc[2], sc[3]));
    float e[4], se = 0.f;
#pragma unroll
    for (int l = 0; l < 4; ++l) { e[l] = expf(sc[l] - mm); se += e[l]; }
    float inv = 1.0f / se;
    float ox = 0.f, oy = 0.f;
#pragma unroll
    for (int l = 0; l < 4; ++l) {
        float a = e[l] * inv;
        ox += a * hx[l];
        oy += a * hy[l];
    }
    *(float2*)(Y + (long)node * HID + 2 * lane) = make_float2(ox, oy);
}

__global__ void graph_ranges(const int* __restrict__ batch, int* __restrict__ gstart,
                             int* __restrict__ gend) {
    int n = blockIdx.x * blockDim.x + threadIdx.x;
    if (n >= N_NODES) return;
    int b = batch[n];
    if (n == 0 || batch[n - 1] != b) gstart[b] = n;
    if (n == N_NODES - 1 || batch[n + 1] != b) gend[b] = n + 1;
}

__global__ __launch_bounds__(128) void pool_kernel(const float* __restrict__ X,
                                                   const int* __restrict__ gstart,
                                                   const int* __restrict__ gend,
                                                   const float* __restrict__ pw,
                                                   float* __restrict__ pooled) {
    int g = blockIdx.x;
    int f = threadIdx.x;
    float w0 = pw[0], w1 = pw[1], w2 = pw[2];
    float m = fmaxf(w0, fmaxf(w1, w2));
    float e0 = expf(w0 - m), e1 = expf(w1 - m), e2 = expf(w2 - m);
    float inv = 1.0f / (e0 + e1 + e2);
    e0 *= inv; e1 *= inv; e2 *= inv;
    int s = gstart[g], e = gend[g];
    float sum = 0.f, mx = -INFINITY;
    for (int n = s; n < e; ++n) {
        float v = X[(long)n * HID + f];
        sum += v;
        mx = fmaxf(mx, v);
    }
    int cnt = e - s;
    float mean = cnt > 0 ? sum / (float)cnt : 0.f;
    float mxv = cnt > 0 ? mx : 0.f;
    pooled[g * HID + f] = sum * e0 + mean * e1 + mxv * e2;
}

__global__ __launch_bounds__(128) void head_kernel(const float* __restrict__ pooled,
                                                   const float* __restrict__ fcAw,
                                                   const float* __restrict__ fcAb,
                                                   const float* __restrict__ lng,
                                                   const float* __restrict__ lnb,
                                                   const float* __restrict__ fcBw,
                                                   const float* __restrict__ fcBb,
                                                   float* __restrict__ out) {
    __shared__ float p[HID], q[HID], red[HID];
    int g = blockIdx.x, j = threadIdx.x;
    p[j] = pooled[g * HID + j];
    __syncthreads();
    float acc = fcAb[j];
    for (int k = 0; k < HID; ++k) acc += p[k] * fcAw[k * HID + j];
    red[j] = acc;
    __syncthreads();
    for (int off = 64; off > 0; off >>= 1) {
        if (j < off) red[j] += red[j + off];
        __syncthreads();
    }
    float mean = red[0] * (1.0f / HID);
    __syncthreads();
    float d = acc - mean;
    red[j] = d * d;
    __syncthreads();
    for (int off = 64; off > 0; off >>= 1) {
        if (j < off) red[j] += red[j + off];
        __syncthreads();
    }
    float var = red[0] * (1.0f / HID);
    float y = d * rsqrtf(var + 1e-5f) * lng[j] + lnb[j];
    q[j] = gelu_exact(y) + p[j];
    __syncthreads();
    if (j < LAT) {
        float o = fcBb[j];
        for (int k = 0; k < HID; ++k) o += q[k] * fcBw[k * LAT + j];
        out[g * LAT + j] = o;
    }
}

extern "C" void kernel_launch(void* const* d_in, const int* in_sizes, int n_in,
                              void* d_out, int out_size, void* d_ws, size_t ws_size,
                              hipStream_t stream) {
    const float* x = (const float*)d_in[0];
    const int* ei = (const int*)d_in[1];
    const int* src = ei;
    const int* dst = ei + N_EDGES;
    const int* batch = (const int*)d_in[2];
    const float* ibn_g = (const float*)d_in[3];
    const float* ibn_b = (const float*)d_in[4];
    const float* eps = (const float*)d_in[5];
    const float* fc1w = (const float*)d_in[6];
    const float* fc1b = (const float*)d_in[7];
    const float* bn1g = (const float*)d_in[8];
    const float* bn1b = (const float*)d_in[9];
    const float* fc2w = (const float*)d_in[10];
    const float* fc2b = (const float*)d_in[11];
    const float* bng = (const float*)d_in[12];
    const float* bnb = (const float*)d_in[13];
    const float* att = (const float*)d_in[14];
    const float* pw = (const float*)d_in[15];
    const float* fcAw = (const float*)d_in[16];
    const float* fcAb = (const float*)d_in[17];
    const float* lng = (const float*)d_in[18];
    const float* lnb = (const float*)d_in[19];
    const float* fcBw = (const float*)d_in[20];
    const float* fcBb = (const float*)d_in[21];
    float* out = (float*)d_out;

    const size_t NH = (size_t)N_NODES * HID;
    char* w8 = (char*)d_ws;
    ushort* x0bf = (ushort*)w8;     w8 += NH * 2;
    ushort* hprebf = (ushort*)w8;   w8 += NH * 2;  // GEMM1 in; GEMM2 out
    ushort* z1bf = (ushort*)w8;     w8 += NH * 2;  // GEMM1 out / GEMM2 in
    ushort* Hlbf[NL];
    for (int l = 0; l < NL; ++l) { Hlbf[l] = (ushort*)w8; w8 += NH * 2; }
    float* ztmp = (float*)w8;       w8 += NH * 4;
    float* statsAll = (float*)w8;   w8 += (size_t)9 * SSET * 4;
    float* pooled = (float*)w8;     w8 += (size_t)N_GRAPHS * HID * 4;
    int* gstart = (int*)w8;         w8 += N_GRAPHS * 4;
    int* gend = (int*)w8;           w8 += N_GRAPHS * 4;
    int* counts = (int*)w8;         w8 += N_NODES * 4;
    int* offs = (int*)w8;           w8 += N_NODES * 4;
    int* cursor = (int*)w8;         w8 += N_NODES * 4;
    int* bsum = (int*)w8;           w8 += 256 * 4;
    int* csr = (int*)w8;            w8 += (size_t)N_EDGES * 4;
    ushort* WtBf = (ushort*)w8;     w8 += (size_t)8 * HID * HID * 2;

    const int nodeBlocks = (N_NODES + 255) / 256;
    const int edgeBlocks = (N_EDGES + 255) / 256;
    const int bnBfBlocks = (N_NODES * (HID / 8) + 1023) / 1024;   // 782
    const int bnF32Blocks = (N_NODES * (HID / 4) + 1023) / 1024;  // 1563

    // weights once
    wt_build<<<512, 256, 0, stream>>>(fc1w, fc2w, WtBf);

    // CSR build
    hipMemsetAsync(counts, 0, N_NODES * sizeof(int), stream);
    csr_count<<<edgeBlocks, 256, 0, stream>>>(dst, counts);
    scan_pass1<<<nodeBlocks, 256, 0, stream>>>(counts, offs, bsum);
    scan_pass2<<<1, 256, 0, stream>>>(bsum, nodeBlocks);
    scan_pass3<<<nodeBlocks, 256, 0, stream>>>(offs, bsum, cursor);
    csr_fill<<<edgeBlocks, 256, 0, stream>>>(src, dst, cursor, csr);

    // zero all padded stat sets once
    hipMemsetAsync(statsAll, 0, (size_t)9 * SSET * sizeof(float), stream);

    // input BN -> bf16 x0
    col_stats<<<256, 256, 0, stream>>>(x, statsAll);
    bn_apply_f32<<<bnF32Blocks, 256, 0, stream>>>(x, x0bf, statsAll, ibn_g, ibn_b);

    const ushort* xin = x0bf;
    for (int l = 0; l < NL; ++l) {
        float* st1 = statsAll + (size_t)(1 + 2 * l) * SSET;
        float* st2 = statsAll + (size_t)(2 + 2 * l) * SSET;
        gin_gather_bf<<<(N_NODES + 7) / 8, 256, 0, stream>>>(xin, hprebf, offs, counts,
                                                             csr, eps, l);
        gemm_persist<<<512, 256, 0, stream>>>(hprebf, WtBf + (size_t)l * HID * HID,
                                              fc1b + l * HID, z1bf,
                                              nullptr, nullptr, nullptr, 0, st1);
        gemm_persist<<<512, 256, 0, stream>>>(z1bf, WtBf + (size_t)(4 + l) * HID * HID,
                                              fc2b + l * HID, hprebf,
                                              st1, bn1g + l * HID, bn1b + l * HID, 1, st2);
        bn_apply_bf<<<bnBfBlocks, 256, 0, stream>>>(hprebf, Hlbf[l], st2, bng + l * HID,
                                                    bnb + l * HID);
        xin = Hlbf[l];
    }

    // JK attention -> ztmp (fp32)
    jk_attn_bf<<<(int)(((long)N_NODES * 64 + 255) / 256), 256, 0, stream>>>(
        Hlbf[0], Hlbf[1], Hlbf[2], Hlbf[3], att, ztmp);

    // pooling
    hipMemsetAsync(gstart, 0, 2 * N_GRAPHS * sizeof(int), stream);
    graph_ranges<<<nodeBlocks, 256, 0, stream>>>(batch, gstart, gend);
    pool_kernel<<<N_GRAPHS, 128, 0, stream>>>(ztmp, gstart, gend, pw, pooled);

    // head
    head_kernel<<<N_GRAPHS, 128, 0, stream>>>(pooled, fcAw, fcAb, lng, lnb, fcBw, fcBb, out);
}

// Round 9
// 563.313 us; speedup vs baseline: 1.9219x; 1.0690x over previous
//
#include <hip/hip_runtime.h>
#include <math.h>

#define N_NODES 50000
#define N_EDGES 600000
#define N_GRAPHS 512
#define HID 128
#define LAT 64
#define NL 4
#define SSTR 16        // stats padding: 1 float per 64B cache line
#define SSET 4096      // floats per stat set: 256 entries * 16
#define N_STILES 1563  // 32-row supertiles; last has only 16 valid rows
#define TLD 72         // per-wave LDS C half-tile row stride (ushort), 64+8 pad

typedef __attribute__((ext_vector_type(8))) __bf16 bf16x8;
typedef __attribute__((ext_vector_type(4))) float f32x4;

union Chunk {
    bf16x8 v;
    uint4 u4;
    ushort us[8];
};

__device__ __forceinline__ float gelu_exact(float x) {
    return 0.5f * x * (1.0f + erff(x * 0.70710678118654752f));
}
// Branchless gelu via A&S 7.1.26 erf poly (|err| <= 1.5e-7) + fast exp/rcp.
__device__ __forceinline__ float gelu_fast(float x) {
    float ax = fabsf(x) * 0.70710678118654752f;
    float t = __builtin_amdgcn_rcpf(fmaf(0.3275911f, ax, 1.0f));
    float p = t * (0.254829592f +
              t * (-0.284496736f +
              t * (1.421413741f +
              t * (-1.453152027f + t * 1.061405429f))));
    float e = __expf(-ax * ax);
    float erfv = 1.0f - p * e;
    float erfs = copysignf(erfv, x);
    return 0.5f * x * (1.0f + erfs);
}
__device__ __forceinline__ float bf2f(ushort h) {
    return __uint_as_float(((unsigned int)h) << 16);
}
__device__ __forceinline__ ushort f2bf(float f) {  // RNE
    unsigned int u = __float_as_uint(f);
    unsigned int r = (u + 0x7FFFu + ((u >> 16) & 1u)) >> 16;
    return (ushort)r;
}

// ---------------------------------------------------------------------------
// Weight pre-transpose + bf16: Wt[g][n][k] = W_g[k][n], g=0..3 fc1, 4..7 fc2
// ---------------------------------------------------------------------------
__global__ __launch_bounds__(256) void wt_build(const float* __restrict__ fc1w,
                                                const float* __restrict__ fc2w,
                                                ushort* __restrict__ Wt) {
    int i = blockIdx.x * 256 + threadIdx.x;  // 131072
    if (i >= 8 * HID * HID) return;
    int g = i >> 14;
    int rem = i & 16383;
    int n = rem >> 7, k = rem & 127;
    const float* W = (g < 4) ? (fc1w + (long)g * HID * HID) : (fc2w + (long)(g - 4) * HID * HID);
    Wt[i] = f2bf(W[k * HID + n]);
}

// ---------------------------------------------------------------------------
// Column stats over fp32 X -> padded stats
// ---------------------------------------------------------------------------
__global__ __launch_bounds__(256) void col_stats(const float* __restrict__ X,
                                                 float* __restrict__ stats) {
    __shared__ float sh[2048];
    int t = threadIdx.x;
    int tx = t & 31, ty = t >> 5;
    float s[4] = {0, 0, 0, 0}, q[4] = {0, 0, 0, 0};
    const int nTiles = (N_NODES + 63) / 64;  // 782
    for (int tile = blockIdx.x; tile < nTiles; tile += gridDim.x) {
        int r0 = tile * 64;
#pragma unroll
        for (int i = 0; i < 8; ++i) {
            int r = r0 + ty + 8 * i;
            int rc = min(r, N_NODES - 1);
            float4 v = *(const float4*)(X + (long)rc * HID + 4 * tx);
            float w = (r < N_NODES) ? 1.f : 0.f;
            float x0 = v.x * w, x1 = v.y * w, x2 = v.z * w, x3 = v.w * w;
            s[0] += x0; s[1] += x1; s[2] += x2; s[3] += x3;
            q[0] += x0 * v.x; q[1] += x1 * v.y; q[2] += x2 * v.z; q[3] += x3 * v.w;
        }
    }
#pragma unroll
    for (int c = 0; c < 4; ++c) {
        sh[ty * HID + 4 * tx + c] = s[c];
        sh[1024 + ty * HID + 4 * tx + c] = q[c];
    }
    __syncthreads();
    if (ty == 0) {
#pragma unroll
        for (int c = 0; c < 4; ++c) {
            float a = 0, b = 0;
#pragma unroll
            for (int j = 0; j < 8; ++j) {
                a += sh[j * HID + 4 * tx + c];
                b += sh[1024 + j * HID + 4 * tx + c];
            }
            atomicAdd(stats + (4 * tx + c) * SSTR, a);
            atomicAdd(stats + (HID + 4 * tx + c) * SSTR, b);
        }
    }
}

// ---------------------------------------------------------------------------
// BN apply, fp32 in -> bf16 out (input BN). Scale/shift from LDS; channel
// index constant per thread.
// ---------------------------------------------------------------------------
__global__ __launch_bounds__(256) void bn_apply_f32(const float* __restrict__ X,
                                                    ushort* __restrict__ Y,
                                                    const float* __restrict__ stats,
                                                    const float* __restrict__ g,
                                                    const float* __restrict__ b) {
    __shared__ float scL[HID], sfL[HID];
    int t = threadIdx.x;
    if (t < HID) {
        const float invN = 1.0f / (float)N_NODES;
        float mean = stats[t * SSTR] * invN;
        float var = stats[(HID + t) * SSTR] * invN - mean * mean;
        float s = g[t] * rsqrtf(var + 1e-5f);
        scL[t] = s;
        sfL[t] = b[t] - mean * s;
    }
    __syncthreads();
    int c4 = (t & 31) * 4;
    float sc[4], sf[4];
#pragma unroll
    for (int j = 0; j < 4; ++j) { sc[j] = scL[c4 + j]; sf[j] = sfL[c4 + j]; }
    const int NC = N_NODES * (HID / 4);
    int base = blockIdx.x * 1024 + t;
#pragma unroll
    for (int k = 0; k < 4; ++k) {
        int i = base + k * 256;
        if (i < NC) {
            float4 v = ((const float4*)X)[i];
            ushort4 w;
            w.x = f2bf(v.x * sc[0] + sf[0]);
            w.y = f2bf(v.y * sc[1] + sf[1]);
            w.z = f2bf(v.z * sc[2] + sf[2]);
            w.w = f2bf(v.w * sc[3] + sf[3]);
            ((ushort4*)Y)[i] = w;
        }
    }
}

// BN + gelu, bf16 in -> bf16 out. Scale/shift from LDS; fast gelu.
__global__ __launch_bounds__(256) void bn_apply_bf(const ushort* __restrict__ X,
                                                   ushort* __restrict__ Y,
                                                   const float* __restrict__ stats,
                                                   const float* __restrict__ g,
                                                   const float* __restrict__ b) {
    __shared__ float scL[HID], sfL[HID];
    int t = threadIdx.x;
    if (t < HID) {
        const float invN = 1.0f / (float)N_NODES;
        float mean = stats[t * SSTR] * invN;
        float var = stats[(HID + t) * SSTR] * invN - mean * mean;
        float s = g[t] * rsqrtf(var + 1e-5f);
        scL[t] = s;
        sfL[t] = b[t] - mean * s;
    }
    __syncthreads();
    int c8 = (t & 15) * 8;
    float sc[8], sf[8];
#pragma unroll
    for (int j = 0; j < 8; ++j) { sc[j] = scL[c8 + j]; sf[j] = sfL[c8 + j]; }
    const int NC = N_NODES * (HID / 8);
    int base = blockIdx.x * 1024 + t;
#pragma unroll
    for (int k = 0; k < 4; ++k) {
        int i = base + k * 256;
        if (i < NC) {
            Chunk ch;
            ch.u4 = ((const uint4*)X)[i];
#pragma unroll
            for (int j = 0; j < 8; ++j) {
                float f = bf2f(ch.us[j]) * sc[j] + sf[j];
                ch.us[j] = f2bf(gelu_fast(f));
            }
            ((uint4*)Y)[i] = ch.u4;
        }
    }
}

// ---------------------------------------------------------------------------
// CSR build: counting sort of edges by dst
// ---------------------------------------------------------------------------
__global__ __launch_bounds__(256) void csr_count(const int* __restrict__ dst,
                                                 int* __restrict__ counts) {
    int e = blockIdx.x * blockDim.x + threadIdx.x;
    if (e >= N_EDGES) return;
    atomicAdd(counts + dst[e], 1);
}

__global__ __launch_bounds__(256) void scan_pass1(const int* __restrict__ counts,
                                                  int* __restrict__ offs,
                                                  int* __restrict__ bsum) {
    __shared__ int sh[256];
    int t = threadIdx.x;
    int i = blockIdx.x * 256 + t;
    int v = (i < N_NODES) ? counts[i] : 0;
    sh[t] = v;
    __syncthreads();
    for (int off = 1; off < 256; off <<= 1) {
        int a = (t >= off) ? sh[t - off] : 0;
        __syncthreads();
        sh[t] += a;
        __syncthreads();
    }
    if (i < N_NODES) offs[i] = sh[t] - v;
    if (t == 255) bsum[blockIdx.x] = sh[255];
}

__global__ __launch_bounds__(256) void scan_pass2(int* __restrict__ bsum, int nblk) {
    __shared__ int sh[256];
    int t = threadIdx.x;
    int v = (t < nblk) ? bsum[t] : 0;
    sh[t] = v;
    __syncthreads();
    for (int off = 1; off < 256; off <<= 1) {
        int a = (t >= off) ? sh[t - off] : 0;
        __syncthreads();
        sh[t] += a;
        __syncthreads();
    }
    if (t < nblk) bsum[t] = sh[t] - v;
}

__global__ __launch_bounds__(256) void scan_pass3(int* __restrict__ offs,
                                                  const int* __restrict__ bsum,
                                                  int* __restrict__ cursor) {
    int i = blockIdx.x * 256 + threadIdx.x;
    if (i >= N_NODES) return;
    int o = offs[i] + bsum[blockIdx.x];
    offs[i] = o;
    cursor[i] = o;
}

__global__ __launch_bounds__(256) void csr_fill(const int* __restrict__ src,
                                                const int* __restrict__ dst,
                                                int* __restrict__ cursor,
                                                int* __restrict__ csr) {
    int e = blockIdx.x * blockDim.x + threadIdx.x;
    if (e >= N_EDGES) return;
    int pos = atomicAdd(cursor + dst[e], 1);
    csr[pos] = src[e];
}

// ---------------------------------------------------------------------------
// GIN aggregation (bf16): Hp[n] = (1+eps)*X[n] + sum X[nbr]; 8-deep pipelined
// ---------------------------------------------------------------------------
__global__ __launch_bounds__(256) void gin_gather_bf(const ushort* __restrict__ Xbf,
                                                     ushort* __restrict__ Hp,
                                                     const int* __restrict__ offs,
                                                     const int* __restrict__ counts,
                                                     const int* __restrict__ csr,
                                                     const float* __restrict__ eps, int l) {
    int t = threadIdx.x;
    int tx = t & 31;
    int node = blockIdx.x * 8 + (t >> 5);
    if (node >= N_NODES) return;
    float ev = 1.0f + eps[l];
    ushort4 sv = *(const ushort4*)(Xbf + (long)node * HID + 4 * tx);
    float a0 = bf2f(sv.x) * ev, a1 = bf2f(sv.y) * ev, a2 = bf2f(sv.z) * ev, a3 = bf2f(sv.w) * ev;
    int o = offs[node];
    int d = counts[node];
    int k = 0;
    for (; k + 8 <= d; k += 8) {
        int si[8];
#pragma unroll
        for (int j = 0; j < 8; ++j) si[j] = csr[o + k + j];
        ushort4 v[8];
#pragma unroll
        for (int j = 0; j < 8; ++j)
            v[j] = *(const ushort4*)(Xbf + (long)si[j] * HID + 4 * tx);
#pragma unroll
        for (int j = 0; j < 8; ++j) {
            a0 += bf2f(v[j].x); a1 += bf2f(v[j].y);
            a2 += bf2f(v[j].z); a3 += bf2f(v[j].w);
        }
    }
    for (; k + 4 <= d; k += 4) {
        int si[4];
#pragma unroll
        for (int j = 0; j < 4; ++j) si[j] = csr[o + k + j];
#pragma unroll
        for (int j = 0; j < 4; ++j) {
            ushort4 v = *(const ushort4*)(Xbf + (long)si[j] * HID + 4 * tx);
            a0 += bf2f(v.x); a1 += bf2f(v.y); a2 += bf2f(v.z); a3 += bf2f(v.w);
        }
    }
    for (; k < d; ++k) {
        int s = csr[o + k];
        ushort4 v = *(const ushort4*)(Xbf + (long)s * HID + 4 * tx);
        a0 += bf2f(v.x); a1 += bf2f(v.y); a2 += bf2f(v.z); a3 += bf2f(v.w);
    }
    ushort4 w;
    w.x = f2bf(a0); w.y = f2bf(a1); w.z = f2bf(a2); w.w = f2bf(a3);
    *(ushort4*)(Hp + (long)node * HID + 4 * tx) = w;
}

// ---------------------------------------------------------------------------
// Persistent MFMA GEMM, wave-pair column split, 32-row supertiles, explicit
// next-supertile prefetch. __launch_bounds__(256,1) frees the VGPR budget so
// Bfrag(64) + Acur(32) + Anxt(32) + acc(32) stay register-resident.
// wave w=(r2,c2): pair r2 grid-strides over supertiles, c2 owns 64 cols.
// ---------------------------------------------------------------------------
__global__ __launch_bounds__(256, 1) void gemm_persist(
    const ushort* __restrict__ Abf, const ushort* __restrict__ Wt,
    const float* __restrict__ bias, ushort* __restrict__ Cbf,
    const float* __restrict__ statsIn, const float* __restrict__ gIn,
    const float* __restrict__ bIn, int applyIn, float* __restrict__ statsOut) {
    __shared__ float scL[HID], sfL[HID];
    __shared__ __align__(16) ushort T[4][16 * TLD];
    __shared__ float shs[8 * 64];
    int t = threadIdx.x;
    if (applyIn && t < HID) {
        const float invN = 1.0f / (float)N_NODES;
        float mean = statsIn[t * SSTR] * invN;
        float var = statsIn[(HID + t) * SSTR] * invN - mean * mean;
        float s = gIn[t] * rsqrtf(var + 1e-5f);
        scL[t] = s;
        sfL[t] = bIn[t] - mean * s;
    }
    __syncthreads();

    int w = t >> 6, lane = t & 63;
    int m = lane & 15, q = lane >> 4;
    int c2 = w & 1, r2 = w >> 1;
    ushort* Tw = T[w];

    // B fragments for this wave's 64 columns: 64 VGPRs
    const ushort* Wh = Wt + (long)(c2 * 64) * HID;
    bf16x8 Bfrag[4][4];
#pragma unroll
    for (int nt = 0; nt < 4; ++nt)
#pragma unroll
        for (int kc = 0; kc < 4; ++kc)
            Bfrag[nt][kc] = *(const bf16x8*)(Wh + (nt * 16 + m) * HID + kc * 32 + q * 8);

    float bias4[4];
#pragma unroll
    for (int nt = 0; nt < 4; ++nt) bias4[nt] = bias[c2 * 64 + nt * 16 + m];

    float s_col[4], q_col[4];
#pragma unroll
    for (int nt = 0; nt < 4; ++nt) { s_col[nt] = 0.f; q_col[nt] = 0.f; }

    int pairId = blockIdx.x * 2 + r2;   // grid 256 -> 512 pairs
    int stride = gridDim.x * 2;         // 512

    int st = pairId;
    Chunk Ac[8];  // [0..3] = rows st*32+m, [4..7] = rows st*32+16+m
    if (st < N_STILES) {
        const ushort* a0 = Abf + (long)(st * 32 + m) * HID + q * 8;
        int r1 = min(st * 32 + 16 + m, N_NODES - 1);
        const ushort* a1 = Abf + (long)r1 * HID + q * 8;
#pragma unroll
        for (int kc = 0; kc < 4; ++kc) {
            Ac[kc].u4 = *(const uint4*)(a0 + kc * 32);
            Ac[4 + kc].u4 = *(const uint4*)(a1 + kc * 32);
        }
    }
    while (st < N_STILES) {
        int nxt = st + stride;
        Chunk An[8];
        if (nxt < N_STILES) {
            const ushort* a0 = Abf + (long)(nxt * 32 + m) * HID + q * 8;
            int r1 = min(nxt * 32 + 16 + m, N_NODES - 1);
            const ushort* a1 = Abf + (long)r1 * HID + q * 8;
#pragma unroll
            for (int kc = 0; kc < 4; ++kc) {
                An[kc].u4 = *(const uint4*)(a0 + kc * 32);
                An[4 + kc].u4 = *(const uint4*)(a1 + kc * 32);
            }
        }
        int valid2 = (st < N_STILES - 1);  // last supertile: only first 16 rows
        if (applyIn) {
#pragma unroll
            for (int h = 0; h < 8; ++h)
#pragma unroll
                for (int j = 0; j < 8; ++j) {
                    int k = (h & 3) * 32 + q * 8 + j;
                    float f = bf2f(Ac[h].us[j]) * scL[k] + sfL[k];
                    Ac[h].us[j] = f2bf(gelu_fast(f));
                }
        }
        f32x4 acc1[4], acc2[4];
#pragma unroll
        for (int nt = 0; nt < 4; ++nt) {
            acc1[nt] = (f32x4){0.f, 0.f, 0.f, 0.f};
            acc2[nt] = (f32x4){0.f, 0.f, 0.f, 0.f};
        }
#pragma unroll
        for (int kc = 0; kc < 4; ++kc)
#pragma unroll
            for (int nt = 0; nt < 4; ++nt) {
                acc1[nt] = __builtin_amdgcn_mfma_f32_16x16x32_bf16(Ac[kc].v, Bfrag[nt][kc],
                                                                   acc1[nt], 0, 0, 0);
                acc2[nt] = __builtin_amdgcn_mfma_f32_16x16x32_bf16(Ac[4 + kc].v,
                                                                   Bfrag[nt][kc],
                                                                   acc2[nt], 0, 0, 0);
            }
        // epilogue half 1 (rows st*32 .. +16)
        {
#pragma unroll
            for (int nt = 0; nt < 4; ++nt) {
                int col = nt * 16 + m;
#pragma unroll
                for (int r = 0; r < 4; ++r) {
                    float z = acc1[nt][r] + bias4[nt];
                    Tw[(q * 4 + r) * TLD + col] = f2bf(z);
                    s_col[nt] += z;
                    q_col[nt] += z * z;
                }
            }
            long cbase = (long)(st * 32) * HID + c2 * 64;
#pragma unroll
            for (int i = 0; i < 2; ++i) {
                int slot = i * 64 + lane;
                int row = slot >> 3, off = slot & 7;
                uint4 vv = *(const uint4*)(Tw + row * TLD + off * 8);
                *(uint4*)(Cbf + cbase + (long)row * HID + off * 8) = vv;
            }
        }
        // epilogue half 2 (rows st*32+16 .. +16), wave-uniform validity
        if (valid2) {
#pragma unroll
            for (int nt = 0; nt < 4; ++nt) {
                int col = nt * 16 + m;
#pragma unroll
                for (int r = 0; r < 4; ++r) {
                    float z = acc2[nt][r] + bias4[nt];
                    Tw[(q * 4 + r) * TLD + col] = f2bf(z);
                    s_col[nt] += z;
                    q_col[nt] += z * z;
                }
            }
            long cbase = (long)(st * 32 + 16) * HID + c2 * 64;
#pragma unroll
            for (int i = 0; i < 2; ++i) {
                int slot = i * 64 + lane;
                int row = slot >> 3, off = slot & 7;
                uint4 vv = *(const uint4*)(Tw + row * TLD + off * 8);
                *(uint4*)(Cbf + cbase + (long)row * HID + off * 8) = vv;
            }
        }
        st = nxt;
#pragma unroll
        for (int h = 0; h < 8; ++h) Ac[h] = An[h];
    }

    // stats combine: shfl over q, then across waves via LDS, padded atomics
#pragma unroll
    for (int nt = 0; nt < 4; ++nt) {
        s_col[nt] += __shfl_xor(s_col[nt], 16);
        s_col[nt] += __shfl_xor(s_col[nt], 32);
        q_col[nt] += __shfl_xor(q_col[nt], 16);
        q_col[nt] += __shfl_xor(q_col[nt], 32);
    }
    if (q == 0) {
#pragma unroll
        for (int nt = 0; nt < 4; ++nt) {
            shs[w * 64 + nt * 16 + m] = s_col[nt];
            shs[256 + w * 64 + nt * 16 + m] = q_col[nt];
        }
    }
    __syncthreads();
    if (t < HID) {
        int half = t >> 6, lc = t & 63;
        float a = shs[half * 64 + lc] + shs[(2 + half) * 64 + lc];
        float b = shs[256 + half * 64 + lc] + shs[256 + (2 + half) * 64 + lc];
        atomicAdd(statsOut + t * SSTR, a);
        atomicAdd(statsOut + (HID + t) * SSTR, b);
    }
}

// JK attention over 4 layers (bf16 in, fp32 out): one wave per node
__global__ __launch_bounds__(256) void jk_attn_bf(const ushort* __restrict__ H0,
                                                  const ushort* __restrict__ H1,
                                                  const ushort* __restrict__ H2,
                                                  const ushort* __restrict__ H3,
                                                  const float* __restrict__ att,
                                                  float* __restrict__ Y) {
    long gid = (long)blockIdx.x * blockDim.x + threadIdx.x;
    int lane = (int)(gid & 63);
    int node = (int)(gid >> 6);
    if (node >= N_NODES) return;
    const ushort* Hs[4] = {H0, H1, H2, H3};
    float hx[4], hy[4], sc[4];
#pragma unroll
    for (int l = 0; l < 4; ++l) {
        unsigned int u = *(const unsigned int*)(Hs[l] + (long)node * HID + 2 * lane);
        float vx = bf2f((ushort)(u & 0xFFFF));
        float vy = bf2f((ushort)(u >> 16));
        float2 a = *(const float2*)(att + l * HID + 2 * lane);
        hx[l] = vx; hy[l] = vy;
        float p = vx * a.x + vy * a.y;
#pragma unroll
        for (int off = 32; off > 0; off >>= 1) p += __shfl_xor(p, off);
        sc[l] = p * (1.0f / HID);
    }
    float mm = fmaxf(fmaxf(sc[0], sc[1]), fmaxf(sc[2], sc[3]));
    float e[4], se = 0.f;
#pragma unroll
    for (int l = 0; l < 4; ++l) { e[l] = expf(sc[l] - mm); se += e[l]; }
    float inv = 1.0f / se;
    float ox = 0.f, oy = 0.f;
#pragma unroll
    for (int l = 0; l < 4; ++l) {
        float a = e[l] * inv;
        ox += a * hx[l];
        oy += a * hy[l];
    }
    *(float2*)(Y + (long)node * HID + 2 * lane) = make_float2(ox, oy);
}

__global__ void graph_ranges(const int* __restrict__ batch, int* __restrict__ gstart,
                             int* __restrict__ gend) {
    int n = blockIdx.x * blockDim.x + threadIdx.x;
    if (n >= N_NODES) return;
    int b = batch[n];
    if (n == 0 || batch[n - 1] != b) gstart[b] = n;
    if (n == N_NODES - 1 || batch[n + 1] != b) gend[b] = n + 1;
}

__global__ __launch_bounds__(128) void pool_kernel(const float* __restrict__ X,
                                                   const int* __restrict__ gstart,
                                                   const int* __restrict__ gend,
                                                   const float* __restrict__ pw,
                                                   float* __restrict__ pooled) {
    int g = blockIdx.x;
    int f = threadIdx.x;
    float w0 = pw[0], w1 = pw[1], w2 = pw[2];
    float m = fmaxf(w0, fmaxf(w1, w2));
    float e0 = expf(w0 - m), e1 = expf(w1 - m), e2 = expf(w2 - m);
    float inv = 1.0f / (e0 + e1 + e2);
    e0 *= inv; e1 *= inv; e2 *= inv;
    int s = gstart[g], e = gend[g];
    float sum = 0.f, mx = -INFINITY;
    for (int n = s; n < e; ++n) {
        float v = X[(long)n * HID + f];
        sum += v;
        mx = fmaxf(mx, v);
    }
    int cnt = e - s;
    float mean = cnt > 0 ? sum / (float)cnt : 0.f;
    float mxv = cnt > 0 ? mx : 0.f;
    pooled[g * HID + f] = sum * e0 + mean * e1 + mxv * e2;
}

__global__ __launch_bounds__(128) void head_kernel(const float* __restrict__ pooled,
                                                   const float* __restrict__ fcAw,
                                                   const float* __restrict__ fcAb,
                                                   const float* __restrict__ lng,
                                                   const float* __restrict__ lnb,
                                                   const float* __restrict__ fcBw,
                                                   const float* __restrict__ fcBb,
                                                   float* __restrict__ out) {
    __shared__ float p[HID], q[HID], red[HID];
    int g = blockIdx.x, j = threadIdx.x;
    p[j] = pooled[g * HID + j];
    __syncthreads();
    float acc = fcAb[j];
    for (int k = 0; k < HID; ++k) acc += p[k] * fcAw[k * HID + j];
    red[j] = acc;
    __syncthreads();
    for (int off = 64; off > 0; off >>= 1) {
        if (j < off) red[j] += red[j + off];
        __syncthreads();
    }
    float mean = red[0] * (1.0f / HID);
    __syncthreads();
    float d = acc - mean;
    red[j] = d * d;
    __syncthreads();
    for (int off = 64; off > 0; off >>= 1) {
        if (j < off) red[j] += red[j + off];
        __syncthreads();
    }
    float var = red[0] * (1.0f / HID);
    float y = d * rsqrtf(var + 1e-5f) * lng[j] + lnb[j];
    q[j] = gelu_exact(y) + p[j];
    __syncthreads();
    if (j < LAT) {
        float o = fcBb[j];
        for (int k = 0; k < HID; ++k) o += q[k] * fcBw[k * LAT + j];
        out[g * LAT + j] = o;
    }
}

extern "C" void kernel_launch(void* const* d_in, const int* in_sizes, int n_in,
                              void* d_out, int out_size, void* d_ws, size_t ws_size,
                              hipStream_t stream) {
    const float* x = (const float*)d_in[0];
    const int* ei = (const int*)d_in[1];
    const int* src = ei;
    const int* dst = ei + N_EDGES;
    const int* batch = (const int*)d_in[2];
    const float* ibn_g = (const float*)d_in[3];
    const float* ibn_b = (const float*)d_in[4];
    const float* eps = (const float*)d_in[5];
    const float* fc1w = (const float*)d_in[6];
    const float* fc1b = (const float*)d_in[7];
    const float* bn1g = (const float*)d_in[8];
    const float* bn1b = (const float*)d_in[9];
    const float* fc2w = (const float*)d_in[10];
    const float* fc2b = (const float*)d_in[11];
    const float* bng = (const float*)d_in[12];
    const float* bnb = (const float*)d_in[13];
    const float* att = (const float*)d_in[14];
    const float* pw = (const float*)d_in[15];
    const float* fcAw = (const float*)d_in[16];
    const float* fcAb = (const float*)d_in[17];
    const float* lng = (const float*)d_in[18];
    const float* lnb = (const float*)d_in[19];
    const float* fcBw = (const float*)d_in[20];
    const float* fcBb = (const float*)d_in[21];
    float* out = (float*)d_out;

    const size_t NH = (size_t)N_NODES * HID;
    char* w8 = (char*)d_ws;
    ushort* x0bf = (ushort*)w8;     w8 += NH * 2;
    ushort* hprebf = (ushort*)w8;   w8 += NH * 2;  // GEMM1 in; GEMM2 out
    ushort* z1bf = (ushort*)w8;     w8 += NH * 2;  // GEMM1 out / GEMM2 in
    ushort* Hlbf[NL];
    for (int l = 0; l < NL; ++l) { Hlbf[l] = (ushort*)w8; w8 += NH * 2; }
    float* ztmp = (float*)w8;       w8 += NH * 4;
    float* statsAll = (float*)w8;   w8 += (size_t)9 * SSET * 4;
    float* pooled = (float*)w8;     w8 += (size_t)N_GRAPHS * HID * 4;
    int* gstart = (int*)w8;         w8 += N_GRAPHS * 4;
    int* gend = (int*)w8;           w8 += N_GRAPHS * 4;
    int* counts = (int*)w8;         w8 += N_NODES * 4;
    int* offs = (int*)w8;           w8 += N_NODES * 4;
    int* cursor = (int*)w8;         w8 += N_NODES * 4;
    int* bsum = (int*)w8;           w8 += 256 * 4;
    int* csr = (int*)w8;            w8 += (size_t)N_EDGES * 4;
    ushort* WtBf = (ushort*)w8;     w8 += (size_t)8 * HID * HID * 2;

    const int nodeBlocks = (N_NODES + 255) / 256;
    const int edgeBlocks = (N_EDGES + 255) / 256;
    const int bnBfBlocks = (N_NODES * (HID / 8) + 1023) / 1024;   // 782
    const int bnF32Blocks = (N_NODES * (HID / 4) + 1023) / 1024;  // 1563

    // weights once
    wt_build<<<512, 256, 0, stream>>>(fc1w, fc2w, WtBf);

    // CSR build
    hipMemsetAsync(counts, 0, N_NODES * sizeof(int), stream);
    csr_count<<<edgeBlocks, 256, 0, stream>>>(dst, counts);
    scan_pass1<<<nodeBlocks, 256, 0, stream>>>(counts, offs, bsum);
    scan_pass2<<<1, 256, 0, stream>>>(bsum, nodeBlocks);
    scan_pass3<<<nodeBlocks, 256, 0, stream>>>(offs, bsum, cursor);
    csr_fill<<<edgeBlocks, 256, 0, stream>>>(src, dst, cursor, csr);

    // zero all padded stat sets once
    hipMemsetAsync(statsAll, 0, (size_t)9 * SSET * sizeof(float), stream);

    // input BN -> bf16 x0
    col_stats<<<256, 256, 0, stream>>>(x, statsAll);
    bn_apply_f32<<<bnF32Blocks, 256, 0, stream>>>(x, x0bf, statsAll, ibn_g, ibn_b);

    const ushort* xin = x0bf;
    for (int l = 0; l < NL; ++l) {
        float* st1 = statsAll + (size_t)(1 + 2 * l) * SSET;
        float* st2 = statsAll + (size_t)(2 + 2 * l) * SSET;
        gin_gather_bf<<<(N_NODES + 7) / 8, 256, 0, stream>>>(xin, hprebf, offs, counts,
                                                             csr, eps, l);
        gemm_persist<<<256, 256, 0, stream>>>(hprebf, WtBf + (size_t)l * HID * HID,
                                              fc1b + l * HID, z1bf,
                                              nullptr, nullptr, nullptr, 0, st1);
        gemm_persist<<<256, 256, 0, stream>>>(z1bf, WtBf + (size_t)(4 + l) * HID * HID,
                                              fc2b + l * HID, hprebf,
                                              st1, bn1g + l * HID, bn1b + l * HID, 1, st2);
        bn_apply_bf<<<bnBfBlocks, 256, 0, stream>>>(hprebf, Hlbf[l], st2, bng + l * HID,
                                                    bnb + l * HID);
        xin = Hlbf[l];
    }

    // JK attention -> ztmp (fp32)
    jk_attn_bf<<<(int)(((long)N_NODES * 64 + 255) / 256), 256, 0, stream>>>(
        Hlbf[0], Hlbf[1], Hlbf[2], Hlbf[3], att, ztmp);

    // pooling
    hipMemsetAsync(gstart, 0, 2 * N_GRAPHS * sizeof(int), stream);
    graph_ranges<<<nodeBlocks, 256, 0, stream>>>(batch, gstart, gend);
    pool_kernel<<<N_GRAPHS, 128, 0, stream>>>(ztmp, gstart, gend, pw, pooled);

    // head
    head_kernel<<<N_GRAPHS, 128, 0, stream>>>(pooled, fcAw, fcAb, lng, lnb, fcBw, fcBb, out);
}

// Round 10
// 557.819 us; speedup vs baseline: 1.9409x; 1.0098x over previous
//
#include <hip/hip_runtime.h>
#include <math.h>

#define N_NODES 50000
#define N_EDGES 600000
#define N_GRAPHS 512
#define HID 128
#define LAT 64
#define NL 4
#define SSTR 16        // stats padding: 1 float per 64B cache line
#define SSET 4096      // floats per stat set: 256 entries * 16
#define N_TILES 3125   // 16-row tiles, exact
#define TLD 72         // per-wave LDS C half-tile row stride (ushort), 64+8 pad

typedef __attribute__((ext_vector_type(8))) __bf16 bf16x8;
typedef __attribute__((ext_vector_type(4))) float f32x4;

union Chunk {
    bf16x8 v;
    uint4 u4;
    ushort us[8];
};

__device__ __forceinline__ float gelu_exact(float x) {
    return 0.5f * x * (1.0f + erff(x * 0.70710678118654752f));
}
// Branchless gelu via A&S 7.1.26 erf poly (|err| <= 1.5e-7) + fast exp/rcp.
__device__ __forceinline__ float gelu_fast(float x) {
    float ax = fabsf(x) * 0.70710678118654752f;
    float t = __builtin_amdgcn_rcpf(fmaf(0.3275911f, ax, 1.0f));
    float p = t * (0.254829592f +
              t * (-0.284496736f +
              t * (1.421413741f +
              t * (-1.453152027f + t * 1.061405429f))));
    float e = __expf(-ax * ax);
    float erfv = 1.0f - p * e;
    float erfs = copysignf(erfv, x);
    return 0.5f * x * (1.0f + erfs);
}
__device__ __forceinline__ float bf2f(ushort h) {
    return __uint_as_float(((unsigned int)h) << 16);
}
__device__ __forceinline__ ushort f2bf(float f) {  // RNE
    unsigned int u = __float_as_uint(f);
    unsigned int r = (u + 0x7FFFu + ((u >> 16) & 1u)) >> 16;
    return (ushort)r;
}

// Canonical row partition p (0..255) -> [r0, r1); sub-chunk j (0..7) -> [s0, s1)
__device__ __forceinline__ void part_range(int p, int& r0, int& r1) {
    r0 = (p * N_NODES) >> 8;
    r1 = ((p + 1) * N_NODES) >> 8;
}
__device__ __forceinline__ void sub_range(int p, int j, int& s0, int& s1) {
    int r0, r1;
    part_range(p, r0, r1);
    int len = r1 - r0;
    s0 = r0 + ((len * j) >> 3);
    s1 = r0 + ((len * (j + 1)) >> 3);
}

// ---------------------------------------------------------------------------
// Weight pre-transpose + bf16: Wt[g][n][k] = W_g[k][n], g=0..3 fc1, 4..7 fc2
// ---------------------------------------------------------------------------
__global__ __launch_bounds__(256) void wt_build(const float* __restrict__ fc1w,
                                                const float* __restrict__ fc2w,
                                                ushort* __restrict__ Wt) {
    int i = blockIdx.x * 256 + threadIdx.x;  // 131072
    if (i >= 8 * HID * HID) return;
    int g = i >> 14;
    int rem = i & 16383;
    int n = rem >> 7, k = rem & 127;
    const float* W = (g < 4) ? (fc1w + (long)g * HID * HID) : (fc2w + (long)(g - 4) * HID * HID);
    Wt[i] = f2bf(W[k * HID + n]);
}

// ---------------------------------------------------------------------------
// Column stats over fp32 X -> padded stats (input is read-only/clean: no
// cross-XCD dirty-line concern here).
// ---------------------------------------------------------------------------
__global__ __launch_bounds__(256) void col_stats(const float* __restrict__ X,
                                                 float* __restrict__ stats) {
    __shared__ float sh[2048];
    int t = threadIdx.x;
    int tx = t & 31, ty = t >> 5;
    float s[4] = {0, 0, 0, 0}, q[4] = {0, 0, 0, 0};
    const int nTiles = (N_NODES + 63) / 64;  // 782
    for (int tile = blockIdx.x; tile < nTiles; tile += gridDim.x) {
        int r0 = tile * 64;
#pragma unroll
        for (int i = 0; i < 8; ++i) {
            int r = r0 + ty + 8 * i;
            int rc = min(r, N_NODES - 1);
            float4 v = *(const float4*)(X + (long)rc * HID + 4 * tx);
            float w = (r < N_NODES) ? 1.f : 0.f;
            float x0 = v.x * w, x1 = v.y * w, x2 = v.z * w, x3 = v.w * w;
            s[0] += x0; s[1] += x1; s[2] += x2; s[3] += x3;
            q[0] += x0 * v.x; q[1] += x1 * v.y; q[2] += x2 * v.z; q[3] += x3 * v.w;
        }
    }
#pragma unroll
    for (int c = 0; c < 4; ++c) {
        sh[ty * HID + 4 * tx + c] = s[c];
        sh[1024 + ty * HID + 4 * tx + c] = q[c];
    }
    __syncthreads();
    if (ty == 0) {
#pragma unroll
        for (int c = 0; c < 4; ++c) {
            float a = 0, b = 0;
#pragma unroll
            for (int j = 0; j < 8; ++j) {
                a += sh[j * HID + 4 * tx + c];
                b += sh[1024 + j * HID + 4 * tx + c];
            }
            atomicAdd(stats + (4 * tx + c) * SSTR, a);
            atomicAdd(stats + (HID + 4 * tx + c) * SSTR, b);
        }
    }
}

// ---------------------------------------------------------------------------
// BN apply, fp32 in -> bf16 out (input BN). Grid 2048, XCD-affine partition.
// ---------------------------------------------------------------------------
__global__ __launch_bounds__(256) void bn_apply_f32(const float* __restrict__ X,
                                                    ushort* __restrict__ Y,
                                                    const float* __restrict__ stats,
                                                    const float* __restrict__ g,
                                                    const float* __restrict__ b) {
    __shared__ float scL[HID], sfL[HID];
    int t = threadIdx.x;
    if (t < HID) {
        const float invN = 1.0f / (float)N_NODES;
        float mean = stats[t * SSTR] * invN;
        float var = stats[(HID + t) * SSTR] * invN - mean * mean;
        float s = g[t] * rsqrtf(var + 1e-5f);
        scL[t] = s;
        sfL[t] = b[t] - mean * s;
    }
    __syncthreads();
    int c4 = (t & 31) * 4;
    float sc[4], sf[4];
#pragma unroll
    for (int j = 0; j < 4; ++j) { sc[j] = scL[c4 + j]; sf[j] = sfL[c4 + j]; }
    int s0, s1;
    sub_range(blockIdx.x & 255, blockIdx.x >> 8, s0, s1);
    int c0 = s0 * 32, c1 = s1 * 32;  // float4 chunks (32/row); c0 % 32 == 0
    for (int i = c0 + t; i < c1; i += 256) {
        float4 v = ((const float4*)X)[i];
        ushort4 w;
        w.x = f2bf(v.x * sc[0] + sf[0]);
        w.y = f2bf(v.y * sc[1] + sf[1]);
        w.z = f2bf(v.z * sc[2] + sf[2]);
        w.w = f2bf(v.w * sc[3] + sf[3]);
        ((ushort4*)Y)[i] = w;
    }
}

// BN + gelu, bf16 in -> bf16 out. Grid 2048, XCD-affine partition.
__global__ __launch_bounds__(256) void bn_apply_bf(const ushort* __restrict__ X,
                                                   ushort* __restrict__ Y,
                                                   const float* __restrict__ stats,
                                                   const float* __restrict__ g,
                                                   const float* __restrict__ b) {
    __shared__ float scL[HID], sfL[HID];
    int t = threadIdx.x;
    if (t < HID) {
        const float invN = 1.0f / (float)N_NODES;
        float mean = stats[t * SSTR] * invN;
        float var = stats[(HID + t) * SSTR] * invN - mean * mean;
        float s = g[t] * rsqrtf(var + 1e-5f);
        scL[t] = s;
        sfL[t] = b[t] - mean * s;
    }
    __syncthreads();
    int c8 = (t & 15) * 8;
    float sc[8], sf[8];
#pragma unroll
    for (int j = 0; j < 8; ++j) { sc[j] = scL[c8 + j]; sf[j] = sfL[c8 + j]; }
    int s0, s1;
    sub_range(blockIdx.x & 255, blockIdx.x >> 8, s0, s1);
    int c0 = s0 * 16, c1 = s1 * 16;  // uint4 chunks (16/row); c0 % 16 == 0
    for (int i = c0 + t; i < c1; i += 256) {
        Chunk ch;
        ch.u4 = ((const uint4*)X)[i];
#pragma unroll
        for (int j = 0; j < 8; ++j) {
            float f = bf2f(ch.us[j]) * sc[j] + sf[j];
            ch.us[j] = f2bf(gelu_fast(f));
        }
        ((uint4*)Y)[i] = ch.u4;
    }
}

// ---------------------------------------------------------------------------
// CSR build: counting sort of edges by dst
// ---------------------------------------------------------------------------
__global__ __launch_bounds__(256) void csr_count(const int* __restrict__ dst,
                                                 int* __restrict__ counts) {
    int e = blockIdx.x * blockDim.x + threadIdx.x;
    if (e >= N_EDGES) return;
    atomicAdd(counts + dst[e], 1);
}

__global__ __launch_bounds__(256) void scan_pass1(const int* __restrict__ counts,
                                                  int* __restrict__ offs,
                                                  int* __restrict__ bsum) {
    __shared__ int sh[256];
    int t = threadIdx.x;
    int i = blockIdx.x * 256 + t;
    int v = (i < N_NODES) ? counts[i] : 0;
    sh[t] = v;
    __syncthreads();
    for (int off = 1; off < 256; off <<= 1) {
        int a = (t >= off) ? sh[t - off] : 0;
        __syncthreads();
        sh[t] += a;
        __syncthreads();
    }
    if (i < N_NODES) offs[i] = sh[t] - v;
    if (t == 255) bsum[blockIdx.x] = sh[255];
}

__global__ __launch_bounds__(256) void scan_pass2(int* __restrict__ bsum, int nblk) {
    __shared__ int sh[256];
    int t = threadIdx.x;
    int v = (t < nblk) ? bsum[t] : 0;
    sh[t] = v;
    __syncthreads();
    for (int off = 1; off < 256; off <<= 1) {
        int a = (t >= off) ? sh[t - off] : 0;
        __syncthreads();
        sh[t] += a;
        __syncthreads();
    }
    if (t < nblk) bsum[t] = sh[t] - v;
}

__global__ __launch_bounds__(256) void scan_pass3(int* __restrict__ offs,
                                                  const int* __restrict__ bsum,
                                                  int* __restrict__ cursor) {
    int i = blockIdx.x * 256 + threadIdx.x;
    if (i >= N_NODES) return;
    int o = offs[i] + bsum[blockIdx.x];
    offs[i] = o;
    cursor[i] = o;
}

__global__ __launch_bounds__(256) void csr_fill(const int* __restrict__ src,
                                                const int* __restrict__ dst,
                                                int* __restrict__ cursor,
                                                int* __restrict__ csr) {
    int e = blockIdx.x * blockDim.x + threadIdx.x;
    if (e >= N_EDGES) return;
    int pos = atomicAdd(cursor + dst[e], 1);
    csr[pos] = src[e];
}

// ---------------------------------------------------------------------------
// GIN aggregation (bf16): Hp[n] = (1+eps)*X[n] + sum X[nbr]; 8-deep pipelined.
// Grid 2048, XCD-affine: own row + output row stay on the producing XCD.
// ---------------------------------------------------------------------------
__global__ __launch_bounds__(256) void gin_gather_bf(const ushort* __restrict__ Xbf,
                                                     ushort* __restrict__ Hp,
                                                     const int* __restrict__ offs,
                                                     const int* __restrict__ counts,
                                                     const int* __restrict__ csr,
                                                     const float* __restrict__ eps, int l) {
    int t = threadIdx.x;
    int tx = t & 31;
    int g = t >> 5;  // 8 node-groups per block
    int s0, s1;
    sub_range(blockIdx.x & 255, blockIdx.x >> 8, s0, s1);
    float ev = 1.0f + eps[l];
    for (int node = s0 + g; node < s1; node += 8) {
        ushort4 sv = *(const ushort4*)(Xbf + (long)node * HID + 4 * tx);
        float a0 = bf2f(sv.x) * ev, a1 = bf2f(sv.y) * ev;
        float a2 = bf2f(sv.z) * ev, a3 = bf2f(sv.w) * ev;
        int o = offs[node];
        int d = counts[node];
        int k = 0;
        for (; k + 8 <= d; k += 8) {
            int si[8];
#pragma unroll
            for (int j = 0; j < 8; ++j) si[j] = csr[o + k + j];
            ushort4 v[8];
#pragma unroll
            for (int j = 0; j < 8; ++j)
                v[j] = *(const ushort4*)(Xbf + (long)si[j] * HID + 4 * tx);
#pragma unroll
            for (int j = 0; j < 8; ++j) {
                a0 += bf2f(v[j].x); a1 += bf2f(v[j].y);
                a2 += bf2f(v[j].z); a3 += bf2f(v[j].w);
            }
        }
        for (; k + 4 <= d; k += 4) {
            int si[4];
#pragma unroll
            for (int j = 0; j < 4; ++j) si[j] = csr[o + k + j];
#pragma unroll
            for (int j = 0; j < 4; ++j) {
                ushort4 v = *(const ushort4*)(Xbf + (long)si[j] * HID + 4 * tx);
                a0 += bf2f(v.x); a1 += bf2f(v.y); a2 += bf2f(v.z); a3 += bf2f(v.w);
            }
        }
        for (; k < d; ++k) {
            int s = csr[o + k];
            ushort4 v = *(const ushort4*)(Xbf + (long)s * HID + 4 * tx);
            a0 += bf2f(v.x); a1 += bf2f(v.y); a2 += bf2f(v.z); a3 += bf2f(v.w);
        }
        ushort4 w;
        w.x = f2bf(a0); w.y = f2bf(a1); w.z = f2bf(a2); w.w = f2bf(a3);
        *(ushort4*)(Hp + (long)node * HID + 4 * tx) = w;
    }
}

// ---------------------------------------------------------------------------
// Persistent MFMA GEMM, wave-pair column split, XCD-affine contiguous tiles:
// block b owns tiles [b*3125/256, (b+1)*3125/256) — same rows its partition's
// producer wrote -> local-L2 A reads. Bfrag 64 VGPR resident; next-tile
// register prefetch; per-wave LDS half-tile C store.
// ---------------------------------------------------------------------------
__global__ __launch_bounds__(256, 1) void gemm_persist(
    const ushort* __restrict__ Abf, const ushort* __restrict__ Wt,
    const float* __restrict__ bias, ushort* __restrict__ Cbf,
    const float* __restrict__ statsIn, const float* __restrict__ gIn,
    const float* __restrict__ bIn, int applyIn, float* __restrict__ statsOut) {
    __shared__ float scL[HID], sfL[HID];
    __shared__ __align__(16) ushort T[4][16 * TLD];
    __shared__ float shs[8 * 64];
    int t = threadIdx.x;
    if (applyIn && t < HID) {
        const float invN = 1.0f / (float)N_NODES;
        float mean = statsIn[t * SSTR] * invN;
        float var = statsIn[(HID + t) * SSTR] * invN - mean * mean;
        float s = gIn[t] * rsqrtf(var + 1e-5f);
        scL[t] = s;
        sfL[t] = bIn[t] - mean * s;
    }
    __syncthreads();

    int w = t >> 6, lane = t & 63;
    int m = lane & 15, q = lane >> 4;
    int c2 = w & 1, r2 = w >> 1;
    ushort* Tw = T[w];

    // B fragments for this wave's 64 columns: 64 VGPRs
    const ushort* Wh = Wt + (long)(c2 * 64) * HID;
    bf16x8 Bfrag[4][4];
#pragma unroll
    for (int nt = 0; nt < 4; ++nt)
#pragma unroll
        for (int kc = 0; kc < 4; ++kc)
            Bfrag[nt][kc] = *(const bf16x8*)(Wh + (nt * 16 + m) * HID + kc * 32 + q * 8);

    float bias4[4];
#pragma unroll
    for (int nt = 0; nt < 4; ++nt) bias4[nt] = bias[c2 * 64 + nt * 16 + m];

    float s_col[4], q_col[4];
#pragma unroll
    for (int nt = 0; nt < 4; ++nt) { s_col[nt] = 0.f; q_col[nt] = 0.f; }

    int t0 = (blockIdx.x * N_TILES) >> 8;
    int t1 = ((blockIdx.x + 1) * N_TILES) >> 8;

    int tile = t0 + r2;
    Chunk Ac[4];
    if (tile < t1) {
        const ushort* arow = Abf + (long)(tile * 16 + m) * HID + q * 8;
#pragma unroll
        for (int kc = 0; kc < 4; ++kc) Ac[kc].u4 = *(const uint4*)(arow + kc * 32);
    }
    while (tile < t1) {
        int nxt = tile + 2;
        Chunk An[4];
        if (nxt < t1) {
            const ushort* arow = Abf + (long)(nxt * 16 + m) * HID + q * 8;
#pragma unroll
            for (int kc = 0; kc < 4; ++kc) An[kc].u4 = *(const uint4*)(arow + kc * 32);
        }
        if (applyIn) {
#pragma unroll
            for (int kc = 0; kc < 4; ++kc)
#pragma unroll
                for (int j = 0; j < 8; ++j) {
                    int k = kc * 32 + q * 8 + j;
                    float f = bf2f(Ac[kc].us[j]) * scL[k] + sfL[k];
                    Ac[kc].us[j] = f2bf(gelu_fast(f));
                }
        }
        f32x4 acc[4];
#pragma unroll
        for (int nt = 0; nt < 4; ++nt) acc[nt] = (f32x4){0.f, 0.f, 0.f, 0.f};
#pragma unroll
        for (int kc = 0; kc < 4; ++kc)
#pragma unroll
            for (int nt = 0; nt < 4; ++nt)
                acc[nt] = __builtin_amdgcn_mfma_f32_16x16x32_bf16(Ac[kc].v, Bfrag[nt][kc],
                                                                  acc[nt], 0, 0, 0);
#pragma unroll
        for (int nt = 0; nt < 4; ++nt) {
            int col = nt * 16 + m;
#pragma unroll
            for (int r = 0; r < 4; ++r) {
                float z = acc[nt][r] + bias4[nt];
                Tw[(q * 4 + r) * TLD + col] = f2bf(z);
                s_col[nt] += z;
                q_col[nt] += z * z;
            }
        }
        long cbase = (long)(tile * 16) * HID + c2 * 64;
#pragma unroll
        for (int i = 0; i < 2; ++i) {
            int slot = i * 64 + lane;
            int row = slot >> 3, off = slot & 7;
            uint4 vv = *(const uint4*)(Tw + row * TLD + off * 8);
            *(uint4*)(Cbf + cbase + (long)row * HID + off * 8) = vv;
        }
        tile = nxt;
#pragma unroll
        for (int kc = 0; kc < 4; ++kc) Ac[kc] = An[kc];
    }

    // stats combine: shfl over q, then across waves via LDS, padded atomics
#pragma unroll
    for (int nt = 0; nt < 4; ++nt) {
        s_col[nt] += __shfl_xor(s_col[nt], 16);
        s_col[nt] += __shfl_xor(s_col[nt], 32);
        q_col[nt] += __shfl_xor(q_col[nt], 16);
        q_col[nt] += __shfl_xor(q_col[nt], 32);
    }
    if (q == 0) {
#pragma unroll
        for (int nt = 0; nt < 4; ++nt) {
            shs[w * 64 + nt * 16 + m] = s_col[nt];
            shs[256 + w * 64 + nt * 16 + m] = q_col[nt];
        }
    }
    __syncthreads();
    if (t < HID) {
        int half = t >> 6, lc = t & 63;
        float a = shs[half * 64 + lc] + shs[(2 + half) * 64 + lc];
        float b = shs[256 + half * 64 + lc] + shs[256 + (2 + half) * 64 + lc];
        atomicAdd(statsOut + t * SSTR, a);
        atomicAdd(statsOut + (HID + t) * SSTR, b);
    }
}

// JK attention over 4 layers (bf16 in, fp32 out). Grid 2048, XCD-affine;
// one wave per node per iteration.
__global__ __launch_bounds__(256) void jk_attn_bf(const ushort* __restrict__ H0,
                                                  const ushort* __restrict__ H1,
                                                  const ushort* __restrict__ H2,
                                                  const ushort* __restrict__ H3,
                                                  const float* __restrict__ att,
                                                  float* __restrict__ Y) {
    int t = threadIdx.x;
    int lane = t & 63, w = t >> 6;
    int s0, s1;
    sub_range(blockIdx.x & 255, blockIdx.x >> 8, s0, s1);
    const ushort* Hs[4] = {H0, H1, H2, H3};
    float2 av[4];
#pragma unroll
    for (int l = 0; l < 4; ++l) av[l] = *(const float2*)(att + l * HID + 2 * lane);
    for (int node = s0 + w; node < s1; node += 4) {
        float hx[4], hy[4], sc[4];
#pragma unroll
        for (int l = 0; l < 4; ++l) {
            unsigned int u = *(const unsigned int*)(Hs[l] + (long)node * HID + 2 * lane);
            float vx = bf2f((ushort)(u & 0xFFFF));
            float vy = bf2f((ushort)(u >> 16));
            hx[l] = vx; hy[l] = vy;
            float p = vx * av[l].x + vy * av[l].y;
#pragma unroll
            for (int off = 32; off > 0; off >>= 1) p += __shfl_xor(p, off);
            sc[l] = p * (1.0f / HID);
        }
        float mm = fmaxf(fmaxf(sc[0], sc[1]), fmaxf(sc[2], sc[3]));
        float e[4], se = 0.f;
#pragma unroll
        for (int l = 0; l < 4; ++l) { e[l] = expf(sc[l] - mm); se += e[l]; }
        float inv = 1.0f / se;
        float ox = 0.f, oy = 0.f;
#pragma unroll
        for (int l = 0; l < 4; ++l) {
            float a = e[l] * inv;
            ox += a * hx[l];
            oy += a * hy[l];
        }
        *(float2*)(Y + (long)node * HID + 2 * lane) = make_float2(ox, oy);
    }
}

__global__ void graph_ranges(const int* __restrict__ batch, int* __restrict__ gstart,
                             int* __restrict__ gend) {
    int n = blockIdx.x * blockDim.x + threadIdx.x;
    if (n >= N_NODES) return;
    int b = batch[n];
    if (n == 0 || batch[n - 1] != b) gstart[b] = n;
    if (n == N_NODES - 1 || batch[n + 1] != b) gend[b] = n + 1;
}

__global__ __launch_bounds__(128) void pool_kernel(const float* __restrict__ X,
                                                   const int* __restrict__ gstart,
                                                   const int* __restrict__ gend,
                                                   const float* __restrict__ pw,
                                                   float* __restrict__ pooled) {
    int g = blockIdx.x;
    int f = threadIdx.x;
    float w0 = pw[0], w1 = pw[1], w2 = pw[2];
    float m = fmaxf(w0, fmaxf(w1, w2));
    float e0 = expf(w0 - m), e1 = expf(w1 - m), e2 = expf(w2 - m);
    float inv = 1.0f / (e0 + e1 + e2);
    e0 *= inv; e1 *= inv; e2 *= inv;
    int s = gstart[g], e = gend[g];
    float sum = 0.f, mx = -INFINITY;
    for (int n = s; n < e; ++n) {
        float v = X[(long)n * HID + f];
        sum += v;
        mx = fmaxf(mx, v);
    }
    int cnt = e - s;
    float mean = cnt > 0 ? sum / (float)cnt : 0.f;
    float mxv = cnt > 0 ? mx : 0.f;
    pooled[g * HID + f] = sum * e0 + mean * e1 + mxv * e2;
}

__global__ __launch_bounds__(128) void head_kernel(const float* __restrict__ pooled,
                                                   const float* __restrict__ fcAw,
                                                   const float* __restrict__ fcAb,
                                                   const float* __restrict__ lng,
                                                   const float* __restrict__ lnb,
                                                   const float* __restrict__ fcBw,
                                                   const float* __restrict__ fcBb,
                                                   float* __restrict__ out) {
    __shared__ float p[HID], q[HID], red[HID];
    int g = blockIdx.x, j = threadIdx.x;
    p[j] = pooled[g * HID + j];
    __syncthreads();
    float acc = fcAb[j];
    for (int k = 0; k < HID; ++k) acc += p[k] * fcAw[k * HID + j];
    red[j] = acc;
    __syncthreads();
    for (int off = 64; off > 0; off >>= 1) {
        if (j < off) red[j] += red[j + off];
        __syncthreads();
    }
    float mean = red[0] * (1.0f / HID);
    __syncthreads();
    float d = acc - mean;
    red[j] = d * d;
    __syncthreads();
    for (int off = 64; off > 0; off >>= 1) {
        if (j < off) red[j] += red[j + off];
        __syncthreads();
    }
    float var = red[0] * (1.0f / HID);
    float y = d * rsqrtf(var + 1e-5f) * lng[j] + lnb[j];
    q[j] = gelu_exact(y) + p[j];
    __syncthreads();
    if (j < LAT) {
        float o = fcBb[j];
        for (int k = 0; k < HID; ++k) o += q[k] * fcBw[k * LAT + j];
        out[g * LAT + j] = o;
    }
}

extern "C" void kernel_launch(void* const* d_in, const int* in_sizes, int n_in,
                              void* d_out, int out_size, void* d_ws, size_t ws_size,
                              hipStream_t stream) {
    const float* x = (const float*)d_in[0];
    const int* ei = (const int*)d_in[1];
    const int* src = ei;
    const int* dst = ei + N_EDGES;
    const int* batch = (const int*)d_in[2];
    const float* ibn_g = (const float*)d_in[3];
    const float* ibn_b = (const float*)d_in[4];
    const float* eps = (const float*)d_in[5];
    const float* fc1w = (const float*)d_in[6];
    const float* fc1b = (const float*)d_in[7];
    const float* bn1g = (const float*)d_in[8];
    const float* bn1b = (const float*)d_in[9];
    const float* fc2w = (const float*)d_in[10];
    const float* fc2b = (const float*)d_in[11];
    const float* bng = (const float*)d_in[12];
    const float* bnb = (const float*)d_in[13];
    const float* att = (const float*)d_in[14];
    const float* pw = (const float*)d_in[15];
    const float* fcAw = (const float*)d_in[16];
    const float* fcAb = (const float*)d_in[17];
    const float* lng = (const float*)d_in[18];
    const float* lnb = (const float*)d_in[19];
    const float* fcBw = (const float*)d_in[20];
    const float* fcBb = (const float*)d_in[21];
    float* out = (float*)d_out;

    const size_t NH = (size_t)N_NODES * HID;
    char* w8 = (char*)d_ws;
    ushort* x0bf = (ushort*)w8;     w8 += NH * 2;
    ushort* hprebf = (ushort*)w8;   w8 += NH * 2;  // GEMM1 in; GEMM2 out
    ushort* z1bf = (ushort*)w8;     w8 += NH * 2;  // GEMM1 out / GEMM2 in
    ushort* Hlbf[NL];
    for (int l = 0; l < NL; ++l) { Hlbf[l] = (ushort*)w8; w8 += NH * 2; }
    float* ztmp = (float*)w8;       w8 += NH * 4;
    float* statsAll = (float*)w8;   w8 += (size_t)9 * SSET * 4;
    float* pooled = (float*)w8;     w8 += (size_t)N_GRAPHS * HID * 4;
    int* gstart = (int*)w8;         w8 += N_GRAPHS * 4;
    int* gend = (int*)w8;           w8 += N_GRAPHS * 4;
    int* counts = (int*)w8;         w8 += N_NODES * 4;
    int* offs = (int*)w8;           w8 += N_NODES * 4;
    int* cursor = (int*)w8;         w8 += N_NODES * 4;
    int* bsum = (int*)w8;           w8 += 256 * 4;
    int* csr = (int*)w8;            w8 += (size_t)N_EDGES * 4;
    ushort* WtBf = (ushort*)w8;     w8 += (size_t)8 * HID * HID * 2;

    const int nodeBlocks = (N_NODES + 255) / 256;
    const int edgeBlocks = (N_EDGES + 255) / 256;

    // weights once
    wt_build<<<512, 256, 0, stream>>>(fc1w, fc2w, WtBf);

    // CSR build
    hipMemsetAsync(counts, 0, N_NODES * sizeof(int), stream);
    csr_count<<<edgeBlocks, 256, 0, stream>>>(dst, counts);
    scan_pass1<<<nodeBlocks, 256, 0, stream>>>(counts, offs, bsum);
    scan_pass2<<<1, 256, 0, stream>>>(bsum, nodeBlocks);
    scan_pass3<<<nodeBlocks, 256, 0, stream>>>(offs, bsum, cursor);
    csr_fill<<<edgeBlocks, 256, 0, stream>>>(src, dst, cursor, csr);

    // zero all padded stat sets once
    hipMemsetAsync(statsAll, 0, (size_t)9 * SSET * sizeof(float), stream);

    // input BN -> bf16 x0
    col_stats<<<256, 256, 0, stream>>>(x, statsAll);
    bn_apply_f32<<<2048, 256, 0, stream>>>(x, x0bf, statsAll, ibn_g, ibn_b);

    const ushort* xin = x0bf;
    for (int l = 0; l < NL; ++l) {
        float* st1 = statsAll + (size_t)(1 + 2 * l) * SSET;
        float* st2 = statsAll + (size_t)(2 + 2 * l) * SSET;
        gin_gather_bf<<<2048, 256, 0, stream>>>(xin, hprebf, offs, counts, csr, eps, l);
        gemm_persist<<<256, 256, 0, stream>>>(hprebf, WtBf + (size_t)l * HID * HID,
                                              fc1b + l * HID, z1bf,
                                              nullptr, nullptr, nullptr, 0, st1);
        gemm_persist<<<256, 256, 0, stream>>>(z1bf, WtBf + (size_t)(4 + l) * HID * HID,
                                              fc2b + l * HID, hprebf,
                                              st1, bn1g + l * HID, bn1b + l * HID, 1, st2);
        bn_apply_bf<<<2048, 256, 0, stream>>>(hprebf, Hlbf[l], st2, bng + l * HID,
                                              bnb + l * HID);
        xin = Hlbf[l];
    }

    // JK attention -> ztmp (fp32)
    jk_attn_bf<<<2048, 256, 0, stream>>>(Hlbf[0], Hlbf[1], Hlbf[2], Hlbf[3], att, ztmp);

    // pooling
    hipMemsetAsync(gstart, 0, 2 * N_GRAPHS * sizeof(int), stream);
    graph_ranges<<<nodeBlocks, 256, 0, stream>>>(batch, gstart, gend);
    pool_kernel<<<N_GRAPHS, 128, 0, stream>>>(ztmp, gstart, gend, pw, pooled);

    // head
    head_kernel<<<N_GRAPHS, 128, 0, stream>>>(pooled, fcAw, fcAb, lng, lnb, fcBw, fcBb, out);
}